// Round 9
// baseline (584.626 us; speedup 1.0000x reference)
//
#include <hip/hip_runtime.h>
#include <hip/hip_bf16.h>
#include <cmath>

#define NL      6
#define NHEADS  4
#define DIM     128
#define FFD     512
#define CMID_   8
#define COUT_   16
#define QOUT_   10
#define MAXLEN_ 512
#define NCLS_   3
#define BB      32
#define TT      500
#define FIN_    232
#define MM      (BB*TT)
#define HD      32
#define RELLEN  (2*MAXLEN_-1)
#define LOG2E   1.4426950408889634f

typedef __attribute__((ext_vector_type(8))) short short8;
typedef __attribute__((ext_vector_type(4))) float f32x4;
typedef unsigned short ushort_t;

__device__ inline unsigned bf16r(float x) {   // RNE float->bf16 bits (finite inputs)
    unsigned u = __float_as_uint(x);
    return (u + 0x7fffu + ((u >> 16) & 1u)) >> 16;
}

// paired RNE pack via HW v_cvt_pk_bf16_f32
__device__ inline unsigned pkbf16(float a, float b) {
    __hip_bfloat162 h2 = __float22bfloat162_rn(float2{a, b});
    return *reinterpret_cast<unsigned*>(&h2);
}

// ---------------- encoder precompute (1 block) ----------------
__global__ __launch_bounds__(128) void enc_pre_kernel(
    const float* __restrict__ proj_w, const float* __restrict__ proj_b,
    const float* __restrict__ queries, const float* __restrict__ fc_w,
    const float* __restrict__ fc_b, const float* __restrict__ embed_w,
    const float* __restrict__ embed_b,
    float* __restrict__ alpha, float* __restrict__ E, float* __restrict__ c0)
{
    __shared__ float pw[CMID_], cb[CMID_], gam[COUT_], del[COUT_];
    int t = threadIdx.x;
    if (t < CMID_) { pw[t] = proj_w[t]; cb[t] = proj_b[t] + ((t & 1) ? 1.f : 0.f); }
    __syncthreads();
    if (t < QOUT_) {
        float a = 0.f;
        for (int c = 0; c < CMID_; ++c) a += pw[c] * queries[t*CMID_ + c];
        alpha[t] = a;
    }
    if (t < COUT_) {
        float gg = 0.f, dd = 0.f;
        for (int c = 0; c < CMID_; ++c) {
            gg += pw[c] * fc_w[c*COUT_ + t];
            dd += cb[c] * fc_w[c*COUT_ + t];
        }
        gam[t] = gg; del[t] = dd + fc_b[t];
    }
    __syncthreads();
    for (int i = t; i < QOUT_*DIM; i += 128) {
        int q = i / DIM, d = i % DIM;
        float e = 0.f;
        for (int o = 0; o < COUT_; ++o) e += gam[o] * embed_w[(o*QOUT_ + q)*DIM + d];
        E[i] = e;
    }
    {
        float c = embed_b[t];
        for (int o = 0; o < COUT_; ++o) {
            float dl = del[o];
            for (int q = 0; q < QOUT_; ++q) c += dl * embed_w[(o*QOUT_ + q)*DIM + t];
        }
        c0[t] = c;
    }
}

// ---------------- encoder main ----------------
__global__ __launch_bounds__(64) void enc_kernel(
    const float* __restrict__ x1, const float* __restrict__ alpha,
    const float* __restrict__ E, const float* __restrict__ c0,
    float* __restrict__ h, ushort_t* __restrict__ hb)
{
    int bt = blockIdx.x;
    int lane = threadIdx.x;
    const float* xr = x1 + (size_t)bt * FIN_;
    float xv[4];
    bool vld[4];
    #pragma unroll
    for (int i = 0; i < 4; ++i) {
        int f = lane + (i << 6);
        vld[i] = (f < FIN_);
        xv[i] = vld[i] ? xr[f] : 0.f;
    }
    float vmax = -INFINITY, vmin = INFINITY;
    #pragma unroll
    for (int i = 0; i < 4; ++i) if (vld[i]) { vmax = fmaxf(vmax, xv[i]); vmin = fminf(vmin, xv[i]); }
    #pragma unroll
    for (int off = 1; off < 64; off <<= 1) {
        vmax = fmaxf(vmax, __shfl_xor(vmax, off));
        vmin = fminf(vmin, __shfl_xor(vmin, off));
    }
    float mq[QOUT_];
    for (int q = 0; q < QOUT_; ++q) {
        float a = alpha[q];
        float Mx = (a >= 0.f) ? a * vmax : a * vmin;
        float se = 0.f, sx = 0.f;
        #pragma unroll
        for (int i = 0; i < 4; ++i) if (vld[i]) {
            float e = __expf(fmaf(a, xv[i], -Mx));
            se += e; sx += e * xv[i];
        }
        #pragma unroll
        for (int off = 1; off < 64; off <<= 1) { se += __shfl_xor(se, off); sx += __shfl_xor(sx, off); }
        mq[q] = sx / se;
    }
    #pragma unroll
    for (int k = 0; k < 2; ++k) {
        int d = lane + (k << 6);
        float hv = c0[d];
        #pragma unroll
        for (int q = 0; q < QOUT_; ++q) hv = fmaf(mq[q], E[q*DIM + d], hv);
        h[(size_t)bt*DIM + d] = hv;
        hb[(size_t)bt*DIM + d] = (ushort_t)bf16r(hv);
    }
}

// ---------------- weight transpose + bf16 convert (once per launch) ----------------
__global__ __launch_bounds__(256) void wtrans_kernel(
    const float* __restrict__ wqkv, const float* __restrict__ wo,
    const float* __restrict__ w1, const float* __restrict__ w2,
    ushort_t* __restrict__ wts)
{
    int bid = blockIdx.x;
    const float* W; ushort_t* Wt; int K, N, tk, tn;
    if (bid < 72) {            // wqkv: K=128,N=384 -> 2x6 tiles x 6 layers
        int l = bid / 12, t = bid % 12; tk = t / 6; tn = t % 6; K = 128; N = 384;
        W = wqkv + (size_t)l*128*384; Wt = wts + (size_t)l*49152;
    } else if (bid < 96) {     // wo: 128x128 -> 2x2 x 6
        int q = bid - 72; int l = q / 4, t = q % 4; tk = t / 2; tn = t % 2; K = 128; N = 128;
        W = wo + (size_t)l*16384; Wt = wts + 294912 + (size_t)l*16384;
    } else if (bid < 192) {    // w1: K=128,N=512 -> 2x8 x 6
        int q = bid - 96; int l = q / 16, t = q % 16; tk = t / 8; tn = t % 8; K = 128; N = 512;
        W = w1 + (size_t)l*65536; Wt = wts + 393216 + (size_t)l*65536;
    } else {                   // w2: K=512,N=128 -> 8x2 x 6
        int q = bid - 192; int l = q / 16, t = q % 16; tk = t / 2; tn = t % 2; K = 512; N = 128;
        W = w2 + (size_t)l*65536; Wt = wts + 786432 + (size_t)l*65536;
    }
    int k0 = tk << 6, n0 = tn << 6;
    __shared__ float Ls[64][65];
    int tid = threadIdx.x;
    #pragma unroll
    for (int i = 0; i < 4; ++i) {
        int id = tid + 256*i;
        int r = id >> 4, ch = id & 15;
        float4 v = *reinterpret_cast<const float4*>(W + (size_t)(k0+r)*N + n0 + ch*4);
        Ls[ch*4+0][r] = v.x; Ls[ch*4+1][r] = v.y; Ls[ch*4+2][r] = v.z; Ls[ch*4+3][r] = v.w;
    }
    __syncthreads();
    #pragma unroll
    for (int i = 0; i < 4; ++i) {
        int id = tid + 256*i;
        int rr = id >> 4, ch = id & 15;
        uint2 o2;
        o2.x = pkbf16(Ls[rr][ch*4+0], Ls[rr][ch*4+1]);
        o2.y = pkbf16(Ls[rr][ch*4+2], Ls[rr][ch*4+3]);
        *reinterpret_cast<uint2*>(Wt + (size_t)(n0+rr)*K + k0 + ch*4) = o2;
    }
}

// ---------------- bf16 MFMA GEMM (qkv projection), reg-prefetch staging ----------------
template<int BM>
__global__ __launch_bounds__(256) void gemm_mfma_kernel(
    const ushort_t* __restrict__ A, const ushort_t* __restrict__ Wt,
    const float* __restrict__ bias, void* __restrict__ C,
    int N, int K, int relu, int obf16)
{
    constexpr int MREP = BM / 32;
    constexpr int APT  = BM / 32;
    __shared__ __align__(16) ushort_t As[BM * 64];
    __shared__ __align__(16) ushort_t Bs[64 * 64];
    const int tid = threadIdx.x;
    const int row0 = blockIdx.y * BM, col0 = blockIdx.x << 6;
    const int w = tid >> 6, lane = tid & 63, g = lane >> 4, n = lane & 15;
    const int wr = w & 1, wc = w >> 1;
    f32x4 acc[MREP][2];
    #pragma unroll
    for (int mt = 0; mt < MREP; ++mt)
        #pragma unroll
        for (int nt = 0; nt < 2; ++nt) acc[mt][nt] = (f32x4){0.f,0.f,0.f,0.f};

    uint4 pA[APT], pB[2];
    auto loadT = [&](int k0) {
        #pragma unroll
        for (int i = 0; i < APT; ++i) {
            int id = tid + 256*i;
            int r = id >> 3, c = id & 7;
            pA[i] = *reinterpret_cast<const uint4*>(A + (size_t)(row0 + r)*K + k0 + c*8);
        }
        #pragma unroll
        for (int i = 0; i < 2; ++i) {
            int id = tid + 256*i;
            int r = id >> 3, c = id & 7;
            pB[i] = *reinterpret_cast<const uint4*>(Wt + (size_t)(col0 + r)*K + k0 + c*8);
        }
    };
    loadT(0);

    for (int k0 = 0; k0 < K; k0 += 64) {
        __syncthreads();
        #pragma unroll
        for (int i = 0; i < APT; ++i) {
            int id = tid + 256*i;
            int r = id >> 3, c = id & 7;
            *reinterpret_cast<uint4*>(As + r*64 + ((c ^ (r & 7)) << 3)) = pA[i];
        }
        #pragma unroll
        for (int i = 0; i < 2; ++i) {
            int id = tid + 256*i;
            int r = id >> 3, c = id & 7;
            *reinterpret_cast<uint4*>(Bs + r*64 + ((c ^ (r & 7)) << 3)) = pB[i];
        }
        if (k0 + 64 < K) loadT(k0 + 64);
        __syncthreads();
        #pragma unroll
        for (int ks = 0; ks < 2; ++ks) {
            short8 af[MREP], bfr[2];
            #pragma unroll
            for (int mt = 0; mt < MREP; ++mt) {
                int r = wr*(BM/2) + mt*16 + n;
                af[mt] = *reinterpret_cast<const short8*>(As + r*64 + (((ks*4 + g) ^ (r & 7)) << 3));
            }
            #pragma unroll
            for (int nt = 0; nt < 2; ++nt) {
                int r = wc*32 + nt*16 + n;
                bfr[nt] = *reinterpret_cast<const short8*>(Bs + r*64 + (((ks*4 + g) ^ (r & 7)) << 3));
            }
            #pragma unroll
            for (int mt = 0; mt < MREP; ++mt)
                #pragma unroll
                for (int nt = 0; nt < 2; ++nt)
                    acc[mt][nt] = __builtin_amdgcn_mfma_f32_16x16x32_bf16(af[mt], bfr[nt], acc[mt][nt], 0, 0, 0);
        }
    }
    #pragma unroll
    for (int mt = 0; mt < MREP; ++mt) {
        #pragma unroll
        for (int nt = 0; nt < 2; ++nt) {
            int col = col0 + wc*32 + nt*16 + n;
            float bv = bias[col];
            #pragma unroll
            for (int r4 = 0; r4 < 4; ++r4) {
                int row = row0 + wr*(BM/2) + mt*16 + g*4 + r4;
                float v = acc[mt][nt][r4] + bv;
                if (relu) v = fmaxf(v, 0.f);
                if (obf16) ((ushort_t*)C)[(size_t)row*N + col] = (ushort_t)bf16r(v);
                else       ((float*)C)[(size_t)row*N + col] = v;
            }
        }
    }
}

// ---------------- MFMA bf16 flash attention (QBLK=128, KVBLK=64, exp2, prefetch) ------
// grid: B*NHEADS*4 blocks, 512 threads = 8 waves x 16 q-rows each.
__global__ __launch_bounds__(512) void attn_mfma_kernel(
    const ushort_t* __restrict__ qkv, const float* __restrict__ rel,
    ushort_t* __restrict__ o)
{
    __shared__ __align__(16) ushort_t Ks[64][40];          // [kcol][dim] 80B rows
    __shared__ __align__(16) ushort_t Vs[64][36];          // [kcol][dim] 72B rows
    __shared__ __align__(16) ushort_t VB[2][2][4][16][8];  // [kchalf][dimhalf][g][n][j]
    __shared__ float rl[RELLEN];
    const int bid = blockIdx.x;
    const int qt = bid & 3;
    const int bh = bid >> 2;
    const int hh = bh & 3, b = bh >> 2;
    const int tid  = threadIdx.x;
    const int w    = tid >> 6;
    const int lane = tid & 63;
    const int g = lane >> 4, n = lane & 15;
    for (int i = tid; i < RELLEN; i += 512) rl[i] = rel[i] * LOG2E;

    const int qrow = (qt << 7) + (w << 4) + n;
    const bool qv = (qrow < TT);
    short8 qf = {0,0,0,0,0,0,0,0};
    if (qv) qf = *reinterpret_cast<const short8*>(qkv + (size_t)(b*TT + qrow)*384 + hh*HD + g*8);

    f32x4 acc0 = {0.f,0.f,0.f,0.f}, acc1 = {0.f,0.f,0.f,0.f};
    float m = -INFINITY, lsum = 0.f;
    const float scale2 = 0.17677669529663687f * LOG2E;
    const f32x4 zf = {0.f,0.f,0.f,0.f};

    const int sr = tid >> 3, sc = tid & 7;      // stage: 64 rows x 8 chunks of 8B
    uint2 kreg, vreg;
    auto issue = [&](int kt) {                   // load tile kt into regs (overlaps compute)
        int t = (kt << 6) + sr;
        kreg = make_uint2(0,0); vreg = make_uint2(0,0);
        if (t < TT) {
            const ushort_t* bp = qkv + (size_t)(b*TT + t)*384 + hh*HD + sc*4;
            kreg = *reinterpret_cast<const uint2*>(bp + 128);
            vreg = *reinterpret_cast<const uint2*>(bp + 256);
        }
    };

    auto compute = [&](const int kt, const bool domask) {
        const int k0 = kt << 6;
        // V relayout into fragment-linear VB (4 elems/thread, 512 threads)
        {
            int jh = (tid & 1)*4, nn = (tid >> 1) & 15, gg = (tid >> 5) & 3;
            int dh = (tid >> 7) & 1, kch = (tid >> 8) & 1;
            ushort_t tmp[4];
            #pragma unroll
            for (int j = 0; j < 4; ++j) tmp[j] = Vs[kch*32 + gg*8 + jh + j][dh*16 + nn];
            *reinterpret_cast<uint2*>(&VB[kch][dh][gg][nn][jh]) = *reinterpret_cast<uint2*>(tmp);
        }

        // S^T = K . Q^T : 4 tiles of 16 kcols (per wave)
        f32x4 s[4];
        #pragma unroll
        for (int c = 0; c < 4; ++c) {
            short8 ak = *reinterpret_cast<const short8*>(&Ks[c*16 + n][g*8]);
            s[c] = __builtin_amdgcn_mfma_f32_16x16x32_bf16(ak, qf, zf, 0, 0, 0);
        }

        float sv[16];
        float tmax = -INFINITY;
        #pragma unroll
        for (int c = 0; c < 4; ++c)
            #pragma unroll
            for (int r = 0; r < 4; ++r) {
                int kc = k0 + c*16 + g*4 + r;
                float bia = rl[kc - qrow + (MAXLEN_-1)];
                float v = fmaf(s[c][r], scale2, bia);
                if (domask && kc >= TT) v = -1e30f;
                sv[c*4 + r] = v;
                tmax = fmaxf(tmax, v);
            }
        tmax = fmaxf(tmax, __shfl_xor(tmax, 16));
        tmax = fmaxf(tmax, __shfl_xor(tmax, 32));
        float mnew = fmaxf(m, tmax);
        float corr = exp2f(m - mnew);
        m = mnew;
        float ps = 0.f;
        #pragma unroll
        for (int r = 0; r < 16; ++r) { float e = exp2f(sv[r] - mnew); sv[r] = e; ps += e; }
        ps += __shfl_xor(ps, 16);
        ps += __shfl_xor(ps, 32);
        lsum = fmaf(lsum, corr, ps);

        int src0 = n + ((g & 1) << 5);
        int src1 = src0 + 16;
        int t0 = (g < 2);
        union { unsigned wd[4]; short8 v; } PA, PB;
        {
            unsigned pk0lo = pkbf16(sv[0], sv[1]);
            unsigned pk0hi = pkbf16(sv[2], sv[3]);
            unsigned pk1lo = pkbf16(sv[4], sv[5]);
            unsigned pk1hi = pkbf16(sv[6], sv[7]);
            unsigned a0 = __shfl((int)pk0lo, src0), c0_ = __shfl((int)pk1lo, src0);
            unsigned a1 = __shfl((int)pk0hi, src0), c1_ = __shfl((int)pk1hi, src0);
            unsigned a2 = __shfl((int)pk0lo, src1), c2_ = __shfl((int)pk1lo, src1);
            unsigned a3 = __shfl((int)pk0hi, src1), c3_ = __shfl((int)pk1hi, src1);
            PA.wd[0] = t0 ? a0 : c0_; PA.wd[1] = t0 ? a1 : c1_;
            PA.wd[2] = t0 ? a2 : c2_; PA.wd[3] = t0 ? a3 : c3_;
        }
        {
            unsigned pk0lo = pkbf16(sv[8],  sv[9]);
            unsigned pk0hi = pkbf16(sv[10], sv[11]);
            unsigned pk1lo = pkbf16(sv[12], sv[13]);
            unsigned pk1hi = pkbf16(sv[14], sv[15]);
            unsigned a0 = __shfl((int)pk0lo, src0), c0_ = __shfl((int)pk1lo, src0);
            unsigned a1 = __shfl((int)pk0hi, src0), c1_ = __shfl((int)pk1hi, src0);
            unsigned a2 = __shfl((int)pk0lo, src1), c2_ = __shfl((int)pk1lo, src1);
            unsigned a3 = __shfl((int)pk0hi, src1), c3_ = __shfl((int)pk1hi, src1);
            PB.wd[0] = t0 ? a0 : c0_; PB.wd[1] = t0 ? a1 : c1_;
            PB.wd[2] = t0 ? a2 : c2_; PB.wd[3] = t0 ? a3 : c3_;
        }

        short8 a00 = *reinterpret_cast<const short8*>(&VB[0][0][g][n][0]);
        short8 a01 = *reinterpret_cast<const short8*>(&VB[0][1][g][n][0]);
        short8 a10 = *reinterpret_cast<const short8*>(&VB[1][0][g][n][0]);
        short8 a11 = *reinterpret_cast<const short8*>(&VB[1][1][g][n][0]);
        #pragma unroll
        for (int r = 0; r < 4; ++r) { acc0[r] *= corr; acc1[r] *= corr; }
        acc0 = __builtin_amdgcn_mfma_f32_16x16x32_bf16(a00, PA.v, acc0, 0, 0, 0);
        acc0 = __builtin_amdgcn_mfma_f32_16x16x32_bf16(a10, PB.v, acc0, 0, 0, 0);
        acc1 = __builtin_amdgcn_mfma_f32_16x16x32_bf16(a01, PA.v, acc1, 0, 0, 0);
        acc1 = __builtin_amdgcn_mfma_f32_16x16x32_bf16(a11, PB.v, acc1, 0, 0, 0);
    };

    issue(0);
    for (int kt = 0; kt < 8; ++kt) {
        __syncthreads();                        // LDS free (prev consumed; rl on kt=0)
        *reinterpret_cast<uint2*>(&Ks[sr][sc*4]) = kreg;
        *reinterpret_cast<uint2*>(&Vs[sr][sc*4]) = vreg;
        if (kt < 7) issue(kt + 1);              // next tile's loads fly during compute
        __syncthreads();                        // LDS ready
        compute(kt, kt == 7);
    }

    if (qv) {
        float inv = 1.f / lsum;
        uint2 p0, p1;
        p0.x = pkbf16(acc0[0]*inv, acc0[1]*inv);
        p0.y = pkbf16(acc0[2]*inv, acc0[3]*inv);
        p1.x = pkbf16(acc1[0]*inv, acc1[1]*inv);
        p1.y = pkbf16(acc1[2]*inv, acc1[3]*inv);
        ushort_t* op = o + (size_t)(b*TT + qrow)*DIM + hh*HD + g*4;
        *reinterpret_cast<uint2*>(op)      = p0;
        *reinterpret_cast<uint2*>(op + 16) = p1;
    }
}

// ---------------- fused post-attention: wo GEMM + LN1 + FFN + LN2 (reg-prefetch) ------
__global__ __launch_bounds__(256) void pa_kernel(
    const ushort_t* __restrict__ attno, const ushort_t* __restrict__ wot,
    const float* __restrict__ bo, const ushort_t* __restrict__ W1t,
    const ushort_t* __restrict__ W2t, const float* __restrict__ b1v,
    const float* __restrict__ b2v, float* __restrict__ h, ushort_t* __restrict__ hb,
    const float* __restrict__ ln1g, const float* __restrict__ ln1b,
    const float* __restrict__ ln2g, const float* __restrict__ ln2b)
{
    __shared__ __align__(16) ushort_t As[32 * 128];     // 8 KB: attno tile, then LN1 bf16
    __shared__ __align__(16) ushort_t Wbuf[8192];       // 16 KB weight chunk
    __shared__ __align__(16) ushort_t Mid[32 * 512];    // 32 KB
    __shared__ float Hres[32 * 132];                    // 16.9 KB, padded rows
    __shared__ float red[4][32][2];
    __shared__ float stats[32][2];
    const int tid = threadIdx.x;
    const int row0 = blockIdx.x << 5;
    const int w = tid >> 6, lane = tid & 63, g = lane >> 4, n = lane & 15;

    uint4 pw[4];
    auto loadWo = [&](int k0) {                 // wo: Wbuf[128 n][64 k]
        #pragma unroll
        for (int i = 0; i < 4; ++i) {
            int id = tid + 256*i;
            int r = id >> 3, c = id & 7;
            pw[i] = *reinterpret_cast<const uint4*>(wot + (size_t)r*DIM + k0 + c*8);
        }
    };
    auto loadW1 = [&](int cc) {                 // W1: Wbuf[64 k1][128 k]
        #pragma unroll
        for (int i = 0; i < 4; ++i) {
            int id = tid + 256*i;
            int r = id >> 4, c = id & 15;
            pw[i] = *reinterpret_cast<const uint4*>(W1t + (size_t)(cc*64 + r)*DIM + c*8);
        }
    };
    auto loadW2 = [&](int kc) {                 // W2: Wbuf[128 c][64 k1]
        #pragma unroll
        for (int i = 0; i < 4; ++i) {
            int id = tid + 256*i;
            int r = id >> 3, c = id & 7;
            pw[i] = *reinterpret_cast<const uint4*>(W2t + (size_t)r*FFD + kc*64 + c*8);
        }
    };

    loadWo(0);
    // stage attno tile (32 x 128)
    #pragma unroll
    for (int i = 0; i < 2; ++i) {
        int id = tid + 256*i;
        int r = id >> 4, c = id & 15;
        uint4 v = *reinterpret_cast<const uint4*>(attno + (size_t)(row0 + r)*DIM + c*8);
        *reinterpret_cast<uint4*>(As + r*128 + ((c ^ (r & 7)) << 3)) = v;
    }

    // ---- phase A: wo GEMM (K=128) ----
    f32x4 acc[2][2];
    #pragma unroll
    for (int a = 0; a < 2; ++a)
        #pragma unroll
        for (int b = 0; b < 2; ++b) acc[a][b] = (f32x4){0.f,0.f,0.f,0.f};
    #pragma unroll
    for (int k0 = 0; k0 < 128; k0 += 64) {
        __syncthreads();
        #pragma unroll
        for (int i = 0; i < 4; ++i) {
            int id = tid + 256*i;
            int r = id >> 3, c = id & 7;
            *reinterpret_cast<uint4*>(Wbuf + r*64 + ((c ^ (r & 7)) << 3)) = pw[i];
        }
        if (k0 == 0) loadWo(64);
        __syncthreads();
        #pragma unroll
        for (int ks = 0; ks < 2; ++ks) {
            short8 af[2], bfr[2];
            #pragma unroll
            for (int mt = 0; mt < 2; ++mt) {
                int r = mt*16 + n;
                int ch = (k0 >> 3) + ks*4 + g;
                af[mt] = *reinterpret_cast<const short8*>(As + r*128 + ((ch ^ (r & 7)) << 3));
            }
            #pragma unroll
            for (int nt = 0; nt < 2; ++nt) {
                int r = w*32 + nt*16 + n;
                bfr[nt] = *reinterpret_cast<const short8*>(Wbuf + r*64 + (((ks*4 + g) ^ (r & 7)) << 3));
            }
            #pragma unroll
            for (int mt = 0; mt < 2; ++mt)
                #pragma unroll
                for (int nt = 0; nt < 2; ++nt)
                    acc[mt][nt] = __builtin_amdgcn_mfma_f32_16x16x32_bf16(af[mt], bfr[nt], acc[mt][nt], 0, 0, 0);
        }
    }
    loadW1(0);                                  // prefetch B1 chunk0 during epilogue A
    // epilogue A: bias + residual + LN1 -> Hres (f32) + As (bf16)
    {
        float vals[2][2][4];
        #pragma unroll
        for (int nt = 0; nt < 2; ++nt) {
            int col = w*32 + nt*16 + n;
            float bv = bo[col];
            #pragma unroll
            for (int mt = 0; mt < 2; ++mt)
                #pragma unroll
                for (int r4 = 0; r4 < 4; ++r4) {
                    int row = row0 + mt*16 + g*4 + r4;
                    vals[mt][nt][r4] = acc[mt][nt][r4] + bv + h[(size_t)row*DIM + col];
                }
        }
        #pragma unroll
        for (int mt = 0; mt < 2; ++mt)
            #pragma unroll
            for (int r4 = 0; r4 < 4; ++r4) {
                float s  = vals[mt][0][r4] + vals[mt][1][r4];
                float s2 = vals[mt][0][r4]*vals[mt][0][r4] + vals[mt][1][r4]*vals[mt][1][r4];
                #pragma unroll
                for (int off = 1; off < 16; off <<= 1) {
                    s  += __shfl_xor(s, off);
                    s2 += __shfl_xor(s2, off);
                }
                if (n == 0) { red[w][mt*16 + g*4 + r4][0] = s; red[w][mt*16 + g*4 + r4][1] = s2; }
            }
        __syncthreads();
        if (tid < 32) {
            float s = 0.f, s2 = 0.f;
            #pragma unroll
            for (int ww = 0; ww < 4; ++ww) { s += red[ww][tid][0]; s2 += red[ww][tid][1]; }
            float mean = s * (1.f/128.f);
            float var  = s2 * (1.f/128.f) - mean*mean;
            stats[tid][0] = mean;
            stats[tid][1] = rsqrtf(var + 1e-5f);
        }
        __syncthreads();
        #pragma unroll
        for (int nt = 0; nt < 2; ++nt) {
            int col = w*32 + nt*16 + n;
            int ch = col >> 3, off8 = col & 7;
            float gv = ln1g[col], bv = ln1b[col];
            #pragma unroll
            for (int mt = 0; mt < 2; ++mt)
                #pragma unroll
                for (int r4 = 0; r4 < 4; ++r4) {
                    int rloc = mt*16 + g*4 + r4;
                    float y = (vals[mt][nt][r4] - stats[rloc][0]) * stats[rloc][1] * gv + bv;
                    Hres[rloc*132 + col] = y;
                    As[rloc*128 + ((ch ^ (rloc & 7)) << 3) + off8] = (ushort_t)bf16r(y);
                }
        }
    }

    // ---- phase B1: Mid = relu(As @ W1 + b1), 8 chunks of 64 k1-cols ----
    for (int cc = 0; cc < 8; ++cc) {
        __syncthreads();                        // Wbuf free + As writes visible (cc=0)
        #pragma unroll
        for (int i = 0; i < 4; ++i) {
            int id = tid + 256*i;
            int r = id >> 4, c = id & 15;
            *reinterpret_cast<uint4*>(Wbuf + r*128 + ((c ^ (r & 7)) << 3)) = pw[i];
        }
        if (cc < 7) loadW1(cc + 1); else loadW2(0);
        __syncthreads();
        f32x4 acc1[2] = {{0.f,0.f,0.f,0.f},{0.f,0.f,0.f,0.f}};
        #pragma unroll
        for (int ks = 0; ks < 4; ++ks) {
            int rW = w*16 + n;
            short8 aw = *reinterpret_cast<const short8*>(Wbuf + rW*128 + (((ks*4 + g) ^ (rW & 7)) << 3));
            #pragma unroll
            for (int mt = 0; mt < 2; ++mt) {
                int rA = mt*16 + n;
                short8 bh_ = *reinterpret_cast<const short8*>(As + rA*128 + (((ks*4 + g) ^ (rA & 7)) << 3));
                acc1[mt] = __builtin_amdgcn_mfma_f32_16x16x32_bf16(aw, bh_, acc1[mt], 0, 0, 0);
            }
        }
        {
            int k1b = cc*64 + w*16 + g*4;
            float4 bb = *reinterpret_cast<const float4*>(b1v + k1b);
            int ch = k1b >> 3;
            int halfoff = (g & 1) * 4;
            #pragma unroll
            for (int mt = 0; mt < 2; ++mt) {
                int mrow = mt*16 + n;
                float v0 = fmaxf(acc1[mt][0] + bb.x, 0.f);
                float v1 = fmaxf(acc1[mt][1] + bb.y, 0.f);
                float v2 = fmaxf(acc1[mt][2] + bb.z, 0.f);
                float v3 = fmaxf(acc1[mt][3] + bb.w, 0.f);
                uint2 pk;
                pk.x = pkbf16(v0, v1);
                pk.y = pkbf16(v2, v3);
                *reinterpret_cast<uint2*>(Mid + mrow*512 + ((ch ^ (mrow & 7)) << 3) + halfoff) = pk;
            }
        }
    }

    // ---- phase B2: out = Mid @ W2, 8 chunks of 64 k1 ----
    f32x4 oacc[2][2];
    #pragma unroll
    for (int a = 0; a < 2; ++a)
        #pragma unroll
        for (int b = 0; b < 2; ++b) oacc[a][b] = (f32x4){0.f,0.f,0.f,0.f};
    for (int kc = 0; kc < 8; ++kc) {
        __syncthreads();                        // Wbuf free + Mid complete (kc=0)
        #pragma unroll
        for (int i = 0; i < 4; ++i) {
            int id = tid + 256*i;
            int r = id >> 3, c = id & 7;
            *reinterpret_cast<uint4*>(Wbuf + r*64 + ((c ^ (r & 7)) << 3)) = pw[i];
        }
        if (kc < 7) loadW2(kc + 1);
        __syncthreads();
        #pragma unroll
        for (int ks = 0; ks < 2; ++ks) {
            short8 aw[2], bm[2];
            #pragma unroll
            for (int ct = 0; ct < 2; ++ct) {
                int r = w*32 + ct*16 + n;
                aw[ct] = *reinterpret_cast<const short8*>(Wbuf + r*64 + (((ks*4 + g) ^ (r & 7)) << 3));
            }
            #pragma unroll
            for (int mt = 0; mt < 2; ++mt) {
                int r = mt*16 + n;
                int ch = kc*8 + ks*4 + g;
                bm[mt] = *reinterpret_cast<const short8*>(Mid + r*512 + ((ch ^ (r & 7)) << 3));
            }
            #pragma unroll
            for (int ct = 0; ct < 2; ++ct)
                #pragma unroll
                for (int mt = 0; mt < 2; ++mt)
                    oacc[ct][mt] = __builtin_amdgcn_mfma_f32_16x16x32_bf16(aw[ct], bm[mt], oacc[ct][mt], 0, 0, 0);
        }
    }

    // epilogue B: bias + residual(Hres) + LN2 -> h, hb
    float vals[2][2][4];
    #pragma unroll
    for (int ct = 0; ct < 2; ++ct) {
        int colb = w*32 + ct*16 + g*4;
        float4 bb = *reinterpret_cast<const float4*>(b2v + colb);
        #pragma unroll
        for (int mt = 0; mt < 2; ++mt) {
            int rloc = mt*16 + n;
            float4 hres = *reinterpret_cast<const float4*>(&Hres[rloc*132 + colb]);
            vals[ct][mt][0] = oacc[ct][mt][0] + bb.x + hres.x;
            vals[ct][mt][1] = oacc[ct][mt][1] + bb.y + hres.y;
            vals[ct][mt][2] = oacc[ct][mt][2] + bb.z + hres.z;
            vals[ct][mt][3] = oacc[ct][mt][3] + bb.w + hres.w;
        }
    }
    __syncthreads();                           // red[] reuse safe
    #pragma unroll
    for (int mt = 0; mt < 2; ++mt) {
        float s = 0.f, s2 = 0.f;
        #pragma unroll
        for (int ct = 0; ct < 2; ++ct)
            #pragma unroll
            for (int r4 = 0; r4 < 4; ++r4) { float v = vals[ct][mt][r4]; s += v; s2 += v*v; }
        s  += __shfl_xor(s, 16);  s  += __shfl_xor(s, 32);
        s2 += __shfl_xor(s2, 16); s2 += __shfl_xor(s2, 32);
        if (g == 0) { red[w][mt*16 + n][0] = s; red[w][mt*16 + n][1] = s2; }
    }
    __syncthreads();
    if (tid < 32) {
        float s = 0.f, s2 = 0.f;
        #pragma unroll
        for (int ww = 0; ww < 4; ++ww) { s += red[ww][tid][0]; s2 += red[ww][tid][1]; }
        float mean = s * (1.f/128.f);
        float var  = s2 * (1.f/128.f) - mean*mean;
        stats[tid][0] = mean;
        stats[tid][1] = rsqrtf(var + 1e-5f);
    }
    __syncthreads();
    #pragma unroll
    for (int ct = 0; ct < 2; ++ct) {
        int colb = w*32 + ct*16 + g*4;
        float4 gv = *reinterpret_cast<const float4*>(ln2g + colb);
        float4 bv = *reinterpret_cast<const float4*>(ln2b + colb);
        #pragma unroll
        for (int mt = 0; mt < 2; ++mt) {
            int rloc = mt*16 + n;
            int mrow = row0 + rloc;
            float mean = stats[rloc][0], rstd = stats[rloc][1];
            float y0 = (vals[ct][mt][0] - mean) * rstd * gv.x + bv.x;
            float y1 = (vals[ct][mt][1] - mean) * rstd * gv.y + bv.y;
            float y2 = (vals[ct][mt][2] - mean) * rstd * gv.z + bv.z;
            float y3 = (vals[ct][mt][3] - mean) * rstd * gv.w + bv.w;
            float4 yo = {y0, y1, y2, y3};
            *reinterpret_cast<float4*>(h + (size_t)mrow*DIM + colb) = yo;
            uint2 pk;
            pk.x = pkbf16(y0, y1);
            pk.y = pkbf16(y2, y3);
            *reinterpret_cast<uint2*>(hb + (size_t)mrow*DIM + colb) = pk;
        }
    }
}

// ---------------- mean-pool + LN + classifier ----------------
__global__ __launch_bounds__(128) void final_kernel(
    const float* __restrict__ h, const float* __restrict__ g,
    const float* __restrict__ bt, const float* __restrict__ cls_w,
    const float* __restrict__ cls_b, float* __restrict__ out)
{
    int b = blockIdx.x, d = threadIdx.x;
    float s = 0.f;
    for (int t = 0; t < TT; ++t) s += h[((size_t)b*TT + t)*DIM + d];
    float pooled = s * (1.f / TT);
    __shared__ float sm[4];
    float v1 = pooled, v2 = pooled * pooled;
    #pragma unroll
    for (int off = 1; off < 64; off <<= 1) { v1 += __shfl_xor(v1, off); v2 += __shfl_xor(v2, off); }
    int wave = threadIdx.x >> 6, lane = threadIdx.x & 63;
    if (lane == 0) { sm[wave*2] = v1; sm[wave*2+1] = v2; }
    __syncthreads();
    float mean = (sm[0] + sm[2]) * (1.f/128.f);
    float var  = (sm[1] + sm[3]) * (1.f/128.f) - mean*mean;
    float xn = (pooled - mean) * rsqrtf(var + 1e-5f) * g[d] + bt[d];
    __shared__ float px[DIM];
    px[d] = xn;
    __syncthreads();
    if (d < NCLS_) {
        float a = cls_b[d];
        for (int i = 0; i < DIM; ++i) a = fmaf(px[i], cls_w[i*NCLS_ + d], a);
        out[b*NCLS_ + d] = a;
    }
}

// ---------------- host ----------------
extern "C" void kernel_launch(void* const* d_in, const int* in_sizes, int n_in,
                              void* d_out, int out_size, void* d_ws, size_t ws_size,
                              hipStream_t stream)
{
    (void)in_sizes; (void)n_in; (void)out_size; (void)ws_size;
    const float* x1      = (const float*)d_in[0];
    const float* proj_w  = (const float*)d_in[1];
    const float* proj_b  = (const float*)d_in[2];
    const float* queries = (const float*)d_in[3];
    const float* fc_w    = (const float*)d_in[4];
    const float* fc_b    = (const float*)d_in[5];
    const float* embed_w = (const float*)d_in[6];
    const float* embed_b = (const float*)d_in[7];
    const float* wqkv    = (const float*)d_in[8];
    const float* bqkv    = (const float*)d_in[9];
    const float* wo      = (const float*)d_in[10];
    const float* bo      = (const float*)d_in[11];
    const float* w1      = (const float*)d_in[12];
    const float* b1      = (const float*)d_in[13];
    const float* w2      = (const float*)d_in[14];
    const float* b2      = (const float*)d_in[15];
    const float* ln1_g   = (const float*)d_in[16];
    const float* ln1_b   = (const float*)d_in[17];
    const float* ln2_g   = (const float*)d_in[18];
    const float* ln2_b   = (const float*)d_in[19];
    const float* rel_t   = (const float*)d_in[20];
    const float* final_g = (const float*)d_in[21];
    const float* final_b = (const float*)d_in[22];
    const float* cls_w   = (const float*)d_in[23];
    const float* cls_b   = (const float*)d_in[24];

    float* ws     = (float*)d_ws;
    float* h      = ws;                                    // MM*128 f32
    ushort_t* hb    = (ushort_t*)(h + (size_t)MM*DIM);     // MM*128 bf16
    ushort_t* qkvb  = hb    + (size_t)MM*DIM;              // MM*384 bf16
    ushort_t* attno = qkvb  + (size_t)MM*384;              // MM*128 bf16
    ushort_t* wts   = attno + (size_t)MM*DIM;              // 1179648 bf16
    float* alpha  = (float*)(wts + 1179648);               // 16
    float* Emat   = alpha + 16;                            // 10*128
    float* c0     = Emat + QOUT_*DIM;                      // 128

    enc_pre_kernel<<<1, 128, 0, stream>>>(proj_w, proj_b, queries, fc_w, fc_b,
                                          embed_w, embed_b, alpha, Emat, c0);
    wtrans_kernel<<<288, 256, 0, stream>>>(wqkv, wo, w1, w2, wts);
    enc_kernel<<<MM, 64, 0, stream>>>(x1, alpha, Emat, c0, h, hb);

    for (int l = 0; l < NL; ++l) {
        const ushort_t* wqkv_t = wts + (size_t)l*49152;
        const ushort_t* wo_t   = wts + 294912 + (size_t)l*16384;
        const ushort_t* w1_t   = wts + 393216 + (size_t)l*65536;
        const ushort_t* w2_t   = wts + 786432 + (size_t)l*65536;

        gemm_mfma_kernel<128><<<dim3(384/64, MM/128), 256, 0, stream>>>(
            hb, wqkv_t, bqkv + l*3*DIM, qkvb, 384, DIM, 0, 1);
        attn_mfma_kernel<<<BB*NHEADS*4, 512, 0, stream>>>(
            qkvb, rel_t + l*RELLEN, attno);
        pa_kernel<<<MM/32, 256, 0, stream>>>(
            attno, wo_t, bo + l*DIM, w1_t, w2_t, b1 + l*FFD, b2 + l*DIM,
            h, hb, ln1_g + l*DIM, ln1_b + l*DIM, ln2_g + l*DIM, ln2_b + l*DIM);
    }

    final_kernel<<<BB, 128, 0, stream>>>(h, final_g, final_b, cls_w, cls_b, (float*)d_out);
}

// Round 10
// 397.485 us; speedup vs baseline: 1.4708x; 1.4708x over previous
//
#include <hip/hip_runtime.h>
#include <hip/hip_bf16.h>
#include <cmath>

#define NL      6
#define NHEADS  4
#define DIM     128
#define FFD     512
#define CMID_   8
#define COUT_   16
#define QOUT_   10
#define MAXLEN_ 512
#define NCLS_   3
#define BB      32
#define TT      500
#define FIN_    232
#define MM      (BB*TT)
#define HD      32
#define RELLEN  (2*MAXLEN_-1)
#define LOG2E   1.4426950408889634f

typedef __attribute__((ext_vector_type(8))) short short8;
typedef __attribute__((ext_vector_type(4))) float f32x4;
typedef unsigned short ushort_t;

__device__ inline unsigned bf16r(float x) {   // RNE float->bf16 bits (finite inputs)
    unsigned u = __float_as_uint(x);
    return (u + 0x7fffu + ((u >> 16) & 1u)) >> 16;
}

// paired RNE pack via HW v_cvt_pk_bf16_f32
__device__ inline unsigned pkbf16(float a, float b) {
    __hip_bfloat162 h2 = __float22bfloat162_rn(float2{a, b});
    return *reinterpret_cast<unsigned*>(&h2);
}

// async 16B global->LDS DMA: per-lane global src, wave-uniform LDS base + lane*16
__device__ inline void gload16(const ushort_t* g, ushort_t* l) {
    __builtin_amdgcn_global_load_lds(
        (const __attribute__((address_space(1))) unsigned*)g,
        (__attribute__((address_space(3))) unsigned*)l, 16, 0, 0);
}

// ---------------- encoder precompute (1 block) ----------------
__global__ __launch_bounds__(128) void enc_pre_kernel(
    const float* __restrict__ proj_w, const float* __restrict__ proj_b,
    const float* __restrict__ queries, const float* __restrict__ fc_w,
    const float* __restrict__ fc_b, const float* __restrict__ embed_w,
    const float* __restrict__ embed_b,
    float* __restrict__ alpha, float* __restrict__ E, float* __restrict__ c0)
{
    __shared__ float pw[CMID_], cb[CMID_], gam[COUT_], del[COUT_];
    int t = threadIdx.x;
    if (t < CMID_) { pw[t] = proj_w[t]; cb[t] = proj_b[t] + ((t & 1) ? 1.f : 0.f); }
    __syncthreads();
    if (t < QOUT_) {
        float a = 0.f;
        for (int c = 0; c < CMID_; ++c) a += pw[c] * queries[t*CMID_ + c];
        alpha[t] = a;
    }
    if (t < COUT_) {
        float gg = 0.f, dd = 0.f;
        for (int c = 0; c < CMID_; ++c) {
            gg += pw[c] * fc_w[c*COUT_ + t];
            dd += cb[c] * fc_w[c*COUT_ + t];
        }
        gam[t] = gg; del[t] = dd + fc_b[t];
    }
    __syncthreads();
    for (int i = t; i < QOUT_*DIM; i += 128) {
        int q = i / DIM, d = i % DIM;
        float e = 0.f;
        for (int o = 0; o < COUT_; ++o) e += gam[o] * embed_w[(o*QOUT_ + q)*DIM + d];
        E[i] = e;
    }
    {
        float c = embed_b[t];
        for (int o = 0; o < COUT_; ++o) {
            float dl = del[o];
            for (int q = 0; q < QOUT_; ++q) c += dl * embed_w[(o*QOUT_ + q)*DIM + t];
        }
        c0[t] = c;
    }
}

// ---------------- encoder main ----------------
__global__ __launch_bounds__(64) void enc_kernel(
    const float* __restrict__ x1, const float* __restrict__ alpha,
    const float* __restrict__ E, const float* __restrict__ c0,
    float* __restrict__ h, ushort_t* __restrict__ hb)
{
    int bt = blockIdx.x;
    int lane = threadIdx.x;
    const float* xr = x1 + (size_t)bt * FIN_;
    float xv[4];
    bool vld[4];
    #pragma unroll
    for (int i = 0; i < 4; ++i) {
        int f = lane + (i << 6);
        vld[i] = (f < FIN_);
        xv[i] = vld[i] ? xr[f] : 0.f;
    }
    float vmax = -INFINITY, vmin = INFINITY;
    #pragma unroll
    for (int i = 0; i < 4; ++i) if (vld[i]) { vmax = fmaxf(vmax, xv[i]); vmin = fminf(vmin, xv[i]); }
    #pragma unroll
    for (int off = 1; off < 64; off <<= 1) {
        vmax = fmaxf(vmax, __shfl_xor(vmax, off));
        vmin = fminf(vmin, __shfl_xor(vmin, off));
    }
    float mq[QOUT_];
    for (int q = 0; q < QOUT_; ++q) {
        float a = alpha[q];
        float Mx = (a >= 0.f) ? a * vmax : a * vmin;
        float se = 0.f, sx = 0.f;
        #pragma unroll
        for (int i = 0; i < 4; ++i) if (vld[i]) {
            float e = __expf(fmaf(a, xv[i], -Mx));
            se += e; sx += e * xv[i];
        }
        #pragma unroll
        for (int off = 1; off < 64; off <<= 1) { se += __shfl_xor(se, off); sx += __shfl_xor(sx, off); }
        mq[q] = sx / se;
    }
    #pragma unroll
    for (int k = 0; k < 2; ++k) {
        int d = lane + (k << 6);
        float hv = c0[d];
        #pragma unroll
        for (int q = 0; q < QOUT_; ++q) hv = fmaf(mq[q], E[q*DIM + d], hv);
        h[(size_t)bt*DIM + d] = hv;
        hb[(size_t)bt*DIM + d] = (ushort_t)bf16r(hv);
    }
}

// ---------------- weight transpose + bf16 convert (once per launch) ----------------
__global__ __launch_bounds__(256) void wtrans_kernel(
    const float* __restrict__ wqkv, const float* __restrict__ wo,
    const float* __restrict__ w1, const float* __restrict__ w2,
    ushort_t* __restrict__ wts)
{
    int bid = blockIdx.x;
    const float* W; ushort_t* Wt; int K, N, tk, tn;
    if (bid < 72) {            // wqkv: K=128,N=384 -> 2x6 tiles x 6 layers
        int l = bid / 12, t = bid % 12; tk = t / 6; tn = t % 6; K = 128; N = 384;
        W = wqkv + (size_t)l*128*384; Wt = wts + (size_t)l*49152;
    } else if (bid < 96) {     // wo: 128x128 -> 2x2 x 6
        int q = bid - 72; int l = q / 4, t = q % 4; tk = t / 2; tn = t % 2; K = 128; N = 128;
        W = wo + (size_t)l*16384; Wt = wts + 294912 + (size_t)l*16384;
    } else if (bid < 192) {    // w1: K=128,N=512 -> 2x8 x 6
        int q = bid - 96; int l = q / 16, t = q % 16; tk = t / 8; tn = t % 8; K = 128; N = 512;
        W = w1 + (size_t)l*65536; Wt = wts + 393216 + (size_t)l*65536;
    } else {                   // w2: K=512,N=128 -> 8x2 x 6
        int q = bid - 192; int l = q / 16, t = q % 16; tk = t / 2; tn = t % 2; K = 512; N = 128;
        W = w2 + (size_t)l*65536; Wt = wts + 786432 + (size_t)l*65536;
    }
    int k0 = tk << 6, n0 = tn << 6;
    __shared__ float Ls[64][65];
    int tid = threadIdx.x;
    #pragma unroll
    for (int i = 0; i < 4; ++i) {
        int id = tid + 256*i;
        int r = id >> 4, ch = id & 15;
        float4 v = *reinterpret_cast<const float4*>(W + (size_t)(k0+r)*N + n0 + ch*4);
        Ls[ch*4+0][r] = v.x; Ls[ch*4+1][r] = v.y; Ls[ch*4+2][r] = v.z; Ls[ch*4+3][r] = v.w;
    }
    __syncthreads();
    #pragma unroll
    for (int i = 0; i < 4; ++i) {
        int id = tid + 256*i;
        int rr = id >> 4, ch = id & 15;
        uint2 o2;
        o2.x = pkbf16(Ls[rr][ch*4+0], Ls[rr][ch*4+1]);
        o2.y = pkbf16(Ls[rr][ch*4+2], Ls[rr][ch*4+3]);
        *reinterpret_cast<uint2*>(Wt + (size_t)(n0+rr)*K + k0 + ch*4) = o2;
    }
}

// ---------------- bf16 MFMA GEMM (qkv projection), global_load_lds staging ----------
template<int BM>
__global__ __launch_bounds__(256) void gemm_mfma_kernel(
    const ushort_t* __restrict__ A, const ushort_t* __restrict__ Wt,
    const float* __restrict__ bias, void* __restrict__ C,
    int N, int K, int relu, int obf16)
{
    constexpr int MREP = BM / 32;
    constexpr int ASEG = BM / 32;              // A segs per wave (1024B each)
    __shared__ __align__(16) ushort_t As[BM * 64];
    __shared__ __align__(16) ushort_t Bs[64 * 64];
    const int tid = threadIdx.x;
    const int row0 = blockIdx.y * BM, col0 = blockIdx.x << 6;
    const int w = tid >> 6, lane = tid & 63, g = lane >> 4, n = lane & 15;
    const int wr = w & 1, wc = w >> 1;
    f32x4 acc[MREP][2];
    #pragma unroll
    for (int mt = 0; mt < MREP; ++mt)
        #pragma unroll
        for (int nt = 0; nt < 2; ++nt) acc[mt][nt] = (f32x4){0.f,0.f,0.f,0.f};

    for (int k0 = 0; k0 < K; k0 += 64) {
        __syncthreads();
        #pragma unroll
        for (int j = 0; j < ASEG; ++j) {       // A: BM*8 chunks, linear LDS + swz src
            int seg = w*ASEG + j;
            int id = seg*64 + lane;
            int r = id >> 3, cp = id & 7;
            gload16(A + (size_t)(row0 + r)*K + k0 + ((cp ^ (r & 7)) << 3),
                    As + seg*512);
        }
        #pragma unroll
        for (int j = 0; j < 2; ++j) {          // B: 512 chunks
            int seg = w*2 + j;
            int id = seg*64 + lane;
            int r = id >> 3, cp = id & 7;
            gload16(Wt + (size_t)(col0 + r)*K + k0 + ((cp ^ (r & 7)) << 3),
                    Bs + seg*512);
        }
        __syncthreads();
        #pragma unroll
        for (int ks = 0; ks < 2; ++ks) {
            short8 af[MREP], bfr[2];
            #pragma unroll
            for (int mt = 0; mt < MREP; ++mt) {
                int r = wr*(BM/2) + mt*16 + n;
                af[mt] = *reinterpret_cast<const short8*>(As + r*64 + (((ks*4 + g) ^ (r & 7)) << 3));
            }
            #pragma unroll
            for (int nt = 0; nt < 2; ++nt) {
                int r = wc*32 + nt*16 + n;
                bfr[nt] = *reinterpret_cast<const short8*>(Bs + r*64 + (((ks*4 + g) ^ (r & 7)) << 3));
            }
            #pragma unroll
            for (int mt = 0; mt < MREP; ++mt)
                #pragma unroll
                for (int nt = 0; nt < 2; ++nt)
                    acc[mt][nt] = __builtin_amdgcn_mfma_f32_16x16x32_bf16(af[mt], bfr[nt], acc[mt][nt], 0, 0, 0);
        }
    }
    #pragma unroll
    for (int mt = 0; mt < MREP; ++mt) {
        #pragma unroll
        for (int nt = 0; nt < 2; ++nt) {
            int col = col0 + wc*32 + nt*16 + n;
            float bv = bias[col];
            #pragma unroll
            for (int r4 = 0; r4 < 4; ++r4) {
                int row = row0 + wr*(BM/2) + mt*16 + g*4 + r4;
                float v = acc[mt][nt][r4] + bv;
                if (relu) v = fmaxf(v, 0.f);
                if (obf16) ((ushort_t*)C)[(size_t)row*N + col] = (ushort_t)bf16r(v);
                else       ((float*)C)[(size_t)row*N + col] = v;
            }
        }
    }
}

// ---------------- MFMA bf16 flash attention (QBLK=128, KVBLK=64, exp2) ----------------
// grid: B*NHEADS*4 blocks, 512 threads = 8 waves x 16 q-rows each.
__global__ __launch_bounds__(512) void attn_mfma_kernel(
    const ushort_t* __restrict__ qkv, const float* __restrict__ rel,
    ushort_t* __restrict__ o)
{
    __shared__ __align__(16) ushort_t Ks[64][40];          // [kcol][dim] 80B rows
    __shared__ __align__(16) ushort_t Vs[64][36];          // [kcol][dim] 72B rows
    __shared__ __align__(16) ushort_t VB[2][2][4][16][8];  // [kchalf][dimhalf][g][n][j]
    __shared__ float rl[RELLEN];
    const int bid = blockIdx.x;
    const int qt = bid & 3;
    const int bh = bid >> 2;
    const int hh = bh & 3, b = bh >> 2;
    const int tid  = threadIdx.x;
    const int w    = tid >> 6;
    const int lane = tid & 63;
    const int g = lane >> 4, n = lane & 15;
    for (int i = tid; i < RELLEN; i += 512) rl[i] = rel[i] * LOG2E;

    const int qrow = (qt << 7) + (w << 4) + n;
    const bool qv = (qrow < TT);
    short8 qf = {0,0,0,0,0,0,0,0};
    if (qv) qf = *reinterpret_cast<const short8*>(qkv + (size_t)(b*TT + qrow)*384 + hh*HD + g*8);

    f32x4 acc0 = {0.f,0.f,0.f,0.f}, acc1 = {0.f,0.f,0.f,0.f};
    float m = -INFINITY, lsum = 0.f;
    const float scale2 = 0.17677669529663687f * LOG2E;
    const f32x4 zf = {0.f,0.f,0.f,0.f};

    const int sr = tid >> 3, sc = tid & 7;      // stage: 64 rows x 8 chunks of 8B

    auto tile = [&](const int kt, const bool domask) {
        const int k0 = kt << 6;
        __syncthreads();                        // prev tile fully consumed
        {
            int t = k0 + sr;
            uint2 kvv = make_uint2(0,0), vvv = make_uint2(0,0);
            if (!domask || t < TT) {
                const ushort_t* bp = qkv + (size_t)(b*TT + t)*384 + hh*HD + sc*4;
                kvv = *reinterpret_cast<const uint2*>(bp + 128);
                vvv = *reinterpret_cast<const uint2*>(bp + 256);
            }
            *reinterpret_cast<uint2*>(&Ks[sr][sc*4]) = kvv;
            *reinterpret_cast<uint2*>(&Vs[sr][sc*4]) = vvv;
        }
        __syncthreads();

        // V relayout into fragment-linear VB (4 elems/thread, 512 threads)
        {
            int jh = (tid & 1)*4, nn = (tid >> 1) & 15, gg = (tid >> 5) & 3;
            int dh = (tid >> 7) & 1, kch = (tid >> 8) & 1;
            ushort_t tmp[4];
            #pragma unroll
            for (int j = 0; j < 4; ++j) tmp[j] = Vs[kch*32 + gg*8 + jh + j][dh*16 + nn];
            *reinterpret_cast<uint2*>(&VB[kch][dh][gg][nn][jh]) = *reinterpret_cast<uint2*>(tmp);
        }

        // S^T = K . Q^T : 4 tiles of 16 kcols (per wave)
        f32x4 s[4];
        #pragma unroll
        for (int c = 0; c < 4; ++c) {
            short8 ak = *reinterpret_cast<const short8*>(&Ks[c*16 + n][g*8]);
            s[c] = __builtin_amdgcn_mfma_f32_16x16x32_bf16(ak, qf, zf, 0, 0, 0);
        }

        float sv[16];
        float tmax = -INFINITY;
        #pragma unroll
        for (int c = 0; c < 4; ++c)
            #pragma unroll
            for (int r = 0; r < 4; ++r) {
                int kc = k0 + c*16 + g*4 + r;
                float bia = rl[kc - qrow + (MAXLEN_-1)];
                float v = fmaf(s[c][r], scale2, bia);
                if (domask && kc >= TT) v = -1e30f;
                sv[c*4 + r] = v;
                tmax = fmaxf(tmax, v);
            }
        tmax = fmaxf(tmax, __shfl_xor(tmax, 16));
        tmax = fmaxf(tmax, __shfl_xor(tmax, 32));
        float mnew = fmaxf(m, tmax);
        float corr = exp2f(m - mnew);
        m = mnew;
        float ps = 0.f;
        #pragma unroll
        for (int r = 0; r < 16; ++r) { float e = exp2f(sv[r] - mnew); sv[r] = e; ps += e; }
        ps += __shfl_xor(ps, 16);
        ps += __shfl_xor(ps, 32);
        lsum = fmaf(lsum, corr, ps);

        int src0 = n + ((g & 1) << 5);
        int src1 = src0 + 16;
        int t0 = (g < 2);
        union { unsigned wd[4]; short8 v; } PA, PB;
        {
            unsigned pk0lo = pkbf16(sv[0], sv[1]);
            unsigned pk0hi = pkbf16(sv[2], sv[3]);
            unsigned pk1lo = pkbf16(sv[4], sv[5]);
            unsigned pk1hi = pkbf16(sv[6], sv[7]);
            unsigned a0 = __shfl((int)pk0lo, src0), c0_ = __shfl((int)pk1lo, src0);
            unsigned a1 = __shfl((int)pk0hi, src0), c1_ = __shfl((int)pk1hi, src0);
            unsigned a2 = __shfl((int)pk0lo, src1), c2_ = __shfl((int)pk1lo, src1);
            unsigned a3 = __shfl((int)pk0hi, src1), c3_ = __shfl((int)pk1hi, src1);
            PA.wd[0] = t0 ? a0 : c0_; PA.wd[1] = t0 ? a1 : c1_;
            PA.wd[2] = t0 ? a2 : c2_; PA.wd[3] = t0 ? a3 : c3_;
        }
        {
            unsigned pk0lo = pkbf16(sv[8],  sv[9]);
            unsigned pk0hi = pkbf16(sv[10], sv[11]);
            unsigned pk1lo = pkbf16(sv[12], sv[13]);
            unsigned pk1hi = pkbf16(sv[14], sv[15]);
            unsigned a0 = __shfl((int)pk0lo, src0), c0_ = __shfl((int)pk1lo, src0);
            unsigned a1 = __shfl((int)pk0hi, src0), c1_ = __shfl((int)pk1hi, src0);
            unsigned a2 = __shfl((int)pk0lo, src1), c2_ = __shfl((int)pk1lo, src1);
            unsigned a3 = __shfl((int)pk0hi, src1), c3_ = __shfl((int)pk1hi, src1);
            PB.wd[0] = t0 ? a0 : c0_; PB.wd[1] = t0 ? a1 : c1_;
            PB.wd[2] = t0 ? a2 : c2_; PB.wd[3] = t0 ? a3 : c3_;
        }

        short8 a00 = *reinterpret_cast<const short8*>(&VB[0][0][g][n][0]);
        short8 a01 = *reinterpret_cast<const short8*>(&VB[0][1][g][n][0]);
        short8 a10 = *reinterpret_cast<const short8*>(&VB[1][0][g][n][0]);
        short8 a11 = *reinterpret_cast<const short8*>(&VB[1][1][g][n][0]);
        #pragma unroll
        for (int r = 0; r < 4; ++r) { acc0[r] *= corr; acc1[r] *= corr; }
        acc0 = __builtin_amdgcn_mfma_f32_16x16x32_bf16(a00, PA.v, acc0, 0, 0, 0);
        acc0 = __builtin_amdgcn_mfma_f32_16x16x32_bf16(a10, PB.v, acc0, 0, 0, 0);
        acc1 = __builtin_amdgcn_mfma_f32_16x16x32_bf16(a01, PA.v, acc1, 0, 0, 0);
        acc1 = __builtin_amdgcn_mfma_f32_16x16x32_bf16(a11, PB.v, acc1, 0, 0, 0);
    };

    for (int kt = 0; kt < 7; ++kt) tile(kt, false);   // kcols 0..447 < 500
    tile(7, true);                                    // kcols 448..511 masked

    if (qv) {
        float inv = 1.f / lsum;
        uint2 p0, p1;
        p0.x = pkbf16(acc0[0]*inv, acc0[1]*inv);
        p0.y = pkbf16(acc0[2]*inv, acc0[3]*inv);
        p1.x = pkbf16(acc1[0]*inv, acc1[1]*inv);
        p1.y = pkbf16(acc1[2]*inv, acc1[3]*inv);
        ushort_t* op = o + (size_t)(b*TT + qrow)*DIM + hh*HD + g*4;
        *reinterpret_cast<uint2*>(op)      = p0;
        *reinterpret_cast<uint2*>(op + 16) = p1;
    }
}

// ---------------- fused post-attention: wo GEMM + LN1 + FFN + LN2 (DMA staging) ------
__global__ __launch_bounds__(256) void pa_kernel(
    const ushort_t* __restrict__ attno, const ushort_t* __restrict__ wot,
    const float* __restrict__ bo, const ushort_t* __restrict__ W1t,
    const ushort_t* __restrict__ W2t, const float* __restrict__ b1v,
    const float* __restrict__ b2v, float* __restrict__ h, ushort_t* __restrict__ hb,
    const float* __restrict__ ln1g, const float* __restrict__ ln1b,
    const float* __restrict__ ln2g, const float* __restrict__ ln2b)
{
    __shared__ __align__(16) ushort_t As[32 * 128];     // 8 KB: attno tile, then LN1 bf16
    __shared__ __align__(16) ushort_t Wbuf[8192];       // 16 KB weight chunk
    __shared__ __align__(16) ushort_t Mid[32 * 512];    // 32 KB
    __shared__ float Hres[32 * 132];                    // 16.9 KB, padded rows
    __shared__ float red[4][32][2];
    __shared__ float stats[32][2];
    const int tid = threadIdx.x;
    const int row0 = blockIdx.x << 5;
    const int w = tid >> 6, lane = tid & 63, g = lane >> 4, n = lane & 15;

    // stage attno tile (32 x 128 = 512 chunks): linear LDS dest + swizzled source
    #pragma unroll
    for (int j = 0; j < 2; ++j) {
        int seg = w*2 + j;
        int id = seg*64 + lane;
        int r = id >> 4, cp = id & 15;
        gload16(attno + (size_t)(row0 + r)*DIM + ((cp ^ (r & 7)) << 3),
                As + seg*512);
    }

    // ---- phase A: wo GEMM (K=128) ----
    f32x4 acc[2][2];
    #pragma unroll
    for (int a = 0; a < 2; ++a)
        #pragma unroll
        for (int b = 0; b < 2; ++b) acc[a][b] = (f32x4){0.f,0.f,0.f,0.f};
    #pragma unroll
    for (int k0 = 0; k0 < 128; k0 += 64) {
        __syncthreads();
        #pragma unroll
        for (int j = 0; j < 4; ++j) {          // Wbuf[128 n][64 k] = 1024 chunks
            int seg = w*4 + j;
            int id = seg*64 + lane;
            int r = id >> 3, cp = id & 7;
            gload16(wot + (size_t)r*DIM + k0 + ((cp ^ (r & 7)) << 3),
                    Wbuf + seg*512);
        }
        __syncthreads();
        #pragma unroll
        for (int ks = 0; ks < 2; ++ks) {
            short8 af[2], bfr[2];
            #pragma unroll
            for (int mt = 0; mt < 2; ++mt) {
                int r = mt*16 + n;
                int ch = (k0 >> 3) + ks*4 + g;
                af[mt] = *reinterpret_cast<const short8*>(As + r*128 + ((ch ^ (r & 7)) << 3));
            }
            #pragma unroll
            for (int nt = 0; nt < 2; ++nt) {
                int r = w*32 + nt*16 + n;
                bfr[nt] = *reinterpret_cast<const short8*>(Wbuf + r*64 + (((ks*4 + g) ^ (r & 7)) << 3));
            }
            #pragma unroll
            for (int mt = 0; mt < 2; ++mt)
                #pragma unroll
                for (int nt = 0; nt < 2; ++nt)
                    acc[mt][nt] = __builtin_amdgcn_mfma_f32_16x16x32_bf16(af[mt], bfr[nt], acc[mt][nt], 0, 0, 0);
        }
    }
    // epilogue A: bias + residual + LN1 -> Hres (f32) + As (bf16)
    {
        float vals[2][2][4];
        #pragma unroll
        for (int nt = 0; nt < 2; ++nt) {
            int col = w*32 + nt*16 + n;
            float bv = bo[col];
            #pragma unroll
            for (int mt = 0; mt < 2; ++mt)
                #pragma unroll
                for (int r4 = 0; r4 < 4; ++r4) {
                    int row = row0 + mt*16 + g*4 + r4;
                    vals[mt][nt][r4] = acc[mt][nt][r4] + bv + h[(size_t)row*DIM + col];
                }
        }
        #pragma unroll
        for (int mt = 0; mt < 2; ++mt)
            #pragma unroll
            for (int r4 = 0; r4 < 4; ++r4) {
                float s  = vals[mt][0][r4] + vals[mt][1][r4];
                float s2 = vals[mt][0][r4]*vals[mt][0][r4] + vals[mt][1][r4]*vals[mt][1][r4];
                #pragma unroll
                for (int off = 1; off < 16; off <<= 1) {
                    s  += __shfl_xor(s, off);
                    s2 += __shfl_xor(s2, off);
                }
                if (n == 0) { red[w][mt*16 + g*4 + r4][0] = s; red[w][mt*16 + g*4 + r4][1] = s2; }
            }
        __syncthreads();
        if (tid < 32) {
            float s = 0.f, s2 = 0.f;
            #pragma unroll
            for (int ww = 0; ww < 4; ++ww) { s += red[ww][tid][0]; s2 += red[ww][tid][1]; }
            float mean = s * (1.f/128.f);
            float var  = s2 * (1.f/128.f) - mean*mean;
            stats[tid][0] = mean;
            stats[tid][1] = rsqrtf(var + 1e-5f);
        }
        __syncthreads();
        #pragma unroll
        for (int nt = 0; nt < 2; ++nt) {
            int col = w*32 + nt*16 + n;
            int ch = col >> 3, off8 = col & 7;
            float gv = ln1g[col], bv = ln1b[col];
            #pragma unroll
            for (int mt = 0; mt < 2; ++mt)
                #pragma unroll
                for (int r4 = 0; r4 < 4; ++r4) {
                    int rloc = mt*16 + g*4 + r4;
                    float y = (vals[mt][nt][r4] - stats[rloc][0]) * stats[rloc][1] * gv + bv;
                    Hres[rloc*132 + col] = y;
                    As[rloc*128 + ((ch ^ (rloc & 7)) << 3) + off8] = (ushort_t)bf16r(y);
                }
        }
    }

    // ---- phase B1: Mid = relu(As @ W1 + b1), 8 chunks of 64 k1-cols ----
    for (int cc = 0; cc < 8; ++cc) {
        __syncthreads();                        // Wbuf free + As writes visible (cc=0)
        #pragma unroll
        for (int j = 0; j < 4; ++j) {          // Wbuf[64 k1][128 k] = 1024 chunks
            int seg = w*4 + j;
            int id = seg*64 + lane;
            int r = id >> 4, cp = id & 15;
            gload16(W1t + (size_t)(cc*64 + r)*DIM + ((cp ^ (r & 7)) << 3),
                    Wbuf + seg*512);
        }
        __syncthreads();
        f32x4 acc1[2] = {{0.f,0.f,0.f,0.f},{0.f,0.f,0.f,0.f}};
        #pragma unroll
        for (int ks = 0; ks < 4; ++ks) {
            int rW = w*16 + n;
            short8 aw = *reinterpret_cast<const short8*>(Wbuf + rW*128 + (((ks*4 + g) ^ (rW & 7)) << 3));
            #pragma unroll
            for (int mt = 0; mt < 2; ++mt) {
                int rA = mt*16 + n;
                short8 bh_ = *reinterpret_cast<const short8*>(As + rA*128 + (((ks*4 + g) ^ (rA & 7)) << 3));
                acc1[mt] = __builtin_amdgcn_mfma_f32_16x16x32_bf16(aw, bh_, acc1[mt], 0, 0, 0);
            }
        }
        {
            int k1b = cc*64 + w*16 + g*4;
            float4 bb = *reinterpret_cast<const float4*>(b1v + k1b);
            int ch = k1b >> 3;
            int halfoff = (g & 1) * 4;
            #pragma unroll
            for (int mt = 0; mt < 2; ++mt) {
                int mrow = mt*16 + n;
                float v0 = fmaxf(acc1[mt][0] + bb.x, 0.f);
                float v1 = fmaxf(acc1[mt][1] + bb.y, 0.f);
                float v2 = fmaxf(acc1[mt][2] + bb.z, 0.f);
                float v3 = fmaxf(acc1[mt][3] + bb.w, 0.f);
                uint2 pk;
                pk.x = pkbf16(v0, v1);
                pk.y = pkbf16(v2, v3);
                *reinterpret_cast<uint2*>(Mid + mrow*512 + ((ch ^ (mrow & 7)) << 3) + halfoff) = pk;
            }
        }
    }

    // ---- phase B2: out = Mid @ W2, 8 chunks of 64 k1 ----
    f32x4 oacc[2][2];
    #pragma unroll
    for (int a = 0; a < 2; ++a)
        #pragma unroll
        for (int b = 0; b < 2; ++b) oacc[a][b] = (f32x4){0.f,0.f,0.f,0.f};
    for (int kc = 0; kc < 8; ++kc) {
        __syncthreads();                        // Wbuf free + Mid complete (kc=0)
        #pragma unroll
        for (int j = 0; j < 4; ++j) {          // Wbuf[128 c][64 k1] = 1024 chunks
            int seg = w*4 + j;
            int id = seg*64 + lane;
            int r = id >> 3, cp = id & 7;
            gload16(W2t + (size_t)r*FFD + kc*64 + ((cp ^ (r & 7)) << 3),
                    Wbuf + seg*512);
        }
        __syncthreads();
        #pragma unroll
        for (int ks = 0; ks < 2; ++ks) {
            short8 aw[2], bm[2];
            #pragma unroll
            for (int ct = 0; ct < 2; ++ct) {
                int r = w*32 + ct*16 + n;
                aw[ct] = *reinterpret_cast<const short8*>(Wbuf + r*64 + (((ks*4 + g) ^ (r & 7)) << 3));
            }
            #pragma unroll
            for (int mt = 0; mt < 2; ++mt) {
                int r = mt*16 + n;
                int ch = kc*8 + ks*4 + g;
                bm[mt] = *reinterpret_cast<const short8*>(Mid + r*512 + ((ch ^ (r & 7)) << 3));
            }
            #pragma unroll
            for (int ct = 0; ct < 2; ++ct)
                #pragma unroll
                for (int mt = 0; mt < 2; ++mt)
                    oacc[ct][mt] = __builtin_amdgcn_mfma_f32_16x16x32_bf16(aw[ct], bm[mt], oacc[ct][mt], 0, 0, 0);
        }
    }

    // epilogue B: bias + residual(Hres) + LN2 -> h, hb
    float vals[2][2][4];
    #pragma unroll
    for (int ct = 0; ct < 2; ++ct) {
        int colb = w*32 + ct*16 + g*4;
        float4 bb = *reinterpret_cast<const float4*>(b2v + colb);
        #pragma unroll
        for (int mt = 0; mt < 2; ++mt) {
            int rloc = mt*16 + n;
            float4 hres = *reinterpret_cast<const float4*>(&Hres[rloc*132 + colb]);
            vals[ct][mt][0] = oacc[ct][mt][0] + bb.x + hres.x;
            vals[ct][mt][1] = oacc[ct][mt][1] + bb.y + hres.y;
            vals[ct][mt][2] = oacc[ct][mt][2] + bb.z + hres.z;
            vals[ct][mt][3] = oacc[ct][mt][3] + bb.w + hres.w;
        }
    }
    __syncthreads();                           // red[] reuse safe
    #pragma unroll
    for (int mt = 0; mt < 2; ++mt) {
        float s = 0.f, s2 = 0.f;
        #pragma unroll
        for (int ct = 0; ct < 2; ++ct)
            #pragma unroll
            for (int r4 = 0; r4 < 4; ++r4) { float v = vals[ct][mt][r4]; s += v; s2 += v*v; }
        s  += __shfl_xor(s, 16);  s  += __shfl_xor(s, 32);
        s2 += __shfl_xor(s2, 16); s2 += __shfl_xor(s2, 32);
        if (g == 0) { red[w][mt*16 + n][0] = s; red[w][mt*16 + n][1] = s2; }
    }
    __syncthreads();
    if (tid < 32) {
        float s = 0.f, s2 = 0.f;
        #pragma unroll
        for (int ww = 0; ww < 4; ++ww) { s += red[ww][tid][0]; s2 += red[ww][tid][1]; }
        float mean = s * (1.f/128.f);
        float var  = s2 * (1.f/128.f) - mean*mean;
        stats[tid][0] = mean;
        stats[tid][1] = rsqrtf(var + 1e-5f);
    }
    __syncthreads();
    #pragma unroll
    for (int ct = 0; ct < 2; ++ct) {
        int colb = w*32 + ct*16 + g*4;
        float4 gv = *reinterpret_cast<const float4*>(ln2g + colb);
        float4 bv = *reinterpret_cast<const float4*>(ln2b + colb);
        #pragma unroll
        for (int mt = 0; mt < 2; ++mt) {
            int rloc = mt*16 + n;
            int mrow = row0 + rloc;
            float mean = stats[rloc][0], rstd = stats[rloc][1];
            float y0 = (vals[ct][mt][0] - mean) * rstd * gv.x + bv.x;
            float y1 = (vals[ct][mt][1] - mean) * rstd * gv.y + bv.y;
            float y2 = (vals[ct][mt][2] - mean) * rstd * gv.z + bv.z;
            float y3 = (vals[ct][mt][3] - mean) * rstd * gv.w + bv.w;
            float4 yo = {y0, y1, y2, y3};
            *reinterpret_cast<float4*>(h + (size_t)mrow*DIM + colb) = yo;
            uint2 pk;
            pk.x = pkbf16(y0, y1);
            pk.y = pkbf16(y2, y3);
            *reinterpret_cast<uint2*>(hb + (size_t)mrow*DIM + colb) = pk;
        }
    }
}

// ---------------- mean-pool + LN + classifier ----------------
__global__ __launch_bounds__(128) void final_kernel(
    const float* __restrict__ h, const float* __restrict__ g,
    const float* __restrict__ bt, const float* __restrict__ cls_w,
    const float* __restrict__ cls_b, float* __restrict__ out)
{
    int b = blockIdx.x, d = threadIdx.x;
    float s = 0.f;
    for (int t = 0; t < TT; ++t) s += h[((size_t)b*TT + t)*DIM + d];
    float pooled = s * (1.f / TT);
    __shared__ float sm[4];
    float v1 = pooled, v2 = pooled * pooled;
    #pragma unroll
    for (int off = 1; off < 64; off <<= 1) { v1 += __shfl_xor(v1, off); v2 += __shfl_xor(v2, off); }
    int wave = threadIdx.x >> 6, lane = threadIdx.x & 63;
    if (lane == 0) { sm[wave*2] = v1; sm[wave*2+1] = v2; }
    __syncthreads();
    float mean = (sm[0] + sm[2]) * (1.f/128.f);
    float var  = (sm[1] + sm[3]) * (1.f/128.f) - mean*mean;
    float xn = (pooled - mean) * rsqrtf(var + 1e-5f) * g[d] + bt[d];
    __shared__ float px[DIM];
    px[d] = xn;
    __syncthreads();
    if (d < NCLS_) {
        float a = cls_b[d];
        for (int i = 0; i < DIM; ++i) a = fmaf(px[i], cls_w[i*NCLS_ + d], a);
        out[b*NCLS_ + d] = a;
    }
}

// ---------------- host ----------------
extern "C" void kernel_launch(void* const* d_in, const int* in_sizes, int n_in,
                              void* d_out, int out_size, void* d_ws, size_t ws_size,
                              hipStream_t stream)
{
    (void)in_sizes; (void)n_in; (void)out_size; (void)ws_size;
    const float* x1      = (const float*)d_in[0];
    const float* proj_w  = (const float*)d_in[1];
    const float* proj_b  = (const float*)d_in[2];
    const float* queries = (const float*)d_in[3];
    const float* fc_w    = (const float*)d_in[4];
    const float* fc_b    = (const float*)d_in[5];
    const float* embed_w = (const float*)d_in[6];
    const float* embed_b = (const float*)d_in[7];
    const float* wqkv    = (const float*)d_in[8];
    const float* bqkv    = (const float*)d_in[9];
    const float* wo      = (const float*)d_in[10];
    const float* bo      = (const float*)d_in[11];
    const float* w1      = (const float*)d_in[12];
    const float* b1      = (const float*)d_in[13];
    const float* w2      = (const float*)d_in[14];
    const float* b2      = (const float*)d_in[15];
    const float* ln1_g   = (const float*)d_in[16];
    const float* ln1_b   = (const float*)d_in[17];
    const float* ln2_g   = (const float*)d_in[18];
    const float* ln2_b   = (const float*)d_in[19];
    const float* rel_t   = (const float*)d_in[20];
    const float* final_g = (const float*)d_in[21];
    const float* final_b = (const float*)d_in[22];
    const float* cls_w   = (const float*)d_in[23];
    const float* cls_b   = (const float*)d_in[24];

    float* ws     = (float*)d_ws;
    float* h      = ws;                                    // MM*128 f32
    ushort_t* hb    = (ushort_t*)(h + (size_t)MM*DIM);     // MM*128 bf16
    ushort_t* qkvb  = hb    + (size_t)MM*DIM;              // MM*384 bf16
    ushort_t* attno = qkvb  + (size_t)MM*384;              // MM*128 bf16
    ushort_t* wts   = attno + (size_t)MM*DIM;              // 1179648 bf16
    float* alpha  = (float*)(wts + 1179648);               // 16
    float* Emat   = alpha + 16;                            // 10*128
    float* c0     = Emat + QOUT_*DIM;                      // 128

    enc_pre_kernel<<<1, 128, 0, stream>>>(proj_w, proj_b, queries, fc_w, fc_b,
                                          embed_w, embed_b, alpha, Emat, c0);
    wtrans_kernel<<<288, 256, 0, stream>>>(wqkv, wo, w1, w2, wts);
    enc_kernel<<<MM, 64, 0, stream>>>(x1, alpha, Emat, c0, h, hb);

    for (int l = 0; l < NL; ++l) {
        const ushort_t* wqkv_t = wts + (size_t)l*49152;
        const ushort_t* wo_t   = wts + 294912 + (size_t)l*16384;
        const ushort_t* w1_t   = wts + 393216 + (size_t)l*65536;
        const ushort_t* w2_t   = wts + 786432 + (size_t)l*65536;

        gemm_mfma_kernel<128><<<dim3(384/64, MM/128), 256, 0, stream>>>(
            hb, wqkv_t, bqkv + l*3*DIM, qkvb, 384, DIM, 0, 1);
        attn_mfma_kernel<<<BB*NHEADS*4, 512, 0, stream>>>(
            qkvb, rel_t + l*RELLEN, attno);
        pa_kernel<<<MM/32, 256, 0, stream>>>(
            attno, wo_t, bo + l*DIM, w1_t, w2_t, b1 + l*FFD, b2 + l*DIM,
            h, hb, ln1_g + l*DIM, ln1_b + l*DIM, ln2_g + l*DIM, ln2_b + l*DIM);
    }

    final_kernel<<<BB, 128, 0, stream>>>(h, final_g, final_b, cls_w, cls_b, (float*)d_out);
}

// Round 11
// 381.991 us; speedup vs baseline: 1.5305x; 1.0406x over previous
//
#include <hip/hip_runtime.h>
#include <hip/hip_bf16.h>
#include <cmath>

#define NL      6
#define NHEADS  4
#define DIM     128
#define FFD     512
#define CMID_   8
#define COUT_   16
#define QOUT_   10
#define MAXLEN_ 512
#define NCLS_   3
#define BB      32
#define TT      500
#define FIN_    232
#define MM      (BB*TT)
#define HD      32
#define RELLEN  (2*MAXLEN_-1)
#define LOG2E   1.4426950408889634f

typedef __attribute__((ext_vector_type(8))) short short8;
typedef __attribute__((ext_vector_type(4))) float f32x4;
typedef unsigned short ushort_t;

__device__ inline unsigned bf16r(float x) {   // RNE float->bf16 bits (finite inputs)
    unsigned u = __float_as_uint(x);
    return (u + 0x7fffu + ((u >> 16) & 1u)) >> 16;
}

// paired RNE pack via HW v_cvt_pk_bf16_f32
__device__ inline unsigned pkbf16(float a, float b) {
    __hip_bfloat162 h2 = __float22bfloat162_rn(float2{a, b});
    return *reinterpret_cast<unsigned*>(&h2);
}

// async 16B global->LDS DMA: per-lane global src, wave-uniform LDS base + lane*16
__device__ inline void gload16(const ushort_t* g, ushort_t* l) {
    __builtin_amdgcn_global_load_lds(
        (const __attribute__((address_space(1))) unsigned*)g,
        (__attribute__((address_space(3))) unsigned*)l, 16, 0, 0);
}

// ---------------- encoder precompute (1 block) ----------------
__global__ __launch_bounds__(128) void enc_pre_kernel(
    const float* __restrict__ proj_w, const float* __restrict__ proj_b,
    const float* __restrict__ queries, const float* __restrict__ fc_w,
    const float* __restrict__ fc_b, const float* __restrict__ embed_w,
    const float* __restrict__ embed_b,
    float* __restrict__ alpha, float* __restrict__ E, float* __restrict__ c0)
{
    __shared__ float pw[CMID_], cb[CMID_], gam[COUT_], del[COUT_];
    int t = threadIdx.x;
    if (t < CMID_) { pw[t] = proj_w[t]; cb[t] = proj_b[t] + ((t & 1) ? 1.f : 0.f); }
    __syncthreads();
    if (t < QOUT_) {
        float a = 0.f;
        for (int c = 0; c < CMID_; ++c) a += pw[c] * queries[t*CMID_ + c];
        alpha[t] = a;
    }
    if (t < COUT_) {
        float gg = 0.f, dd = 0.f;
        for (int c = 0; c < CMID_; ++c) {
            gg += pw[c] * fc_w[c*COUT_ + t];
            dd += cb[c] * fc_w[c*COUT_ + t];
        }
        gam[t] = gg; del[t] = dd + fc_b[t];
    }
    __syncthreads();
    for (int i = t; i < QOUT_*DIM; i += 128) {
        int q = i / DIM, d = i % DIM;
        float e = 0.f;
        for (int o = 0; o < COUT_; ++o) e += gam[o] * embed_w[(o*QOUT_ + q)*DIM + d];
        E[i] = e;
    }
    {
        float c = embed_b[t];
        for (int o = 0; o < COUT_; ++o) {
            float dl = del[o];
            for (int q = 0; q < QOUT_; ++q) c += dl * embed_w[(o*QOUT_ + q)*DIM + t];
        }
        c0[t] = c;
    }
}

// ---------------- encoder main ----------------
__global__ __launch_bounds__(64) void enc_kernel(
    const float* __restrict__ x1, const float* __restrict__ alpha,
    const float* __restrict__ E, const float* __restrict__ c0,
    float* __restrict__ h, ushort_t* __restrict__ hb)
{
    int bt = blockIdx.x;
    int lane = threadIdx.x;
    const float* xr = x1 + (size_t)bt * FIN_;
    float xv[4];
    bool vld[4];
    #pragma unroll
    for (int i = 0; i < 4; ++i) {
        int f = lane + (i << 6);
        vld[i] = (f < FIN_);
        xv[i] = vld[i] ? xr[f] : 0.f;
    }
    float vmax = -INFINITY, vmin = INFINITY;
    #pragma unroll
    for (int i = 0; i < 4; ++i) if (vld[i]) { vmax = fmaxf(vmax, xv[i]); vmin = fminf(vmin, xv[i]); }
    #pragma unroll
    for (int off = 1; off < 64; off <<= 1) {
        vmax = fmaxf(vmax, __shfl_xor(vmax, off));
        vmin = fminf(vmin, __shfl_xor(vmin, off));
    }
    float mq[QOUT_];
    for (int q = 0; q < QOUT_; ++q) {
        float a = alpha[q];
        float Mx = (a >= 0.f) ? a * vmax : a * vmin;
        float se = 0.f, sx = 0.f;
        #pragma unroll
        for (int i = 0; i < 4; ++i) if (vld[i]) {
            float e = __expf(fmaf(a, xv[i], -Mx));
            se += e; sx += e * xv[i];
        }
        #pragma unroll
        for (int off = 1; off < 64; off <<= 1) { se += __shfl_xor(se, off); sx += __shfl_xor(sx, off); }
        mq[q] = sx / se;
    }
    #pragma unroll
    for (int k = 0; k < 2; ++k) {
        int d = lane + (k << 6);
        float hv = c0[d];
        #pragma unroll
        for (int q = 0; q < QOUT_; ++q) hv = fmaf(mq[q], E[q*DIM + d], hv);
        h[(size_t)bt*DIM + d] = hv;
        hb[(size_t)bt*DIM + d] = (ushort_t)bf16r(hv);
    }
}

// ---------------- weight transpose + bf16 convert (once per launch) ----------------
__global__ __launch_bounds__(256) void wtrans_kernel(
    const float* __restrict__ wqkv, const float* __restrict__ wo,
    const float* __restrict__ w1, const float* __restrict__ w2,
    ushort_t* __restrict__ wts)
{
    int bid = blockIdx.x;
    const float* W; ushort_t* Wt; int K, N, tk, tn;
    if (bid < 72) {            // wqkv: K=128,N=384 -> 2x6 tiles x 6 layers
        int l = bid / 12, t = bid % 12; tk = t / 6; tn = t % 6; K = 128; N = 384;
        W = wqkv + (size_t)l*128*384; Wt = wts + (size_t)l*49152;
    } else if (bid < 96) {     // wo: 128x128 -> 2x2 x 6
        int q = bid - 72; int l = q / 4, t = q % 4; tk = t / 2; tn = t % 2; K = 128; N = 128;
        W = wo + (size_t)l*16384; Wt = wts + 294912 + (size_t)l*16384;
    } else if (bid < 192) {    // w1: K=128,N=512 -> 2x8 x 6
        int q = bid - 96; int l = q / 16, t = q % 16; tk = t / 8; tn = t % 8; K = 128; N = 512;
        W = w1 + (size_t)l*65536; Wt = wts + 393216 + (size_t)l*65536;
    } else {                   // w2: K=512,N=128 -> 8x2 x 6
        int q = bid - 192; int l = q / 16, t = q % 16; tk = t / 2; tn = t % 2; K = 512; N = 128;
        W = w2 + (size_t)l*65536; Wt = wts + 786432 + (size_t)l*65536;
    }
    int k0 = tk << 6, n0 = tn << 6;
    __shared__ float Ls[64][65];
    int tid = threadIdx.x;
    #pragma unroll
    for (int i = 0; i < 4; ++i) {
        int id = tid + 256*i;
        int r = id >> 4, ch = id & 15;
        float4 v = *reinterpret_cast<const float4*>(W + (size_t)(k0+r)*N + n0 + ch*4);
        Ls[ch*4+0][r] = v.x; Ls[ch*4+1][r] = v.y; Ls[ch*4+2][r] = v.z; Ls[ch*4+3][r] = v.w;
    }
    __syncthreads();
    #pragma unroll
    for (int i = 0; i < 4; ++i) {
        int id = tid + 256*i;
        int rr = id >> 4, ch = id & 15;
        uint2 o2;
        o2.x = pkbf16(Ls[rr][ch*4+0], Ls[rr][ch*4+1]);
        o2.y = pkbf16(Ls[rr][ch*4+2], Ls[rr][ch*4+3]);
        *reinterpret_cast<uint2*>(Wt + (size_t)(n0+rr)*K + k0 + ch*4) = o2;
    }
}

// ---------------- bf16 MFMA GEMM (first-layer qkv projection only) ----------
template<int BM>
__global__ __launch_bounds__(256) void gemm_mfma_kernel(
    const ushort_t* __restrict__ A, const ushort_t* __restrict__ Wt,
    const float* __restrict__ bias, void* __restrict__ C,
    int N, int K, int relu, int obf16)
{
    constexpr int MREP = BM / 32;
    constexpr int ASEG = BM / 32;
    __shared__ __align__(16) ushort_t As[BM * 64];
    __shared__ __align__(16) ushort_t Bs[64 * 64];
    const int tid = threadIdx.x;
    const int row0 = blockIdx.y * BM, col0 = blockIdx.x << 6;
    const int w = tid >> 6, lane = tid & 63, g = lane >> 4, n = lane & 15;
    const int wr = w & 1, wc = w >> 1;
    f32x4 acc[MREP][2];
    #pragma unroll
    for (int mt = 0; mt < MREP; ++mt)
        #pragma unroll
        for (int nt = 0; nt < 2; ++nt) acc[mt][nt] = (f32x4){0.f,0.f,0.f,0.f};

    for (int k0 = 0; k0 < K; k0 += 64) {
        __syncthreads();
        #pragma unroll
        for (int j = 0; j < ASEG; ++j) {
            int seg = w*ASEG + j;
            int id = seg*64 + lane;
            int r = id >> 3, cp = id & 7;
            gload16(A + (size_t)(row0 + r)*K + k0 + ((cp ^ (r & 7)) << 3),
                    As + seg*512);
        }
        #pragma unroll
        for (int j = 0; j < 2; ++j) {
            int seg = w*2 + j;
            int id = seg*64 + lane;
            int r = id >> 3, cp = id & 7;
            gload16(Wt + (size_t)(col0 + r)*K + k0 + ((cp ^ (r & 7)) << 3),
                    Bs + seg*512);
        }
        __syncthreads();
        #pragma unroll
        for (int ks = 0; ks < 2; ++ks) {
            short8 af[MREP], bfr[2];
            #pragma unroll
            for (int mt = 0; mt < MREP; ++mt) {
                int r = wr*(BM/2) + mt*16 + n;
                af[mt] = *reinterpret_cast<const short8*>(As + r*64 + (((ks*4 + g) ^ (r & 7)) << 3));
            }
            #pragma unroll
            for (int nt = 0; nt < 2; ++nt) {
                int r = wc*32 + nt*16 + n;
                bfr[nt] = *reinterpret_cast<const short8*>(Bs + r*64 + (((ks*4 + g) ^ (r & 7)) << 3));
            }
            #pragma unroll
            for (int mt = 0; mt < MREP; ++mt)
                #pragma unroll
                for (int nt = 0; nt < 2; ++nt)
                    acc[mt][nt] = __builtin_amdgcn_mfma_f32_16x16x32_bf16(af[mt], bfr[nt], acc[mt][nt], 0, 0, 0);
        }
    }
    #pragma unroll
    for (int mt = 0; mt < MREP; ++mt) {
        #pragma unroll
        for (int nt = 0; nt < 2; ++nt) {
            int col = col0 + wc*32 + nt*16 + n;
            float bv = bias[col];
            #pragma unroll
            for (int r4 = 0; r4 < 4; ++r4) {
                int row = row0 + wr*(BM/2) + mt*16 + g*4 + r4;
                float v = acc[mt][nt][r4] + bv;
                if (relu) v = fmaxf(v, 0.f);
                if (obf16) ((ushort_t*)C)[(size_t)row*N + col] = (ushort_t)bf16r(v);
                else       ((float*)C)[(size_t)row*N + col] = v;
            }
        }
    }
}

// ---------------- MFMA bf16 flash attention (QBLK=128, KVBLK=64, exp2) ----------------
__global__ __launch_bounds__(512) void attn_mfma_kernel(
    const ushort_t* __restrict__ qkv, const float* __restrict__ rel,
    ushort_t* __restrict__ o)
{
    __shared__ __align__(16) ushort_t Ks[64][40];          // [kcol][dim] 80B rows
    __shared__ __align__(16) ushort_t Vs[64][36];          // [kcol][dim] 72B rows
    __shared__ __align__(16) ushort_t VB[2][2][4][16][8];  // [kchalf][dimhalf][g][n][j]
    __shared__ float rl[RELLEN];
    const int bid = blockIdx.x;
    const int qt = bid & 3;
    const int bh = bid >> 2;
    const int hh = bh & 3, b = bh >> 2;
    const int tid  = threadIdx.x;
    const int w    = tid >> 6;
    const int lane = tid & 63;
    const int g = lane >> 4, n = lane & 15;
    for (int i = tid; i < RELLEN; i += 512) rl[i] = rel[i] * LOG2E;

    const int qrow = (qt << 7) + (w << 4) + n;
    const bool qv = (qrow < TT);
    short8 qf = {0,0,0,0,0,0,0,0};
    if (qv) qf = *reinterpret_cast<const short8*>(qkv + (size_t)(b*TT + qrow)*384 + hh*HD + g*8);

    f32x4 acc0 = {0.f,0.f,0.f,0.f}, acc1 = {0.f,0.f,0.f,0.f};
    float m = -INFINITY, lsum = 0.f;
    const float scale2 = 0.17677669529663687f * LOG2E;
    const f32x4 zf = {0.f,0.f,0.f,0.f};

    const int sr = tid >> 3, sc = tid & 7;      // stage: 64 rows x 8 chunks of 8B

    auto tile = [&](const int kt, const bool domask) {
        const int k0 = kt << 6;
        __syncthreads();                        // prev tile fully consumed
        {
            int t = k0 + sr;
            uint2 kvv = make_uint2(0,0), vvv = make_uint2(0,0);
            if (!domask || t < TT) {
                const ushort_t* bp = qkv + (size_t)(b*TT + t)*384 + hh*HD + sc*4;
                kvv = *reinterpret_cast<const uint2*>(bp + 128);
                vvv = *reinterpret_cast<const uint2*>(bp + 256);
            }
            *reinterpret_cast<uint2*>(&Ks[sr][sc*4]) = kvv;
            *reinterpret_cast<uint2*>(&Vs[sr][sc*4]) = vvv;
        }
        __syncthreads();

        // V relayout into fragment-linear VB (4 elems/thread, 512 threads)
        {
            int jh = (tid & 1)*4, nn = (tid >> 1) & 15, gg = (tid >> 5) & 3;
            int dh = (tid >> 7) & 1, kch = (tid >> 8) & 1;
            ushort_t tmp[4];
            #pragma unroll
            for (int j = 0; j < 4; ++j) tmp[j] = Vs[kch*32 + gg*8 + jh + j][dh*16 + nn];
            *reinterpret_cast<uint2*>(&VB[kch][dh][gg][nn][jh]) = *reinterpret_cast<uint2*>(tmp);
        }

        // S^T = K . Q^T : 4 tiles of 16 kcols (per wave)
        f32x4 s[4];
        #pragma unroll
        for (int c = 0; c < 4; ++c) {
            short8 ak = *reinterpret_cast<const short8*>(&Ks[c*16 + n][g*8]);
            s[c] = __builtin_amdgcn_mfma_f32_16x16x32_bf16(ak, qf, zf, 0, 0, 0);
        }

        float sv[16];
        float tmax = -INFINITY;
        #pragma unroll
        for (int c = 0; c < 4; ++c)
            #pragma unroll
            for (int r = 0; r < 4; ++r) {
                int kc = k0 + c*16 + g*4 + r;
                float bia = rl[kc - qrow + (MAXLEN_-1)];
                float v = fmaf(s[c][r], scale2, bia);
                if (domask && kc >= TT) v = -1e30f;
                sv[c*4 + r] = v;
                tmax = fmaxf(tmax, v);
            }
        tmax = fmaxf(tmax, __shfl_xor(tmax, 16));
        tmax = fmaxf(tmax, __shfl_xor(tmax, 32));
        float mnew = fmaxf(m, tmax);
        float corr = exp2f(m - mnew);
        m = mnew;
        float ps = 0.f;
        #pragma unroll
        for (int r = 0; r < 16; ++r) { float e = exp2f(sv[r] - mnew); sv[r] = e; ps += e; }
        ps += __shfl_xor(ps, 16);
        ps += __shfl_xor(ps, 32);
        lsum = fmaf(lsum, corr, ps);

        int src0 = n + ((g & 1) << 5);
        int src1 = src0 + 16;
        int t0 = (g < 2);
        union { unsigned wd[4]; short8 v; } PA, PB;
        {
            unsigned pk0lo = pkbf16(sv[0], sv[1]);
            unsigned pk0hi = pkbf16(sv[2], sv[3]);
            unsigned pk1lo = pkbf16(sv[4], sv[5]);
            unsigned pk1hi = pkbf16(sv[6], sv[7]);
            unsigned a0 = __shfl((int)pk0lo, src0), c0_ = __shfl((int)pk1lo, src0);
            unsigned a1 = __shfl((int)pk0hi, src0), c1_ = __shfl((int)pk1hi, src0);
            unsigned a2 = __shfl((int)pk0lo, src1), c2_ = __shfl((int)pk1lo, src1);
            unsigned a3 = __shfl((int)pk0hi, src1), c3_ = __shfl((int)pk1hi, src1);
            PA.wd[0] = t0 ? a0 : c0_; PA.wd[1] = t0 ? a1 : c1_;
            PA.wd[2] = t0 ? a2 : c2_; PA.wd[3] = t0 ? a3 : c3_;
        }
        {
            unsigned pk0lo = pkbf16(sv[8],  sv[9]);
            unsigned pk0hi = pkbf16(sv[10], sv[11]);
            unsigned pk1lo = pkbf16(sv[12], sv[13]);
            unsigned pk1hi = pkbf16(sv[14], sv[15]);
            unsigned a0 = __shfl((int)pk0lo, src0), c0_ = __shfl((int)pk1lo, src0);
            unsigned a1 = __shfl((int)pk0hi, src0), c1_ = __shfl((int)pk1hi, src0);
            unsigned a2 = __shfl((int)pk0lo, src1), c2_ = __shfl((int)pk1lo, src1);
            unsigned a3 = __shfl((int)pk0hi, src1), c3_ = __shfl((int)pk1hi, src1);
            PB.wd[0] = t0 ? a0 : c0_; PB.wd[1] = t0 ? a1 : c1_;
            PB.wd[2] = t0 ? a2 : c2_; PB.wd[3] = t0 ? a3 : c3_;
        }

        short8 a00 = *reinterpret_cast<const short8*>(&VB[0][0][g][n][0]);
        short8 a01 = *reinterpret_cast<const short8*>(&VB[0][1][g][n][0]);
        short8 a10 = *reinterpret_cast<const short8*>(&VB[1][0][g][n][0]);
        short8 a11 = *reinterpret_cast<const short8*>(&VB[1][1][g][n][0]);
        #pragma unroll
        for (int r = 0; r < 4; ++r) { acc0[r] *= corr; acc1[r] *= corr; }
        acc0 = __builtin_amdgcn_mfma_f32_16x16x32_bf16(a00, PA.v, acc0, 0, 0, 0);
        acc0 = __builtin_amdgcn_mfma_f32_16x16x32_bf16(a10, PB.v, acc0, 0, 0, 0);
        acc1 = __builtin_amdgcn_mfma_f32_16x16x32_bf16(a01, PA.v, acc1, 0, 0, 0);
        acc1 = __builtin_amdgcn_mfma_f32_16x16x32_bf16(a11, PB.v, acc1, 0, 0, 0);
    };

    for (int kt = 0; kt < 7; ++kt) tile(kt, false);   // kcols 0..447 < 500
    tile(7, true);                                    // kcols 448..511 masked

    if (qv) {
        float inv = 1.f / lsum;
        uint2 p0, p1;
        p0.x = pkbf16(acc0[0]*inv, acc0[1]*inv);
        p0.y = pkbf16(acc0[2]*inv, acc0[3]*inv);
        p1.x = pkbf16(acc1[0]*inv, acc1[1]*inv);
        p1.y = pkbf16(acc1[2]*inv, acc1[3]*inv);
        ushort_t* op = o + (size_t)(b*TT + qrow)*DIM + hh*HD + g*4;
        *reinterpret_cast<uint2*>(op)      = p0;
        *reinterpret_cast<uint2*>(op + 16) = p1;
    }
}

// ------- fused post-attention: wo GEMM + LN1 + FFN + LN2 + next-layer qkv ----------
__global__ __launch_bounds__(256) void pa_kernel(
    const ushort_t* __restrict__ attno, const ushort_t* __restrict__ wot,
    const float* __restrict__ bo, const ushort_t* __restrict__ W1t,
    const ushort_t* __restrict__ W2t, const float* __restrict__ b1v,
    const float* __restrict__ b2v, float* __restrict__ h,
    const float* __restrict__ ln1g, const float* __restrict__ ln1b,
    const float* __restrict__ ln2g, const float* __restrict__ ln2b,
    const ushort_t* __restrict__ wqkvN, const float* __restrict__ bqkvN,
    ushort_t* __restrict__ qkvout, int doqkv)
{
    __shared__ __align__(16) ushort_t As[32 * 128];     // 8 KB: attno, LN1 y, then LN2 y
    __shared__ __align__(16) ushort_t Wbuf[8192];       // 16 KB weight chunk
    __shared__ __align__(16) ushort_t Mid[32 * 512];    // 32 KB
    __shared__ float Hres[32 * 132];                    // 16.9 KB, padded rows
    __shared__ float red[4][32][2];
    __shared__ float stats[32][2];
    const int tid = threadIdx.x;
    const int row0 = blockIdx.x << 5;
    const int w = tid >> 6, lane = tid & 63, g = lane >> 4, n = lane & 15;

    // stage attno tile (32 x 128 = 512 chunks): linear LDS dest + swizzled source
    #pragma unroll
    for (int j = 0; j < 2; ++j) {
        int seg = w*2 + j;
        int id = seg*64 + lane;
        int r = id >> 4, cp = id & 15;
        gload16(attno + (size_t)(row0 + r)*DIM + ((cp ^ (r & 7)) << 3),
                As + seg*512);
    }

    // ---- phase A: wo GEMM (K=128) ----
    f32x4 acc[2][2];
    #pragma unroll
    for (int a = 0; a < 2; ++a)
        #pragma unroll
        for (int b = 0; b < 2; ++b) acc[a][b] = (f32x4){0.f,0.f,0.f,0.f};
    #pragma unroll
    for (int k0 = 0; k0 < 128; k0 += 64) {
        __syncthreads();
        #pragma unroll
        for (int j = 0; j < 4; ++j) {          // Wbuf[128 n][64 k] = 1024 chunks
            int seg = w*4 + j;
            int id = seg*64 + lane;
            int r = id >> 3, cp = id & 7;
            gload16(wot + (size_t)r*DIM + k0 + ((cp ^ (r & 7)) << 3),
                    Wbuf + seg*512);
        }
        __syncthreads();
        #pragma unroll
        for (int ks = 0; ks < 2; ++ks) {
            short8 af[2], bfr[2];
            #pragma unroll
            for (int mt = 0; mt < 2; ++mt) {
                int r = mt*16 + n;
                int ch = (k0 >> 3) + ks*4 + g;
                af[mt] = *reinterpret_cast<const short8*>(As + r*128 + ((ch ^ (r & 7)) << 3));
            }
            #pragma unroll
            for (int nt = 0; nt < 2; ++nt) {
                int r = w*32 + nt*16 + n;
                bfr[nt] = *reinterpret_cast<const short8*>(Wbuf + r*64 + (((ks*4 + g) ^ (r & 7)) << 3));
            }
            #pragma unroll
            for (int mt = 0; mt < 2; ++mt)
                #pragma unroll
                for (int nt = 0; nt < 2; ++nt)
                    acc[mt][nt] = __builtin_amdgcn_mfma_f32_16x16x32_bf16(af[mt], bfr[nt], acc[mt][nt], 0, 0, 0);
        }
    }
    // epilogue A: bias + residual + LN1 -> Hres (f32) + As (bf16)
    {
        float vals[2][2][4];
        #pragma unroll
        for (int nt = 0; nt < 2; ++nt) {
            int col = w*32 + nt*16 + n;
            float bv = bo[col];
            #pragma unroll
            for (int mt = 0; mt < 2; ++mt)
                #pragma unroll
                for (int r4 = 0; r4 < 4; ++r4) {
                    int row = row0 + mt*16 + g*4 + r4;
                    vals[mt][nt][r4] = acc[mt][nt][r4] + bv + h[(size_t)row*DIM + col];
                }
        }
        #pragma unroll
        for (int mt = 0; mt < 2; ++mt)
            #pragma unroll
            for (int r4 = 0; r4 < 4; ++r4) {
                float s  = vals[mt][0][r4] + vals[mt][1][r4];
                float s2 = vals[mt][0][r4]*vals[mt][0][r4] + vals[mt][1][r4]*vals[mt][1][r4];
                #pragma unroll
                for (int off = 1; off < 16; off <<= 1) {
                    s  += __shfl_xor(s, off);
                    s2 += __shfl_xor(s2, off);
                }
                if (n == 0) { red[w][mt*16 + g*4 + r4][0] = s; red[w][mt*16 + g*4 + r4][1] = s2; }
            }
        __syncthreads();
        if (tid < 32) {
            float s = 0.f, s2 = 0.f;
            #pragma unroll
            for (int ww = 0; ww < 4; ++ww) { s += red[ww][tid][0]; s2 += red[ww][tid][1]; }
            float mean = s * (1.f/128.f);
            float var  = s2 * (1.f/128.f) - mean*mean;
            stats[tid][0] = mean;
            stats[tid][1] = rsqrtf(var + 1e-5f);
        }
        __syncthreads();
        #pragma unroll
        for (int nt = 0; nt < 2; ++nt) {
            int col = w*32 + nt*16 + n;
            int ch = col >> 3, off8 = col & 7;
            float gv = ln1g[col], bv = ln1b[col];
            #pragma unroll
            for (int mt = 0; mt < 2; ++mt)
                #pragma unroll
                for (int r4 = 0; r4 < 4; ++r4) {
                    int rloc = mt*16 + g*4 + r4;
                    float y = (vals[mt][nt][r4] - stats[rloc][0]) * stats[rloc][1] * gv + bv;
                    Hres[rloc*132 + col] = y;
                    As[rloc*128 + ((ch ^ (rloc & 7)) << 3) + off8] = (ushort_t)bf16r(y);
                }
        }
    }

    // ---- phase B1: Mid = relu(As @ W1 + b1), 8 chunks of 64 k1-cols ----
    for (int cc = 0; cc < 8; ++cc) {
        __syncthreads();                        // Wbuf free + As writes visible (cc=0)
        #pragma unroll
        for (int j = 0; j < 4; ++j) {          // Wbuf[64 k1][128 k] = 1024 chunks
            int seg = w*4 + j;
            int id = seg*64 + lane;
            int r = id >> 4, cp = id & 15;
            gload16(W1t + (size_t)(cc*64 + r)*DIM + ((cp ^ (r & 7)) << 3),
                    Wbuf + seg*512);
        }
        __syncthreads();
        f32x4 acc1[2] = {{0.f,0.f,0.f,0.f},{0.f,0.f,0.f,0.f}};
        #pragma unroll
        for (int ks = 0; ks < 4; ++ks) {
            int rW = w*16 + n;
            short8 aw = *reinterpret_cast<const short8*>(Wbuf + rW*128 + (((ks*4 + g) ^ (rW & 7)) << 3));
            #pragma unroll
            for (int mt = 0; mt < 2; ++mt) {
                int rA = mt*16 + n;
                short8 bh_ = *reinterpret_cast<const short8*>(As + rA*128 + (((ks*4 + g) ^ (rA & 7)) << 3));
                acc1[mt] = __builtin_amdgcn_mfma_f32_16x16x32_bf16(aw, bh_, acc1[mt], 0, 0, 0);
            }
        }
        {
            int k1b = cc*64 + w*16 + g*4;
            float4 bb = *reinterpret_cast<const float4*>(b1v + k1b);
            int ch = k1b >> 3;
            int halfoff = (g & 1) * 4;
            #pragma unroll
            for (int mt = 0; mt < 2; ++mt) {
                int mrow = mt*16 + n;
                float v0 = fmaxf(acc1[mt][0] + bb.x, 0.f);
                float v1 = fmaxf(acc1[mt][1] + bb.y, 0.f);
                float v2 = fmaxf(acc1[mt][2] + bb.z, 0.f);
                float v3 = fmaxf(acc1[mt][3] + bb.w, 0.f);
                uint2 pk;
                pk.x = pkbf16(v0, v1);
                pk.y = pkbf16(v2, v3);
                *reinterpret_cast<uint2*>(Mid + mrow*512 + ((ch ^ (mrow & 7)) << 3) + halfoff) = pk;
            }
        }
    }

    // ---- phase B2: out = Mid @ W2, 8 chunks of 64 k1 ----
    f32x4 oacc[2][2];
    #pragma unroll
    for (int a = 0; a < 2; ++a)
        #pragma unroll
        for (int b = 0; b < 2; ++b) oacc[a][b] = (f32x4){0.f,0.f,0.f,0.f};
    for (int kc = 0; kc < 8; ++kc) {
        __syncthreads();                        // Wbuf free + Mid complete (kc=0)
        #pragma unroll
        for (int j = 0; j < 4; ++j) {          // Wbuf[128 c][64 k1] = 1024 chunks
            int seg = w*4 + j;
            int id = seg*64 + lane;
            int r = id >> 3, cp = id & 7;
            gload16(W2t + (size_t)r*FFD + kc*64 + ((cp ^ (r & 7)) << 3),
                    Wbuf + seg*512);
        }
        __syncthreads();
        #pragma unroll
        for (int ks = 0; ks < 2; ++ks) {
            short8 aw[2], bm[2];
            #pragma unroll
            for (int ct = 0; ct < 2; ++ct) {
                int r = w*32 + ct*16 + n;
                aw[ct] = *reinterpret_cast<const short8*>(Wbuf + r*64 + (((ks*4 + g) ^ (r & 7)) << 3));
            }
            #pragma unroll
            for (int mt = 0; mt < 2; ++mt) {
                int r = mt*16 + n;
                int ch = kc*8 + ks*4 + g;
                bm[mt] = *reinterpret_cast<const short8*>(Mid + r*512 + ((ch ^ (r & 7)) << 3));
            }
            #pragma unroll
            for (int ct = 0; ct < 2; ++ct)
                #pragma unroll
                for (int mt = 0; mt < 2; ++mt)
                    oacc[ct][mt] = __builtin_amdgcn_mfma_f32_16x16x32_bf16(aw[ct], bm[mt], oacc[ct][mt], 0, 0, 0);
        }
    }

    // epilogue B: bias + residual(Hres) + LN2 -> h (f32 global) + As (bf16 LDS)
    float vals[2][2][4];
    #pragma unroll
    for (int ct = 0; ct < 2; ++ct) {
        int colb = w*32 + ct*16 + g*4;
        float4 bb = *reinterpret_cast<const float4*>(b2v + colb);
        #pragma unroll
        for (int mt = 0; mt < 2; ++mt) {
            int rloc = mt*16 + n;
            float4 hres = *reinterpret_cast<const float4*>(&Hres[rloc*132 + colb]);
            vals[ct][mt][0] = oacc[ct][mt][0] + bb.x + hres.x;
            vals[ct][mt][1] = oacc[ct][mt][1] + bb.y + hres.y;
            vals[ct][mt][2] = oacc[ct][mt][2] + bb.z + hres.z;
            vals[ct][mt][3] = oacc[ct][mt][3] + bb.w + hres.w;
        }
    }
    __syncthreads();                           // red[] reuse safe
    #pragma unroll
    for (int mt = 0; mt < 2; ++mt) {
        float s = 0.f, s2 = 0.f;
        #pragma unroll
        for (int ct = 0; ct < 2; ++ct)
            #pragma unroll
            for (int r4 = 0; r4 < 4; ++r4) { float v = vals[ct][mt][r4]; s += v; s2 += v*v; }
        s  += __shfl_xor(s, 16);  s  += __shfl_xor(s, 32);
        s2 += __shfl_xor(s2, 16); s2 += __shfl_xor(s2, 32);
        if (g == 0) { red[w][mt*16 + n][0] = s; red[w][mt*16 + n][1] = s2; }
    }
    __syncthreads();
    if (tid < 32) {
        float s = 0.f, s2 = 0.f;
        #pragma unroll
        for (int ww = 0; ww < 4; ++ww) { s += red[ww][tid][0]; s2 += red[ww][tid][1]; }
        float mean = s * (1.f/128.f);
        float var  = s2 * (1.f/128.f) - mean*mean;
        stats[tid][0] = mean;
        stats[tid][1] = rsqrtf(var + 1e-5f);
    }
    __syncthreads();
    #pragma unroll
    for (int ct = 0; ct < 2; ++ct) {
        int colb = w*32 + ct*16 + g*4;
        float4 gv = *reinterpret_cast<const float4*>(ln2g + colb);
        float4 bv = *reinterpret_cast<const float4*>(ln2b + colb);
        int ch = colb >> 3;
        int halfoff = (g & 1) * 4;
        #pragma unroll
        for (int mt = 0; mt < 2; ++mt) {
            int rloc = mt*16 + n;
            int mrow = row0 + rloc;
            float mean = stats[rloc][0], rstd = stats[rloc][1];
            float y0 = (vals[ct][mt][0] - mean) * rstd * gv.x + bv.x;
            float y1 = (vals[ct][mt][1] - mean) * rstd * gv.y + bv.y;
            float y2 = (vals[ct][mt][2] - mean) * rstd * gv.z + bv.z;
            float y3 = (vals[ct][mt][3] - mean) * rstd * gv.w + bv.w;
            float4 yo = {y0, y1, y2, y3};
            *reinterpret_cast<float4*>(h + (size_t)mrow*DIM + colb) = yo;
            uint2 pk;
            pk.x = pkbf16(y0, y1);
            pk.y = pkbf16(y2, y3);
            *reinterpret_cast<uint2*>(As + rloc*128 + ((ch ^ (rloc & 7)) << 3) + halfoff) = pk;
        }
    }

    // ---- phase C: next-layer qkv projection: qkvout = As @ wqkvN + bqkvN ----
    if (doqkv) {
        for (int c = 0; c < 6; ++c) {
            __syncthreads();                    // Wbuf free + As (LN2 y) visible (c=0)
            #pragma unroll
            for (int j = 0; j < 4; ++j) {      // Wbuf[64 qcol][128 k] = 1024 chunks
                int seg = w*4 + j;
                int id = seg*64 + lane;
                int r = id >> 4, cp = id & 15;
                gload16(wqkvN + (size_t)(c*64 + r)*DIM + ((cp ^ (r & 7)) << 3),
                        Wbuf + seg*512);
            }
            __syncthreads();
            f32x4 qacc[2] = {{0.f,0.f,0.f,0.f},{0.f,0.f,0.f,0.f}};
            #pragma unroll
            for (int ks = 0; ks < 4; ++ks) {
                int rW = w*16 + n;
                short8 aw = *reinterpret_cast<const short8*>(Wbuf + rW*128 + (((ks*4 + g) ^ (rW & 7)) << 3));
                #pragma unroll
                for (int mt = 0; mt < 2; ++mt) {
                    int rA = mt*16 + n;
                    short8 bh_ = *reinterpret_cast<const short8*>(As + rA*128 + (((ks*4 + g) ^ (rA & 7)) << 3));
                    qacc[mt] = __builtin_amdgcn_mfma_f32_16x16x32_bf16(aw, bh_, qacc[mt], 0, 0, 0);
                }
            }
            int colb = c*64 + w*16 + g*4;
            float4 bb = *reinterpret_cast<const float4*>(bqkvN + colb);
            #pragma unroll
            for (int mt = 0; mt < 2; ++mt) {
                int mrow = row0 + mt*16 + n;
                uint2 pk;
                pk.x = pkbf16(qacc[mt][0] + bb.x, qacc[mt][1] + bb.y);
                pk.y = pkbf16(qacc[mt][2] + bb.z, qacc[mt][3] + bb.w);
                *reinterpret_cast<uint2*>(qkvout + (size_t)mrow*384 + colb) = pk;
            }
        }
    }
}

// ---------------- mean-pool + LN + classifier ----------------
__global__ __launch_bounds__(128) void final_kernel(
    const float* __restrict__ h, const float* __restrict__ g,
    const float* __restrict__ bt, const float* __restrict__ cls_w,
    const float* __restrict__ cls_b, float* __restrict__ out)
{
    int b = blockIdx.x, d = threadIdx.x;
    float s = 0.f;
    for (int t = 0; t < TT; ++t) s += h[((size_t)b*TT + t)*DIM + d];
    float pooled = s * (1.f / TT);
    __shared__ float sm[4];
    float v1 = pooled, v2 = pooled * pooled;
    #pragma unroll
    for (int off = 1; off < 64; off <<= 1) { v1 += __shfl_xor(v1, off); v2 += __shfl_xor(v2, off); }
    int wave = threadIdx.x >> 6, lane = threadIdx.x & 63;
    if (lane == 0) { sm[wave*2] = v1; sm[wave*2+1] = v2; }
    __syncthreads();
    float mean = (sm[0] + sm[2]) * (1.f/128.f);
    float var  = (sm[1] + sm[3]) * (1.f/128.f) - mean*mean;
    float xn = (pooled - mean) * rsqrtf(var + 1e-5f) * g[d] + bt[d];
    __shared__ float px[DIM];
    px[d] = xn;
    __syncthreads();
    if (d < NCLS_) {
        float a = cls_b[d];
        for (int i = 0; i < DIM; ++i) a = fmaf(px[i], cls_w[i*NCLS_ + d], a);
        out[b*NCLS_ + d] = a;
    }
}

// ---------------- host ----------------
extern "C" void kernel_launch(void* const* d_in, const int* in_sizes, int n_in,
                              void* d_out, int out_size, void* d_ws, size_t ws_size,
                              hipStream_t stream)
{
    (void)in_sizes; (void)n_in; (void)out_size; (void)ws_size;
    const float* x1      = (const float*)d_in[0];
    const float* proj_w  = (const float*)d_in[1];
    const float* proj_b  = (const float*)d_in[2];
    const float* queries = (const float*)d_in[3];
    const float* fc_w    = (const float*)d_in[4];
    const float* fc_b    = (const float*)d_in[5];
    const float* embed_w = (const float*)d_in[6];
    const float* embed_b = (const float*)d_in[7];
    const float* wqkv    = (const float*)d_in[8];
    const float* bqkv    = (const float*)d_in[9];
    const float* wo      = (const float*)d_in[10];
    const float* bo      = (const float*)d_in[11];
    const float* w1      = (const float*)d_in[12];
    const float* b1      = (const float*)d_in[13];
    const float* w2      = (const float*)d_in[14];
    const float* b2      = (const float*)d_in[15];
    const float* ln1_g   = (const float*)d_in[16];
    const float* ln1_b   = (const float*)d_in[17];
    const float* ln2_g   = (const float*)d_in[18];
    const float* ln2_b   = (const float*)d_in[19];
    const float* rel_t   = (const float*)d_in[20];
    const float* final_g = (const float*)d_in[21];
    const float* final_b = (const float*)d_in[22];
    const float* cls_w   = (const float*)d_in[23];
    const float* cls_b   = (const float*)d_in[24];

    float* ws     = (float*)d_ws;
    float* h      = ws;                                    // MM*128 f32
    ushort_t* hb    = (ushort_t*)(h + (size_t)MM*DIM);     // MM*128 bf16 (enc -> first gemm)
    ushort_t* qkvb  = hb    + (size_t)MM*DIM;              // MM*384 bf16
    ushort_t* attno = qkvb  + (size_t)MM*384;              // MM*128 bf16
    ushort_t* wts   = attno + (size_t)MM*DIM;              // 1179648 bf16
    float* alpha  = (float*)(wts + 1179648);               // 16
    float* Emat   = alpha + 16;                            // 10*128
    float* c0     = Emat + QOUT_*DIM;                      // 128

    enc_pre_kernel<<<1, 128, 0, stream>>>(proj_w, proj_b, queries, fc_w, fc_b,
                                          embed_w, embed_b, alpha, Emat, c0);
    wtrans_kernel<<<288, 256, 0, stream>>>(wqkv, wo, w1, w2, wts);
    enc_kernel<<<MM, 64, 0, stream>>>(x1, alpha, Emat, c0, h, hb);

    // first-layer qkv projection (later layers fused into pa)
    gemm_mfma_kernel<128><<<dim3(384/64, MM/128), 256, 0, stream>>>(
        hb, wts, bqkv, qkvb, 384, DIM, 0, 1);

    for (int l = 0; l < NL; ++l) {
        const ushort_t* wo_t   = wts + 294912 + (size_t)l*16384;
        const ushort_t* w1_t   = wts + 393216 + (size_t)l*65536;
        const ushort_t* w2_t   = wts + 786432 + (size_t)l*65536;
        const int lnext = l + 1;
        const int doqkv = (lnext < NL);
        const ushort_t* wqkvN = wts + (size_t)(doqkv ? lnext : 0)*49152;
        const float*    bqkvN = bqkv + (doqkv ? lnext : 0)*3*DIM;

        attn_mfma_kernel<<<BB*NHEADS*4, 512, 0, stream>>>(
            qkvb, rel_t + l*RELLEN, attno);
        pa_kernel<<<MM/32, 256, 0, stream>>>(
            attno, wo_t, bo + l*DIM, w1_t, w2_t, b1 + l*FFD, b2 + l*DIM,
            h, ln1_g + l*DIM, ln1_b + l*DIM, ln2_g + l*DIM, ln2_b + l*DIM,
            wqkvN, bqkvN, qkvb, doqkv);
    }

    final_kernel<<<BB, 128, 0, stream>>>(h, final_g, final_b, cls_w, cls_b, (float*)d_out);
}

// Round 12
// 373.338 us; speedup vs baseline: 1.5659x; 1.0232x over previous
//
#include <hip/hip_runtime.h>
#include <hip/hip_bf16.h>
#include <cmath>

#define NL      6
#define NHEADS  4
#define DIM     128
#define FFD     512
#define CMID_   8
#define COUT_   16
#define QOUT_   10
#define MAXLEN_ 512
#define NCLS_   3
#define BB      32
#define TT      500
#define FIN_    232
#define MM      (BB*TT)
#define HD      32
#define RELLEN  (2*MAXLEN_-1)
#define LOG2E   1.4426950408889634f

typedef __attribute__((ext_vector_type(8))) short short8;
typedef __attribute__((ext_vector_type(4))) float f32x4;
typedef unsigned short ushort_t;

__device__ inline unsigned bf16r(float x) {   // RNE float->bf16 bits (finite inputs)
    unsigned u = __float_as_uint(x);
    return (u + 0x7fffu + ((u >> 16) & 1u)) >> 16;
}

// paired RNE pack via HW v_cvt_pk_bf16_f32
__device__ inline unsigned pkbf16(float a, float b) {
    __hip_bfloat162 h2 = __float22bfloat162_rn(float2{a, b});
    return *reinterpret_cast<unsigned*>(&h2);
}

// async 16B global->LDS DMA: per-lane global src, wave-uniform LDS base + lane*16
__device__ inline void gload16(const ushort_t* g, ushort_t* l) {
    __builtin_amdgcn_global_load_lds(
        (const __attribute__((address_space(1))) unsigned*)g,
        (__attribute__((address_space(3))) unsigned*)l, 16, 0, 0);
}

// ---------------- encoder precompute (1 block) ----------------
__global__ __launch_bounds__(128) void enc_pre_kernel(
    const float* __restrict__ proj_w, const float* __restrict__ proj_b,
    const float* __restrict__ queries, const float* __restrict__ fc_w,
    const float* __restrict__ fc_b, const float* __restrict__ embed_w,
    const float* __restrict__ embed_b,
    float* __restrict__ alpha, float* __restrict__ E, float* __restrict__ c0)
{
    __shared__ float pw[CMID_], cb[CMID_], gam[COUT_], del[COUT_];
    int t = threadIdx.x;
    if (t < CMID_) { pw[t] = proj_w[t]; cb[t] = proj_b[t] + ((t & 1) ? 1.f : 0.f); }
    __syncthreads();
    if (t < QOUT_) {
        float a = 0.f;
        for (int c = 0; c < CMID_; ++c) a += pw[c] * queries[t*CMID_ + c];
        alpha[t] = a;
    }
    if (t < COUT_) {
        float gg = 0.f, dd = 0.f;
        for (int c = 0; c < CMID_; ++c) {
            gg += pw[c] * fc_w[c*COUT_ + t];
            dd += cb[c] * fc_w[c*COUT_ + t];
        }
        gam[t] = gg; del[t] = dd + fc_b[t];
    }
    __syncthreads();
    for (int i = t; i < QOUT_*DIM; i += 128) {
        int q = i / DIM, d = i % DIM;
        float e = 0.f;
        for (int o = 0; o < COUT_; ++o) e += gam[o] * embed_w[(o*QOUT_ + q)*DIM + d];
        E[i] = e;
    }
    {
        float c = embed_b[t];
        for (int o = 0; o < COUT_; ++o) {
            float dl = del[o];
            for (int q = 0; q < QOUT_; ++q) c += dl * embed_w[(o*QOUT_ + q)*DIM + t];
        }
        c0[t] = c;
    }
}

// ---------------- encoder main (4 waves/block, one bt each) ----------------
__global__ __launch_bounds__(256) void enc_kernel(
    const float* __restrict__ x1, const float* __restrict__ alpha,
    const float* __restrict__ E, const float* __restrict__ c0,
    float* __restrict__ h, ushort_t* __restrict__ hb)
{
    int bt = (blockIdx.x << 2) + (threadIdx.x >> 6);
    int lane = threadIdx.x & 63;
    const float* xr = x1 + (size_t)bt * FIN_;
    float xv[4];
    bool vld[4];
    #pragma unroll
    for (int i = 0; i < 4; ++i) {
        int f = lane + (i << 6);
        vld[i] = (f < FIN_);
        xv[i] = vld[i] ? xr[f] : 0.f;
    }
    float vmax = -INFINITY, vmin = INFINITY;
    #pragma unroll
    for (int i = 0; i < 4; ++i) if (vld[i]) { vmax = fmaxf(vmax, xv[i]); vmin = fminf(vmin, xv[i]); }
    #pragma unroll
    for (int off = 1; off < 64; off <<= 1) {
        vmax = fmaxf(vmax, __shfl_xor(vmax, off));
        vmin = fminf(vmin, __shfl_xor(vmin, off));
    }
    float mq[QOUT_];
    for (int q = 0; q < QOUT_; ++q) {
        float a = alpha[q];
        float Mx = (a >= 0.f) ? a * vmax : a * vmin;
        float se = 0.f, sx = 0.f;
        #pragma unroll
        for (int i = 0; i < 4; ++i) if (vld[i]) {
            float e = __expf(fmaf(a, xv[i], -Mx));
            se += e; sx += e * xv[i];
        }
        #pragma unroll
        for (int off = 1; off < 64; off <<= 1) { se += __shfl_xor(se, off); sx += __shfl_xor(sx, off); }
        mq[q] = sx / se;
    }
    #pragma unroll
    for (int k = 0; k < 2; ++k) {
        int d = lane + (k << 6);
        float hv = c0[d];
        #pragma unroll
        for (int q = 0; q < QOUT_; ++q) hv = fmaf(mq[q], E[q*DIM + d], hv);
        h[(size_t)bt*DIM + d] = hv;
        hb[(size_t)bt*DIM + d] = (ushort_t)bf16r(hv);
    }
}

// ---------------- weight transpose + bf16 convert (once per launch) ----------------
__global__ __launch_bounds__(256) void wtrans_kernel(
    const float* __restrict__ wqkv, const float* __restrict__ wo,
    const float* __restrict__ w1, const float* __restrict__ w2,
    ushort_t* __restrict__ wts)
{
    int bid = blockIdx.x;
    const float* W; ushort_t* Wt; int K, N, tk, tn;
    if (bid < 72) {            // wqkv: K=128,N=384 -> 2x6 tiles x 6 layers
        int l = bid / 12, t = bid % 12; tk = t / 6; tn = t % 6; K = 128; N = 384;
        W = wqkv + (size_t)l*128*384; Wt = wts + (size_t)l*49152;
    } else if (bid < 96) {     // wo: 128x128 -> 2x2 x 6
        int q = bid - 72; int l = q / 4, t = q % 4; tk = t / 2; tn = t % 2; K = 128; N = 128;
        W = wo + (size_t)l*16384; Wt = wts + 294912 + (size_t)l*16384;
    } else if (bid < 192) {    // w1: K=128,N=512 -> 2x8 x 6
        int q = bid - 96; int l = q / 16, t = q % 16; tk = t / 8; tn = t % 8; K = 128; N = 512;
        W = w1 + (size_t)l*65536; Wt = wts + 393216 + (size_t)l*65536;
    } else {                   // w2: K=512,N=128 -> 8x2 x 6
        int q = bid - 192; int l = q / 16, t = q % 16; tk = t / 2; tn = t % 2; K = 512; N = 128;
        W = w2 + (size_t)l*65536; Wt = wts + 786432 + (size_t)l*65536;
    }
    int k0 = tk << 6, n0 = tn << 6;
    __shared__ float Ls[64][65];
    int tid = threadIdx.x;
    #pragma unroll
    for (int i = 0; i < 4; ++i) {
        int id = tid + 256*i;
        int r = id >> 4, ch = id & 15;
        float4 v = *reinterpret_cast<const float4*>(W + (size_t)(k0+r)*N + n0 + ch*4);
        Ls[ch*4+0][r] = v.x; Ls[ch*4+1][r] = v.y; Ls[ch*4+2][r] = v.z; Ls[ch*4+3][r] = v.w;
    }
    __syncthreads();
    #pragma unroll
    for (int i = 0; i < 4; ++i) {
        int id = tid + 256*i;
        int rr = id >> 4, ch = id & 15;
        uint2 o2;
        o2.x = pkbf16(Ls[rr][ch*4+0], Ls[rr][ch*4+1]);
        o2.y = pkbf16(Ls[rr][ch*4+2], Ls[rr][ch*4+3]);
        *reinterpret_cast<uint2*>(Wt + (size_t)(n0+rr)*K + k0 + ch*4) = o2;
    }
}

// ---------------- bf16 MFMA GEMM (first-layer qkv projection only) ----------
template<int BM>
__global__ __launch_bounds__(256) void gemm_mfma_kernel(
    const ushort_t* __restrict__ A, const ushort_t* __restrict__ Wt,
    const float* __restrict__ bias, void* __restrict__ C,
    int N, int K, int relu, int obf16)
{
    constexpr int MREP = BM / 32;
    constexpr int ASEG = BM / 32;
    __shared__ __align__(16) ushort_t As[BM * 64];
    __shared__ __align__(16) ushort_t Bs[64 * 64];
    const int tid = threadIdx.x;
    const int row0 = blockIdx.y * BM, col0 = blockIdx.x << 6;
    const int w = tid >> 6, lane = tid & 63, g = lane >> 4, n = lane & 15;
    const int wr = w & 1, wc = w >> 1;
    f32x4 acc[MREP][2];
    #pragma unroll
    for (int mt = 0; mt < MREP; ++mt)
        #pragma unroll
        for (int nt = 0; nt < 2; ++nt) acc[mt][nt] = (f32x4){0.f,0.f,0.f,0.f};

    for (int k0 = 0; k0 < K; k0 += 64) {
        __syncthreads();
        #pragma unroll
        for (int j = 0; j < ASEG; ++j) {
            int seg = w*ASEG + j;
            int id = seg*64 + lane;
            int r = id >> 3, cp = id & 7;
            gload16(A + (size_t)(row0 + r)*K + k0 + ((cp ^ (r & 7)) << 3),
                    As + seg*512);
        }
        #pragma unroll
        for (int j = 0; j < 2; ++j) {
            int seg = w*2 + j;
            int id = seg*64 + lane;
            int r = id >> 3, cp = id & 7;
            gload16(Wt + (size_t)(col0 + r)*K + k0 + ((cp ^ (r & 7)) << 3),
                    Bs + seg*512);
        }
        __syncthreads();
        #pragma unroll
        for (int ks = 0; ks < 2; ++ks) {
            short8 af[MREP], bfr[2];
            #pragma unroll
            for (int mt = 0; mt < MREP; ++mt) {
                int r = wr*(BM/2) + mt*16 + n;
                af[mt] = *reinterpret_cast<const short8*>(As + r*64 + (((ks*4 + g) ^ (r & 7)) << 3));
            }
            #pragma unroll
            for (int nt = 0; nt < 2; ++nt) {
                int r = wc*32 + nt*16 + n;
                bfr[nt] = *reinterpret_cast<const short8*>(Bs + r*64 + (((ks*4 + g) ^ (r & 7)) << 3));
            }
            #pragma unroll
            for (int mt = 0; mt < MREP; ++mt)
                #pragma unroll
                for (int nt = 0; nt < 2; ++nt)
                    acc[mt][nt] = __builtin_amdgcn_mfma_f32_16x16x32_bf16(af[mt], bfr[nt], acc[mt][nt], 0, 0, 0);
        }
    }
    #pragma unroll
    for (int mt = 0; mt < MREP; ++mt) {
        #pragma unroll
        for (int nt = 0; nt < 2; ++nt) {
            int col = col0 + wc*32 + nt*16 + n;
            float bv = bias[col];
            #pragma unroll
            for (int r4 = 0; r4 < 4; ++r4) {
                int row = row0 + wr*(BM/2) + mt*16 + g*4 + r4;
                float v = acc[mt][nt][r4] + bv;
                if (relu) v = fmaxf(v, 0.f);
                if (obf16) ((ushort_t*)C)[(size_t)row*N + col] = (ushort_t)bf16r(v);
                else       ((float*)C)[(size_t)row*N + col] = v;
            }
        }
    }
}

// ---------------- MFMA bf16 flash attention (QBLK=128, KVBLK=128, exp2) ----------------
// grid: B*NHEADS*4 blocks, 512 threads = 8 waves x 16 q-rows each.
__global__ __launch_bounds__(512) void attn_mfma_kernel(
    const ushort_t* __restrict__ qkv, const float* __restrict__ rel,
    ushort_t* __restrict__ o)
{
    __shared__ __align__(16) ushort_t Ks[128][40];          // [kcol][dim] 80B rows
    __shared__ __align__(16) ushort_t Vs[128][40];          // [kcol][dim] 80B rows
    __shared__ __align__(16) ushort_t VB[4][2][4][16][8];   // [kch][dimhalf][g][n][j]
    __shared__ float rl[RELLEN];
    const int bid = blockIdx.x;
    const int qt = bid & 3;
    const int bh = bid >> 2;
    const int hh = bh & 3, b = bh >> 2;
    const int tid  = threadIdx.x;
    const int w    = tid >> 6;
    const int lane = tid & 63;
    const int g = lane >> 4, n = lane & 15;
    for (int i = tid; i < RELLEN; i += 512) rl[i] = rel[i] * LOG2E;

    const int qrow = (qt << 7) + (w << 4) + n;
    const bool qv = (qrow < TT);
    short8 qf = {0,0,0,0,0,0,0,0};
    if (qv) qf = *reinterpret_cast<const short8*>(qkv + (size_t)(b*TT + qrow)*384 + hh*HD + g*8);

    f32x4 acc0 = {0.f,0.f,0.f,0.f}, acc1 = {0.f,0.f,0.f,0.f};
    float m = -INFINITY, lsum = 0.f;
    const float scale2 = 0.17677669529663687f * LOG2E;
    const f32x4 zf = {0.f,0.f,0.f,0.f};

    const int sr = tid >> 2, sc = tid & 3;      // stage: 128 rows x 4 chunks of 16B

    auto tile = [&](const int kt, const bool domask) {
        const int k0 = kt << 7;
        __syncthreads();                        // prev tile fully consumed
        {
            int t = k0 + sr;
            uint4 kvv = make_uint4(0,0,0,0), vvv = make_uint4(0,0,0,0);
            if (!domask || t < TT) {
                const ushort_t* bp = qkv + (size_t)(b*TT + t)*384 + hh*HD + sc*8;
                kvv = *reinterpret_cast<const uint4*>(bp + 128);
                vvv = *reinterpret_cast<const uint4*>(bp + 256);
            }
            *reinterpret_cast<uint4*>(&Ks[sr][sc*8]) = kvv;
            *reinterpret_cast<uint4*>(&Vs[sr][sc*8]) = vvv;
        }
        __syncthreads();

        // V relayout into fragment-linear VB (8 elems/thread, 512 threads)
        #pragma unroll
        for (int i = 0; i < 2; ++i) {
            int id = tid + (i << 9);
            int jh = (id & 1)*4, nn = (id >> 1) & 15, gg = (id >> 5) & 3;
            int dh = (id >> 7) & 1, kch = (id >> 8) & 3;
            ushort_t tmp[4];
            #pragma unroll
            for (int j = 0; j < 4; ++j) tmp[j] = Vs[kch*32 + gg*8 + jh + j][dh*16 + nn];
            *reinterpret_cast<uint2*>(&VB[kch][dh][gg][nn][jh]) = *reinterpret_cast<uint2*>(tmp);
        }

        // S^T = K . Q^T : 8 tiles of 16 kcols, in two halves (register pressure)
        float sv[32];
        float tmax = -INFINITY;
        #pragma unroll
        for (int half = 0; half < 2; ++half) {
            f32x4 s[4];
            #pragma unroll
            for (int c = 0; c < 4; ++c) {
                int cc = half*4 + c;
                short8 ak = *reinterpret_cast<const short8*>(&Ks[cc*16 + n][g*8]);
                s[c] = __builtin_amdgcn_mfma_f32_16x16x32_bf16(ak, qf, zf, 0, 0, 0);
            }
            #pragma unroll
            for (int c = 0; c < 4; ++c)
                #pragma unroll
                for (int r = 0; r < 4; ++r) {
                    int kc = k0 + (half*4 + c)*16 + g*4 + r;
                    float bia = rl[kc - qrow + (MAXLEN_-1)];
                    float v = fmaf(s[c][r], scale2, bia);
                    if (domask && kc >= TT) v = -1e30f;
                    sv[(half*4 + c)*4 + r] = v;
                    tmax = fmaxf(tmax, v);
                }
        }
        tmax = fmaxf(tmax, __shfl_xor(tmax, 16));
        tmax = fmaxf(tmax, __shfl_xor(tmax, 32));
        float mnew = fmaxf(m, tmax);
        float corr = exp2f(m - mnew);
        m = mnew;
        float ps = 0.f;
        #pragma unroll
        for (int r = 0; r < 32; ++r) { float e = exp2f(sv[r] - mnew); sv[r] = e; ps += e; }
        ps += __shfl_xor(ps, 16);
        ps += __shfl_xor(ps, 32);
        lsum = fmaf(lsum, corr, ps);

        // pack + exchange: 4 chains of 32 kcols each
        int src0 = n + ((g & 1) << 5);
        int src1 = src0 + 16;
        int t0 = (g < 2);
        short8 Pv[4];
        #pragma unroll
        for (int cch = 0; cch < 4; ++cch) {
            unsigned pk0lo = pkbf16(sv[cch*8+0], sv[cch*8+1]);
            unsigned pk0hi = pkbf16(sv[cch*8+2], sv[cch*8+3]);
            unsigned pk1lo = pkbf16(sv[cch*8+4], sv[cch*8+5]);
            unsigned pk1hi = pkbf16(sv[cch*8+6], sv[cch*8+7]);
            unsigned a0 = __shfl((int)pk0lo, src0), c0_ = __shfl((int)pk1lo, src0);
            unsigned a1 = __shfl((int)pk0hi, src0), c1_ = __shfl((int)pk1hi, src0);
            unsigned a2 = __shfl((int)pk0lo, src1), c2_ = __shfl((int)pk1lo, src1);
            unsigned a3 = __shfl((int)pk0hi, src1), c3_ = __shfl((int)pk1hi, src1);
            union { unsigned wd[4]; short8 v; } P;
            P.wd[0] = t0 ? a0 : c0_; P.wd[1] = t0 ? a1 : c1_;
            P.wd[2] = t0 ? a2 : c2_; P.wd[3] = t0 ? a3 : c3_;
            Pv[cch] = P.v;
        }

        #pragma unroll
        for (int r = 0; r < 4; ++r) { acc0[r] *= corr; acc1[r] *= corr; }
        #pragma unroll
        for (int kch = 0; kch < 4; ++kch) {
            short8 av0 = *reinterpret_cast<const short8*>(&VB[kch][0][g][n][0]);
            short8 av1 = *reinterpret_cast<const short8*>(&VB[kch][1][g][n][0]);
            acc0 = __builtin_amdgcn_mfma_f32_16x16x32_bf16(av0, Pv[kch], acc0, 0, 0, 0);
            acc1 = __builtin_amdgcn_mfma_f32_16x16x32_bf16(av1, Pv[kch], acc1, 0, 0, 0);
        }
    };

    for (int kt = 0; kt < 3; ++kt) tile(kt, false);   // kcols 0..383 < 500
    tile(3, true);                                    // kcols 384..511 masked

    if (qv) {
        float inv = 1.f / lsum;
        uint2 p0, p1;
        p0.x = pkbf16(acc0[0]*inv, acc0[1]*inv);
        p0.y = pkbf16(acc0[2]*inv, acc0[3]*inv);
        p1.x = pkbf16(acc1[0]*inv, acc1[1]*inv);
        p1.y = pkbf16(acc1[2]*inv, acc1[3]*inv);
        ushort_t* op = o + (size_t)(b*TT + qrow)*DIM + hh*HD + g*4;
        *reinterpret_cast<uint2*>(op)      = p0;
        *reinterpret_cast<uint2*>(op + 16) = p1;
    }
}

// ------- fused post-attention: wo GEMM + LN1 + FFN + LN2 + next-layer qkv ----------
__global__ __launch_bounds__(256) void pa_kernel(
    const ushort_t* __restrict__ attno, const ushort_t* __restrict__ wot,
    const float* __restrict__ bo, const ushort_t* __restrict__ W1t,
    const ushort_t* __restrict__ W2t, const float* __restrict__ b1v,
    const float* __restrict__ b2v, float* __restrict__ h,
    const float* __restrict__ ln1g, const float* __restrict__ ln1b,
    const float* __restrict__ ln2g, const float* __restrict__ ln2b,
    const ushort_t* __restrict__ wqkvN, const float* __restrict__ bqkvN,
    ushort_t* __restrict__ qkvout, int doqkv)
{
    __shared__ __align__(16) ushort_t As[32 * 128];     // 8 KB: attno, LN1 y, then LN2 y
    __shared__ __align__(16) ushort_t Wbuf[8192];       // 16 KB weight chunk
    __shared__ __align__(16) ushort_t Mid[32 * 512];    // 32 KB
    __shared__ float Hres[32 * 132];                    // 16.9 KB, padded rows
    __shared__ float red[4][32][2];
    __shared__ float stats[32][2];
    const int tid = threadIdx.x;
    const int row0 = blockIdx.x << 5;
    const int w = tid >> 6, lane = tid & 63, g = lane >> 4, n = lane & 15;

    // stage attno tile (32 x 128 = 512 chunks): linear LDS dest + swizzled source
    #pragma unroll
    for (int j = 0; j < 2; ++j) {
        int seg = w*2 + j;
        int id = seg*64 + lane;
        int r = id >> 4, cp = id & 15;
        gload16(attno + (size_t)(row0 + r)*DIM + ((cp ^ (r & 7)) << 3),
                As + seg*512);
    }

    // ---- phase A: wo GEMM (K=128) ----
    f32x4 acc[2][2];
    #pragma unroll
    for (int a = 0; a < 2; ++a)
        #pragma unroll
        for (int b = 0; b < 2; ++b) acc[a][b] = (f32x4){0.f,0.f,0.f,0.f};
    #pragma unroll
    for (int k0 = 0; k0 < 128; k0 += 64) {
        __syncthreads();
        #pragma unroll
        for (int j = 0; j < 4; ++j) {          // Wbuf[128 n][64 k] = 1024 chunks
            int seg = w*4 + j;
            int id = seg*64 + lane;
            int r = id >> 3, cp = id & 7;
            gload16(wot + (size_t)r*DIM + k0 + ((cp ^ (r & 7)) << 3),
                    Wbuf + seg*512);
        }
        __syncthreads();
        #pragma unroll
        for (int ks = 0; ks < 2; ++ks) {
            short8 af[2], bfr[2];
            #pragma unroll
            for (int mt = 0; mt < 2; ++mt) {
                int r = mt*16 + n;
                int ch = (k0 >> 3) + ks*4 + g;
                af[mt] = *reinterpret_cast<const short8*>(As + r*128 + ((ch ^ (r & 7)) << 3));
            }
            #pragma unroll
            for (int nt = 0; nt < 2; ++nt) {
                int r = w*32 + nt*16 + n;
                bfr[nt] = *reinterpret_cast<const short8*>(Wbuf + r*64 + (((ks*4 + g) ^ (r & 7)) << 3));
            }
            #pragma unroll
            for (int mt = 0; mt < 2; ++mt)
                #pragma unroll
                for (int nt = 0; nt < 2; ++nt)
                    acc[mt][nt] = __builtin_amdgcn_mfma_f32_16x16x32_bf16(af[mt], bfr[nt], acc[mt][nt], 0, 0, 0);
        }
    }
    // epilogue A: bias + residual + LN1 -> Hres (f32) + As (bf16)
    {
        float vals[2][2][4];
        #pragma unroll
        for (int nt = 0; nt < 2; ++nt) {
            int col = w*32 + nt*16 + n;
            float bv = bo[col];
            #pragma unroll
            for (int mt = 0; mt < 2; ++mt)
                #pragma unroll
                for (int r4 = 0; r4 < 4; ++r4) {
                    int row = row0 + mt*16 + g*4 + r4;
                    vals[mt][nt][r4] = acc[mt][nt][r4] + bv + h[(size_t)row*DIM + col];
                }
        }
        #pragma unroll
        for (int mt = 0; mt < 2; ++mt)
            #pragma unroll
            for (int r4 = 0; r4 < 4; ++r4) {
                float s  = vals[mt][0][r4] + vals[mt][1][r4];
                float s2 = vals[mt][0][r4]*vals[mt][0][r4] + vals[mt][1][r4]*vals[mt][1][r4];
                #pragma unroll
                for (int off = 1; off < 16; off <<= 1) {
                    s  += __shfl_xor(s, off);
                    s2 += __shfl_xor(s2, off);
                }
                if (n == 0) { red[w][mt*16 + g*4 + r4][0] = s; red[w][mt*16 + g*4 + r4][1] = s2; }
            }
        __syncthreads();
        if (tid < 32) {
            float s = 0.f, s2 = 0.f;
            #pragma unroll
            for (int ww = 0; ww < 4; ++ww) { s += red[ww][tid][0]; s2 += red[ww][tid][1]; }
            float mean = s * (1.f/128.f);
            float var  = s2 * (1.f/128.f) - mean*mean;
            stats[tid][0] = mean;
            stats[tid][1] = rsqrtf(var + 1e-5f);
        }
        __syncthreads();
        #pragma unroll
        for (int nt = 0; nt < 2; ++nt) {
            int col = w*32 + nt*16 + n;
            int ch = col >> 3, off8 = col & 7;
            float gv = ln1g[col], bv = ln1b[col];
            #pragma unroll
            for (int mt = 0; mt < 2; ++mt)
                #pragma unroll
                for (int r4 = 0; r4 < 4; ++r4) {
                    int rloc = mt*16 + g*4 + r4;
                    float y = (vals[mt][nt][r4] - stats[rloc][0]) * stats[rloc][1] * gv + bv;
                    Hres[rloc*132 + col] = y;
                    As[rloc*128 + ((ch ^ (rloc & 7)) << 3) + off8] = (ushort_t)bf16r(y);
                }
        }
    }

    // ---- phase B1: Mid = relu(As @ W1 + b1), 8 chunks of 64 k1-cols ----
    for (int cc = 0; cc < 8; ++cc) {
        __syncthreads();                        // Wbuf free + As writes visible (cc=0)
        #pragma unroll
        for (int j = 0; j < 4; ++j) {          // Wbuf[64 k1][128 k] = 1024 chunks
            int seg = w*4 + j;
            int id = seg*64 + lane;
            int r = id >> 4, cp = id & 15;
            gload16(W1t + (size_t)(cc*64 + r)*DIM + ((cp ^ (r & 7)) << 3),
                    Wbuf + seg*512);
        }
        __syncthreads();
        f32x4 acc1[2] = {{0.f,0.f,0.f,0.f},{0.f,0.f,0.f,0.f}};
        #pragma unroll
        for (int ks = 0; ks < 4; ++ks) {
            int rW = w*16 + n;
            short8 aw = *reinterpret_cast<const short8*>(Wbuf + rW*128 + (((ks*4 + g) ^ (rW & 7)) << 3));
            #pragma unroll
            for (int mt = 0; mt < 2; ++mt) {
                int rA = mt*16 + n;
                short8 bh_ = *reinterpret_cast<const short8*>(As + rA*128 + (((ks*4 + g) ^ (rA & 7)) << 3));
                acc1[mt] = __builtin_amdgcn_mfma_f32_16x16x32_bf16(aw, bh_, acc1[mt], 0, 0, 0);
            }
        }
        {
            int k1b = cc*64 + w*16 + g*4;
            float4 bb = *reinterpret_cast<const float4*>(b1v + k1b);
            int ch = k1b >> 3;
            int halfoff = (g & 1) * 4;
            #pragma unroll
            for (int mt = 0; mt < 2; ++mt) {
                int mrow = mt*16 + n;
                float v0 = fmaxf(acc1[mt][0] + bb.x, 0.f);
                float v1 = fmaxf(acc1[mt][1] + bb.y, 0.f);
                float v2 = fmaxf(acc1[mt][2] + bb.z, 0.f);
                float v3 = fmaxf(acc1[mt][3] + bb.w, 0.f);
                uint2 pk;
                pk.x = pkbf16(v0, v1);
                pk.y = pkbf16(v2, v3);
                *reinterpret_cast<uint2*>(Mid + mrow*512 + ((ch ^ (mrow & 7)) << 3) + halfoff) = pk;
            }
        }
    }

    // ---- phase B2: out = Mid @ W2, 8 chunks of 64 k1 ----
    f32x4 oacc[2][2];
    #pragma unroll
    for (int a = 0; a < 2; ++a)
        #pragma unroll
        for (int b = 0; b < 2; ++b) oacc[a][b] = (f32x4){0.f,0.f,0.f,0.f};
    for (int kc = 0; kc < 8; ++kc) {
        __syncthreads();                        // Wbuf free + Mid complete (kc=0)
        #pragma unroll
        for (int j = 0; j < 4; ++j) {          // Wbuf[128 c][64 k1] = 1024 chunks
            int seg = w*4 + j;
            int id = seg*64 + lane;
            int r = id >> 3, cp = id & 7;
            gload16(W2t + (size_t)r*FFD + kc*64 + ((cp ^ (r & 7)) << 3),
                    Wbuf + seg*512);
        }
        __syncthreads();
        #pragma unroll
        for (int ks = 0; ks < 2; ++ks) {
            short8 aw[2], bm[2];
            #pragma unroll
            for (int ct = 0; ct < 2; ++ct) {
                int r = w*32 + ct*16 + n;
                aw[ct] = *reinterpret_cast<const short8*>(Wbuf + r*64 + (((ks*4 + g) ^ (r & 7)) << 3));
            }
            #pragma unroll
            for (int mt = 0; mt < 2; ++mt) {
                int r = mt*16 + n;
                int ch = kc*8 + ks*4 + g;
                bm[mt] = *reinterpret_cast<const short8*>(Mid + r*512 + ((ch ^ (r & 7)) << 3));
            }
            #pragma unroll
            for (int ct = 0; ct < 2; ++ct)
                #pragma unroll
                for (int mt = 0; mt < 2; ++mt)
                    oacc[ct][mt] = __builtin_amdgcn_mfma_f32_16x16x32_bf16(aw[ct], bm[mt], oacc[ct][mt], 0, 0, 0);
        }
    }

    // epilogue B: bias + residual(Hres) + LN2 -> h (f32 global) + As (bf16 LDS)
    float vals[2][2][4];
    #pragma unroll
    for (int ct = 0; ct < 2; ++ct) {
        int colb = w*32 + ct*16 + g*4;
        float4 bb = *reinterpret_cast<const float4*>(b2v + colb);
        #pragma unroll
        for (int mt = 0; mt < 2; ++mt) {
            int rloc = mt*16 + n;
            float4 hres = *reinterpret_cast<const float4*>(&Hres[rloc*132 + colb]);
            vals[ct][mt][0] = oacc[ct][mt][0] + bb.x + hres.x;
            vals[ct][mt][1] = oacc[ct][mt][1] + bb.y + hres.y;
            vals[ct][mt][2] = oacc[ct][mt][2] + bb.z + hres.z;
            vals[ct][mt][3] = oacc[ct][mt][3] + bb.w + hres.w;
        }
    }
    __syncthreads();                           // red[] reuse safe
    #pragma unroll
    for (int mt = 0; mt < 2; ++mt) {
        float s = 0.f, s2 = 0.f;
        #pragma unroll
        for (int ct = 0; ct < 2; ++ct)
            #pragma unroll
            for (int r4 = 0; r4 < 4; ++r4) { float v = vals[ct][mt][r4]; s += v; s2 += v*v; }
        s  += __shfl_xor(s, 16);  s  += __shfl_xor(s, 32);
        s2 += __shfl_xor(s2, 16); s2 += __shfl_xor(s2, 32);
        if (g == 0) { red[w][mt*16 + n][0] = s; red[w][mt*16 + n][1] = s2; }
    }
    __syncthreads();
    if (tid < 32) {
        float s = 0.f, s2 = 0.f;
        #pragma unroll
        for (int ww = 0; ww < 4; ++ww) { s += red[ww][tid][0]; s2 += red[ww][tid][1]; }
        float mean = s * (1.f/128.f);
        float var  = s2 * (1.f/128.f) - mean*mean;
        stats[tid][0] = mean;
        stats[tid][1] = rsqrtf(var + 1e-5f);
    }
    __syncthreads();
    #pragma unroll
    for (int ct = 0; ct < 2; ++ct) {
        int colb = w*32 + ct*16 + g*4;
        float4 gv = *reinterpret_cast<const float4*>(ln2g + colb);
        float4 bv = *reinterpret_cast<const float4*>(ln2b + colb);
        int ch = colb >> 3;
        int halfoff = (g & 1) * 4;
        #pragma unroll
        for (int mt = 0; mt < 2; ++mt) {
            int rloc = mt*16 + n;
            int mrow = row0 + rloc;
            float mean = stats[rloc][0], rstd = stats[rloc][1];
            float y0 = (vals[ct][mt][0] - mean) * rstd * gv.x + bv.x;
            float y1 = (vals[ct][mt][1] - mean) * rstd * gv.y + bv.y;
            float y2 = (vals[ct][mt][2] - mean) * rstd * gv.z + bv.z;
            float y3 = (vals[ct][mt][3] - mean) * rstd * gv.w + bv.w;
            float4 yo = {y0, y1, y2, y3};
            *reinterpret_cast<float4*>(h + (size_t)mrow*DIM + colb) = yo;
            uint2 pk;
            pk.x = pkbf16(y0, y1);
            pk.y = pkbf16(y2, y3);
            *reinterpret_cast<uint2*>(As + rloc*128 + ((ch ^ (rloc & 7)) << 3) + halfoff) = pk;
        }
    }

    // ---- phase C: next-layer qkv projection: qkvout = As @ wqkvN + bqkvN ----
    if (doqkv) {
        for (int c = 0; c < 6; ++c) {
            __syncthreads();                    // Wbuf free + As (LN2 y) visible (c=0)
            #pragma unroll
            for (int j = 0; j < 4; ++j) {      // Wbuf[64 qcol][128 k] = 1024 chunks
                int seg = w*4 + j;
                int id = seg*64 + lane;
                int r = id >> 4, cp = id & 15;
                gload16(wqkvN + (size_t)(c*64 + r)*DIM + ((cp ^ (r & 7)) << 3),
                        Wbuf + seg*512);
            }
            __syncthreads();
            f32x4 qacc[2] = {{0.f,0.f,0.f,0.f},{0.f,0.f,0.f,0.f}};
            #pragma unroll
            for (int ks = 0; ks < 4; ++ks) {
                int rW = w*16 + n;
                short8 aw = *reinterpret_cast<const short8*>(Wbuf + rW*128 + (((ks*4 + g) ^ (rW & 7)) << 3));
                #pragma unroll
                for (int mt = 0; mt < 2; ++mt) {
                    int rA = mt*16 + n;
                    short8 bh_ = *reinterpret_cast<const short8*>(As + rA*128 + (((ks*4 + g) ^ (rA & 7)) << 3));
                    qacc[mt] = __builtin_amdgcn_mfma_f32_16x16x32_bf16(aw, bh_, qacc[mt], 0, 0, 0);
                }
            }
            int colb = c*64 + w*16 + g*4;
            float4 bb = *reinterpret_cast<const float4*>(bqkvN + colb);
            #pragma unroll
            for (int mt = 0; mt < 2; ++mt) {
                int mrow = row0 + mt*16 + n;
                uint2 pk;
                pk.x = pkbf16(qacc[mt][0] + bb.x, qacc[mt][1] + bb.y);
                pk.y = pkbf16(qacc[mt][2] + bb.z, qacc[mt][3] + bb.w);
                *reinterpret_cast<uint2*>(qkvout + (size_t)mrow*384 + colb) = pk;
            }
        }
    }
}

// ---------------- mean-pool + LN + classifier (4-way split pooling) ----------------
__global__ __launch_bounds__(512) void final_kernel(
    const float* __restrict__ h, const float* __restrict__ g,
    const float* __restrict__ bt, const float* __restrict__ cls_w,
    const float* __restrict__ cls_b, float* __restrict__ out)
{
    int b = blockIdx.x;
    int d = threadIdx.x & 127, q = threadIdx.x >> 7;
    __shared__ float psum[4][128];
    __shared__ float sm[4];
    __shared__ float px[DIM];
    float s = 0.f;
    int ta = q*125, tb = ta + 125;
    for (int t = ta; t < tb; ++t) s += h[((size_t)b*TT + t)*DIM + d];
    psum[q][d] = s;
    __syncthreads();
    if (q == 0) {
        float pooled = (psum[0][d] + psum[1][d] + psum[2][d] + psum[3][d]) * (1.f / TT);
        float v1 = pooled, v2 = pooled * pooled;
        #pragma unroll
        for (int off = 1; off < 64; off <<= 1) { v1 += __shfl_xor(v1, off); v2 += __shfl_xor(v2, off); }
        int wave = threadIdx.x >> 6, lane = threadIdx.x & 63;
        if (lane == 0) { sm[wave*2] = v1; sm[wave*2+1] = v2; }
        px[d] = pooled;
    }
    __syncthreads();
    if (q == 0) {
        float mean = (sm[0] + sm[2]) * (1.f/128.f);
        float var  = (sm[1] + sm[3]) * (1.f/128.f) - mean*mean;
        px[d] = (px[d] - mean) * rsqrtf(var + 1e-5f) * g[d] + bt[d];
    }
    __syncthreads();
    if (threadIdx.x < NCLS_) {
        float a = cls_b[threadIdx.x];
        for (int i = 0; i < DIM; ++i) a = fmaf(px[i], cls_w[i*NCLS_ + threadIdx.x], a);
        out[b*NCLS_ + threadIdx.x] = a;
    }
}

// ---------------- host ----------------
extern "C" void kernel_launch(void* const* d_in, const int* in_sizes, int n_in,
                              void* d_out, int out_size, void* d_ws, size_t ws_size,
                              hipStream_t stream)
{
    (void)in_sizes; (void)n_in; (void)out_size; (void)ws_size;
    const float* x1      = (const float*)d_in[0];
    const float* proj_w  = (const float*)d_in[1];
    const float* proj_b  = (const float*)d_in[2];
    const float* queries = (const float*)d_in[3];
    const float* fc_w    = (const float*)d_in[4];
    const float* fc_b    = (const float*)d_in[5];
    const float* embed_w = (const float*)d_in[6];
    const float* embed_b = (const float*)d_in[7];
    const float* wqkv    = (const float*)d_in[8];
    const float* bqkv    = (const float*)d_in[9];
    const float* wo      = (const float*)d_in[10];
    const float* bo      = (const float*)d_in[11];
    const float* w1      = (const float*)d_in[12];
    const float* b1      = (const float*)d_in[13];
    const float* w2      = (const float*)d_in[14];
    const float* b2      = (const float*)d_in[15];
    const float* ln1_g   = (const float*)d_in[16];
    const float* ln1_b   = (const float*)d_in[17];
    const float* ln2_g   = (const float*)d_in[18];
    const float* ln2_b   = (const float*)d_in[19];
    const float* rel_t   = (const float*)d_in[20];
    const float* final_g = (const float*)d_in[21];
    const float* final_b = (const float*)d_in[22];
    const float* cls_w   = (const float*)d_in[23];
    const float* cls_b   = (const float*)d_in[24];

    float* ws     = (float*)d_ws;
    float* h      = ws;                                    // MM*128 f32
    ushort_t* hb    = (ushort_t*)(h + (size_t)MM*DIM);     // MM*128 bf16 (enc -> first gemm)
    ushort_t* qkvb  = hb    + (size_t)MM*DIM;              // MM*384 bf16
    ushort_t* attno = qkvb  + (size_t)MM*384;              // MM*128 bf16
    ushort_t* wts   = attno + (size_t)MM*DIM;              // 1179648 bf16
    float* alpha  = (float*)(wts + 1179648);               // 16
    float* Emat   = alpha + 16;                            // 10*128
    float* c0     = Emat + QOUT_*DIM;                      // 128

    enc_pre_kernel<<<1, 128, 0, stream>>>(proj_w, proj_b, queries, fc_w, fc_b,
                                          embed_w, embed_b, alpha, Emat, c0);
    wtrans_kernel<<<288, 256, 0, stream>>>(wqkv, wo, w1, w2, wts);
    enc_kernel<<<MM/4, 256, 0, stream>>>(x1, alpha, Emat, c0, h, hb);

    // first-layer qkv projection (later layers fused into pa)
    gemm_mfma_kernel<128><<<dim3(384/64, MM/128), 256, 0, stream>>>(
        hb, wts, bqkv, qkvb, 384, DIM, 0, 1);

    for (int l = 0; l < NL; ++l) {
        const ushort_t* wo_t   = wts + 294912 + (size_t)l*16384;
        const ushort_t* w1_t   = wts + 393216 + (size_t)l*65536;
        const ushort_t* w2_t   = wts + 786432 + (size_t)l*65536;
        const int lnext = l + 1;
        const int doqkv = (lnext < NL);
        const ushort_t* wqkvN = wts + (size_t)(doqkv ? lnext : 0)*49152;
        const float*    bqkvN = bqkv + (doqkv ? lnext : 0)*3*DIM;

        attn_mfma_kernel<<<BB*NHEADS*4, 512, 0, stream>>>(
            qkvb, rel_t + l*RELLEN, attno);
        pa_kernel<<<MM/32, 256, 0, stream>>>(
            attno, wo_t, bo + l*DIM, w1_t, w2_t, b1 + l*FFD, b2 + l*DIM,
            h, ln1_g + l*DIM, ln1_b + l*DIM, ln2_g + l*DIM, ln2_b + l*DIM,
            wqkvN, bqkvN, qkvb, doqkv);
    }

    final_kernel<<<BB, 512, 0, stream>>>(h, final_g, final_b, cls_w, cls_b, (float*)d_out);
}

// Round 13
// 358.263 us; speedup vs baseline: 1.6318x; 1.0421x over previous
//
#include <hip/hip_runtime.h>
#include <hip/hip_bf16.h>
#include <cmath>

#define NL      6
#define NHEADS  4
#define DIM     128
#define FFD     512
#define CMID_   8
#define COUT_   16
#define QOUT_   10
#define MAXLEN_ 512
#define NCLS_   3
#define BB      32
#define TT      500
#define FIN_    232
#define MM      (BB*TT)
#define HD      32
#define RELLEN  (2*MAXLEN_-1)
#define LOG2E   1.4426950408889634f

typedef __attribute__((ext_vector_type(8))) short short8;
typedef __attribute__((ext_vector_type(4))) float f32x4;
typedef unsigned short ushort_t;

__device__ inline unsigned bf16r(float x) {   // RNE float->bf16 bits (finite inputs)
    unsigned u = __float_as_uint(x);
    return (u + 0x7fffu + ((u >> 16) & 1u)) >> 16;
}

// paired RNE pack via HW v_cvt_pk_bf16_f32
__device__ inline unsigned pkbf16(float a, float b) {
    __hip_bfloat162 h2 = __float22bfloat162_rn(float2{a, b});
    return *reinterpret_cast<unsigned*>(&h2);
}

// async 16B global->LDS DMA: per-lane global src, wave-uniform LDS base + lane*16
__device__ inline void gload16(const ushort_t* g, ushort_t* l) {
    __builtin_amdgcn_global_load_lds(
        (const __attribute__((address_space(1))) unsigned*)g,
        (__attribute__((address_space(3))) unsigned*)l, 16, 0, 0);
}

// ---------------- encoder precompute (1 block) ----------------
__global__ __launch_bounds__(128) void enc_pre_kernel(
    const float* __restrict__ proj_w, const float* __restrict__ proj_b,
    const float* __restrict__ queries, const float* __restrict__ fc_w,
    const float* __restrict__ fc_b, const float* __restrict__ embed_w,
    const float* __restrict__ embed_b,
    float* __restrict__ alpha, float* __restrict__ E, float* __restrict__ c0)
{
    __shared__ float pw[CMID_], cb[CMID_], gam[COUT_], del[COUT_];
    int t = threadIdx.x;
    if (t < CMID_) { pw[t] = proj_w[t]; cb[t] = proj_b[t] + ((t & 1) ? 1.f : 0.f); }
    __syncthreads();
    if (t < QOUT_) {
        float a = 0.f;
        for (int c = 0; c < CMID_; ++c) a += pw[c] * queries[t*CMID_ + c];
        alpha[t] = a;
    }
    if (t < COUT_) {
        float gg = 0.f, dd = 0.f;
        for (int c = 0; c < CMID_; ++c) {
            gg += pw[c] * fc_w[c*COUT_ + t];
            dd += cb[c] * fc_w[c*COUT_ + t];
        }
        gam[t] = gg; del[t] = dd + fc_b[t];
    }
    __syncthreads();
    for (int i = t; i < QOUT_*DIM; i += 128) {
        int q = i / DIM, d = i % DIM;
        float e = 0.f;
        for (int o = 0; o < COUT_; ++o) e += gam[o] * embed_w[(o*QOUT_ + q)*DIM + d];
        E[i] = e;
    }
    {
        float c = embed_b[t];
        for (int o = 0; o < COUT_; ++o) {
            float dl = del[o];
            for (int q = 0; q < QOUT_; ++q) c += dl * embed_w[(o*QOUT_ + q)*DIM + t];
        }
        c0[t] = c;
    }
}

// ---------------- encoder main (4 waves/block, one bt each) ----------------
__global__ __launch_bounds__(256) void enc_kernel(
    const float* __restrict__ x1, const float* __restrict__ alpha,
    const float* __restrict__ E, const float* __restrict__ c0,
    float* __restrict__ h, ushort_t* __restrict__ hb)
{
    int bt = (blockIdx.x << 2) + (threadIdx.x >> 6);
    int lane = threadIdx.x & 63;
    const float* xr = x1 + (size_t)bt * FIN_;
    float xv[4];
    bool vld[4];
    #pragma unroll
    for (int i = 0; i < 4; ++i) {
        int f = lane + (i << 6);
        vld[i] = (f < FIN_);
        xv[i] = vld[i] ? xr[f] : 0.f;
    }
    float vmax = -INFINITY, vmin = INFINITY;
    #pragma unroll
    for (int i = 0; i < 4; ++i) if (vld[i]) { vmax = fmaxf(vmax, xv[i]); vmin = fminf(vmin, xv[i]); }
    #pragma unroll
    for (int off = 1; off < 64; off <<= 1) {
        vmax = fmaxf(vmax, __shfl_xor(vmax, off));
        vmin = fminf(vmin, __shfl_xor(vmin, off));
    }
    float mq[QOUT_];
    for (int q = 0; q < QOUT_; ++q) {
        float a = alpha[q];
        float Mx = (a >= 0.f) ? a * vmax : a * vmin;
        float se = 0.f, sx = 0.f;
        #pragma unroll
        for (int i = 0; i < 4; ++i) if (vld[i]) {
            float e = __expf(fmaf(a, xv[i], -Mx));
            se += e; sx += e * xv[i];
        }
        #pragma unroll
        for (int off = 1; off < 64; off <<= 1) { se += __shfl_xor(se, off); sx += __shfl_xor(sx, off); }
        mq[q] = sx / se;
    }
    #pragma unroll
    for (int k = 0; k < 2; ++k) {
        int d = lane + (k << 6);
        float hv = c0[d];
        #pragma unroll
        for (int q = 0; q < QOUT_; ++q) hv = fmaf(mq[q], E[q*DIM + d], hv);
        h[(size_t)bt*DIM + d] = hv;
        hb[(size_t)bt*DIM + d] = (ushort_t)bf16r(hv);
    }
}

// ---------------- weight transpose + bf16 convert (once per launch) ----------------
__global__ __launch_bounds__(256) void wtrans_kernel(
    const float* __restrict__ wqkv, const float* __restrict__ wo,
    const float* __restrict__ w1, const float* __restrict__ w2,
    ushort_t* __restrict__ wts)
{
    int bid = blockIdx.x;
    const float* W; ushort_t* Wt; int K, N, tk, tn;
    if (bid < 72) {            // wqkv: K=128,N=384 -> 2x6 tiles x 6 layers
        int l = bid / 12, t = bid % 12; tk = t / 6; tn = t % 6; K = 128; N = 384;
        W = wqkv + (size_t)l*128*384; Wt = wts + (size_t)l*49152;
    } else if (bid < 96) {     // wo: 128x128 -> 2x2 x 6
        int q = bid - 72; int l = q / 4, t = q % 4; tk = t / 2; tn = t % 2; K = 128; N = 128;
        W = wo + (size_t)l*16384; Wt = wts + 294912 + (size_t)l*16384;
    } else if (bid < 192) {    // w1: K=128,N=512 -> 2x8 x 6
        int q = bid - 96; int l = q / 16, t = q % 16; tk = t / 8; tn = t % 8; K = 128; N = 512;
        W = w1 + (size_t)l*65536; Wt = wts + 393216 + (size_t)l*65536;
    } else {                   // w2: K=512,N=128 -> 8x2 x 6
        int q = bid - 192; int l = q / 16, t = q % 16; tk = t / 2; tn = t % 2; K = 512; N = 128;
        W = w2 + (size_t)l*65536; Wt = wts + 786432 + (size_t)l*65536;
    }
    int k0 = tk << 6, n0 = tn << 6;
    __shared__ float Ls[64][65];
    int tid = threadIdx.x;
    #pragma unroll
    for (int i = 0; i < 4; ++i) {
        int id = tid + 256*i;
        int r = id >> 4, ch = id & 15;
        float4 v = *reinterpret_cast<const float4*>(W + (size_t)(k0+r)*N + n0 + ch*4);
        Ls[ch*4+0][r] = v.x; Ls[ch*4+1][r] = v.y; Ls[ch*4+2][r] = v.z; Ls[ch*4+3][r] = v.w;
    }
    __syncthreads();
    #pragma unroll
    for (int i = 0; i < 4; ++i) {
        int id = tid + 256*i;
        int rr = id >> 4, ch = id & 15;
        uint2 o2;
        o2.x = pkbf16(Ls[rr][ch*4+0], Ls[rr][ch*4+1]);
        o2.y = pkbf16(Ls[rr][ch*4+2], Ls[rr][ch*4+3]);
        *reinterpret_cast<uint2*>(Wt + (size_t)(n0+rr)*K + k0 + ch*4) = o2;
    }
}

// ---------------- bf16 MFMA GEMM (first-layer qkv projection only) ----------
template<int BM>
__global__ __launch_bounds__(256) void gemm_mfma_kernel(
    const ushort_t* __restrict__ A, const ushort_t* __restrict__ Wt,
    const float* __restrict__ bias, void* __restrict__ C,
    int N, int K, int relu, int obf16)
{
    constexpr int MREP = BM / 32;
    constexpr int ASEG = BM / 32;
    __shared__ __align__(16) ushort_t As[BM * 64];
    __shared__ __align__(16) ushort_t Bs[64 * 64];
    const int tid = threadIdx.x;
    const int row0 = blockIdx.y * BM, col0 = blockIdx.x << 6;
    const int w = tid >> 6, lane = tid & 63, g = lane >> 4, n = lane & 15;
    const int wr = w & 1, wc = w >> 1;
    f32x4 acc[MREP][2];
    #pragma unroll
    for (int mt = 0; mt < MREP; ++mt)
        #pragma unroll
        for (int nt = 0; nt < 2; ++nt) acc[mt][nt] = (f32x4){0.f,0.f,0.f,0.f};

    for (int k0 = 0; k0 < K; k0 += 64) {
        __syncthreads();
        #pragma unroll
        for (int j = 0; j < ASEG; ++j) {
            int seg = w*ASEG + j;
            int id = seg*64 + lane;
            int r = id >> 3, cp = id & 7;
            gload16(A + (size_t)(row0 + r)*K + k0 + ((cp ^ (r & 7)) << 3),
                    As + seg*512);
        }
        #pragma unroll
        for (int j = 0; j < 2; ++j) {
            int seg = w*2 + j;
            int id = seg*64 + lane;
            int r = id >> 3, cp = id & 7;
            gload16(Wt + (size_t)(col0 + r)*K + k0 + ((cp ^ (r & 7)) << 3),
                    Bs + seg*512);
        }
        __syncthreads();
        #pragma unroll
        for (int ks = 0; ks < 2; ++ks) {
            short8 af[MREP], bfr[2];
            #pragma unroll
            for (int mt = 0; mt < MREP; ++mt) {
                int r = wr*(BM/2) + mt*16 + n;
                af[mt] = *reinterpret_cast<const short8*>(As + r*64 + (((ks*4 + g) ^ (r & 7)) << 3));
            }
            #pragma unroll
            for (int nt = 0; nt < 2; ++nt) {
                int r = wc*32 + nt*16 + n;
                bfr[nt] = *reinterpret_cast<const short8*>(Bs + r*64 + (((ks*4 + g) ^ (r & 7)) << 3));
            }
            #pragma unroll
            for (int mt = 0; mt < MREP; ++mt)
                #pragma unroll
                for (int nt = 0; nt < 2; ++nt)
                    acc[mt][nt] = __builtin_amdgcn_mfma_f32_16x16x32_bf16(af[mt], bfr[nt], acc[mt][nt], 0, 0, 0);
        }
    }
    #pragma unroll
    for (int mt = 0; mt < MREP; ++mt) {
        #pragma unroll
        for (int nt = 0; nt < 2; ++nt) {
            int col = col0 + wc*32 + nt*16 + n;
            float bv = bias[col];
            #pragma unroll
            for (int r4 = 0; r4 < 4; ++r4) {
                int row = row0 + wr*(BM/2) + mt*16 + g*4 + r4;
                float v = acc[mt][nt][r4] + bv;
                if (relu) v = fmaxf(v, 0.f);
                if (obf16) ((ushort_t*)C)[(size_t)row*N + col] = (ushort_t)bf16r(v);
                else       ((float*)C)[(size_t)row*N + col] = v;
            }
        }
    }
}

// ---------------- MFMA bf16 flash attention (QBLK=128, KVBLK=128, exp2) ----------------
// grid: B*NHEADS*4 blocks, 512 threads = 8 waves x 16 q-rows each.
__global__ __launch_bounds__(512) void attn_mfma_kernel(
    const ushort_t* __restrict__ qkv, const float* __restrict__ rel,
    ushort_t* __restrict__ o)
{
    __shared__ __align__(16) ushort_t Ks[128][40];          // [kcol][dim] 80B rows
    __shared__ __align__(16) ushort_t Vs[128][40];          // [kcol][dim] 80B rows
    __shared__ __align__(16) ushort_t VB[4][2][4][16][8];   // [kch][dimhalf][g][n][j]
    __shared__ float rl[RELLEN];
    const int bid = blockIdx.x;
    const int qt = bid & 3;
    const int bh = bid >> 2;
    const int hh = bh & 3, b = bh >> 2;
    const int tid  = threadIdx.x;
    const int w    = tid >> 6;
    const int lane = tid & 63;
    const int g = lane >> 4, n = lane & 15;
    for (int i = tid; i < RELLEN; i += 512) rl[i] = rel[i] * LOG2E;

    const int qrow = (qt << 7) + (w << 4) + n;
    const bool qv = (qrow < TT);
    short8 qf = {0,0,0,0,0,0,0,0};
    if (qv) qf = *reinterpret_cast<const short8*>(qkv + (size_t)(b*TT + qrow)*384 + hh*HD + g*8);

    f32x4 acc0 = {0.f,0.f,0.f,0.f}, acc1 = {0.f,0.f,0.f,0.f};
    float m = -INFINITY, lsum = 0.f;
    const float scale2 = 0.17677669529663687f * LOG2E;
    const f32x4 zf = {0.f,0.f,0.f,0.f};

    const int sr = tid >> 2, sc = tid & 3;      // stage: 128 rows x 4 chunks of 16B

    auto tile = [&](const int kt, const bool domask) {
        const int k0 = kt << 7;
        __syncthreads();                        // prev tile fully consumed
        {
            int t = k0 + sr;
            uint4 kvv = make_uint4(0,0,0,0), vvv = make_uint4(0,0,0,0);
            if (!domask || t < TT) {
                const ushort_t* bp = qkv + (size_t)(b*TT + t)*384 + hh*HD + sc*8;
                kvv = *reinterpret_cast<const uint4*>(bp + 128);
                vvv = *reinterpret_cast<const uint4*>(bp + 256);
            }
            *reinterpret_cast<uint4*>(&Ks[sr][sc*8]) = kvv;
            *reinterpret_cast<uint4*>(&Vs[sr][sc*8]) = vvv;
        }
        __syncthreads();

        // V relayout into fragment-linear VB (8 elems/thread, 512 threads)
        #pragma unroll
        for (int i = 0; i < 2; ++i) {
            int id = tid + (i << 9);
            int jh = (id & 1)*4, nn = (id >> 1) & 15, gg = (id >> 5) & 3;
            int dh = (id >> 7) & 1, kch = (id >> 8) & 3;
            ushort_t tmp[4];
            #pragma unroll
            for (int j = 0; j < 4; ++j) tmp[j] = Vs[kch*32 + gg*8 + jh + j][dh*16 + nn];
            *reinterpret_cast<uint2*>(&VB[kch][dh][gg][nn][jh]) = *reinterpret_cast<uint2*>(tmp);
        }

        // S^T = K . Q^T : 8 tiles of 16 kcols, in two halves (register pressure)
        float sv[32];
        float tmax = -INFINITY;
        #pragma unroll
        for (int half = 0; half < 2; ++half) {
            f32x4 s[4];
            #pragma unroll
            for (int c = 0; c < 4; ++c) {
                int cc = half*4 + c;
                short8 ak = *reinterpret_cast<const short8*>(&Ks[cc*16 + n][g*8]);
                s[c] = __builtin_amdgcn_mfma_f32_16x16x32_bf16(ak, qf, zf, 0, 0, 0);
            }
            #pragma unroll
            for (int c = 0; c < 4; ++c)
                #pragma unroll
                for (int r = 0; r < 4; ++r) {
                    int kc = k0 + (half*4 + c)*16 + g*4 + r;
                    float bia = rl[kc - qrow + (MAXLEN_-1)];
                    float v = fmaf(s[c][r], scale2, bia);
                    if (domask && kc >= TT) v = -1e30f;
                    sv[(half*4 + c)*4 + r] = v;
                    tmax = fmaxf(tmax, v);
                }
        }
        tmax = fmaxf(tmax, __shfl_xor(tmax, 16));
        tmax = fmaxf(tmax, __shfl_xor(tmax, 32));
        float mnew = fmaxf(m, tmax);
        float corr = exp2f(m - mnew);
        m = mnew;
        float ps = 0.f;
        #pragma unroll
        for (int r = 0; r < 32; ++r) { float e = exp2f(sv[r] - mnew); sv[r] = e; ps += e; }
        ps += __shfl_xor(ps, 16);
        ps += __shfl_xor(ps, 32);
        lsum = fmaf(lsum, corr, ps);

        // pack + exchange: 4 chains of 32 kcols each
        int src0 = n + ((g & 1) << 5);
        int src1 = src0 + 16;
        int t0 = (g < 2);
        short8 Pv[4];
        #pragma unroll
        for (int cch = 0; cch < 4; ++cch) {
            unsigned pk0lo = pkbf16(sv[cch*8+0], sv[cch*8+1]);
            unsigned pk0hi = pkbf16(sv[cch*8+2], sv[cch*8+3]);
            unsigned pk1lo = pkbf16(sv[cch*8+4], sv[cch*8+5]);
            unsigned pk1hi = pkbf16(sv[cch*8+6], sv[cch*8+7]);
            unsigned a0 = __shfl((int)pk0lo, src0), c0_ = __shfl((int)pk1lo, src0);
            unsigned a1 = __shfl((int)pk0hi, src0), c1_ = __shfl((int)pk1hi, src0);
            unsigned a2 = __shfl((int)pk0lo, src1), c2_ = __shfl((int)pk1lo, src1);
            unsigned a3 = __shfl((int)pk0hi, src1), c3_ = __shfl((int)pk1hi, src1);
            union { unsigned wd[4]; short8 v; } P;
            P.wd[0] = t0 ? a0 : c0_; P.wd[1] = t0 ? a1 : c1_;
            P.wd[2] = t0 ? a2 : c2_; P.wd[3] = t0 ? a3 : c3_;
            Pv[cch] = P.v;
        }

        #pragma unroll
        for (int r = 0; r < 4; ++r) { acc0[r] *= corr; acc1[r] *= corr; }
        #pragma unroll
        for (int kch = 0; kch < 4; ++kch) {
            short8 av0 = *reinterpret_cast<const short8*>(&VB[kch][0][g][n][0]);
            short8 av1 = *reinterpret_cast<const short8*>(&VB[kch][1][g][n][0]);
            acc0 = __builtin_amdgcn_mfma_f32_16x16x32_bf16(av0, Pv[kch], acc0, 0, 0, 0);
            acc1 = __builtin_amdgcn_mfma_f32_16x16x32_bf16(av1, Pv[kch], acc1, 0, 0, 0);
        }
    };

    for (int kt = 0; kt < 3; ++kt) tile(kt, false);   // kcols 0..383 < 500
    tile(3, true);                                    // kcols 384..511 masked

    if (qv) {
        float inv = 1.f / lsum;
        uint2 p0, p1;
        p0.x = pkbf16(acc0[0]*inv, acc0[1]*inv);
        p0.y = pkbf16(acc0[2]*inv, acc0[3]*inv);
        p1.x = pkbf16(acc1[0]*inv, acc1[1]*inv);
        p1.y = pkbf16(acc1[2]*inv, acc1[3]*inv);
        ushort_t* op = o + (size_t)(b*TT + qrow)*DIM + hh*HD + g*4;
        *reinterpret_cast<uint2*>(op)      = p0;
        *reinterpret_cast<uint2*>(op + 16) = p1;
    }
}

// ------- fused post-attention (T3 2-phase ping-pong weight staging) ----------
// wo GEMM + LN1 + merged FFN (per-chunk Mid) + LN2 + next-layer qkv.
__global__ __launch_bounds__(256) void pa_kernel(
    const ushort_t* __restrict__ attno, const ushort_t* __restrict__ wot,
    const float* __restrict__ bo, const ushort_t* __restrict__ W1t,
    const ushort_t* __restrict__ W2t, const float* __restrict__ b1v,
    const float* __restrict__ b2v, float* __restrict__ h,
    const float* __restrict__ ln1g, const float* __restrict__ ln1b,
    const float* __restrict__ ln2g, const float* __restrict__ ln2b,
    const ushort_t* __restrict__ wqkvN, const float* __restrict__ bqkvN,
    ushort_t* __restrict__ qkvout, int doqkv)
{
    __shared__ __align__(16) ushort_t As[32 * 128];     // 8 KB: attno, LN1 y, then LN2 y
    __shared__ __align__(16) ushort_t Wb0[8192];        // 16 KB ping
    __shared__ __align__(16) ushort_t Wb1[8192];        // 16 KB pong
    __shared__ __align__(16) ushort_t Mid[32 * 64];     // 4 KB (one k1-chunk)
    __shared__ float Hres[32 * 132];                    // 16.9 KB, padded rows
    __shared__ float red[4][32][2];
    __shared__ float stats[32][2];
    const int tid = threadIdx.x;
    const int row0 = blockIdx.x << 5;
    const int w = tid >> 6, lane = tid & 63, g = lane >> 4, n = lane & 15;

    // staging lambdas: per-lane swizzled global src -> linear LDS dest
    auto stageWo = [&](ushort_t* buf, int k0) {         // [128 n][64 k]
        #pragma unroll
        for (int j = 0; j < 4; ++j) {
            int seg = w*4 + j;
            int id = seg*64 + lane;
            int r = id >> 3, cp = id & 7;
            gload16(wot + (size_t)r*DIM + k0 + ((cp ^ (r & 7)) << 3), buf + seg*512);
        }
    };
    auto stageW1 = [&](ushort_t* buf, int cc) {         // [64 k1][128 k]
        #pragma unroll
        for (int j = 0; j < 4; ++j) {
            int seg = w*4 + j;
            int id = seg*64 + lane;
            int r = id >> 4, cp = id & 15;
            gload16(W1t + (size_t)(cc*64 + r)*DIM + ((cp ^ (r & 7)) << 3), buf + seg*512);
        }
    };
    auto stageW2 = [&](ushort_t* buf, int kc) {         // [128 c][64 k1]
        #pragma unroll
        for (int j = 0; j < 4; ++j) {
            int seg = w*4 + j;
            int id = seg*64 + lane;
            int r = id >> 3, cp = id & 7;
            gload16(W2t + (size_t)r*FFD + kc*64 + ((cp ^ (r & 7)) << 3), buf + seg*512);
        }
    };
    auto stageQ = [&](ushort_t* buf, int c) {           // [64 qcol][128 k]
        #pragma unroll
        for (int j = 0; j < 4; ++j) {
            int seg = w*4 + j;
            int id = seg*64 + lane;
            int r = id >> 4, cp = id & 15;
            gload16(wqkvN + (size_t)(c*64 + r)*DIM + ((cp ^ (r & 7)) << 3), buf + seg*512);
        }
    };

    // prologue: attno tile + wo chunk0
    #pragma unroll
    for (int j = 0; j < 2; ++j) {
        int seg = w*2 + j;
        int id = seg*64 + lane;
        int r = id >> 4, cp = id & 15;
        gload16(attno + (size_t)(row0 + r)*DIM + ((cp ^ (r & 7)) << 3), As + seg*512);
    }
    stageWo(Wb0, 0);
    __syncthreads();

    // ---- phase A: wo GEMM (K=128), 2 chunks ----
    f32x4 acc[2][2];
    #pragma unroll
    for (int a = 0; a < 2; ++a)
        #pragma unroll
        for (int b = 0; b < 2; ++b) acc[a][b] = (f32x4){0.f,0.f,0.f,0.f};
    #pragma unroll
    for (int ph = 0; ph < 2; ++ph) {
        // issue next chunk, then compute current (loads fly under MFMA)
        if (ph == 0) stageWo(Wb1, 64); else stageW1(Wb0, 0);
        const ushort_t* buf = (ph == 0) ? Wb0 : Wb1;
        int k0 = ph << 6;
        #pragma unroll
        for (int ks = 0; ks < 2; ++ks) {
            short8 af[2], bfr[2];
            #pragma unroll
            for (int mt = 0; mt < 2; ++mt) {
                int r = mt*16 + n;
                int ch = (k0 >> 3) + ks*4 + g;
                af[mt] = *reinterpret_cast<const short8*>(As + r*128 + ((ch ^ (r & 7)) << 3));
            }
            #pragma unroll
            for (int nt = 0; nt < 2; ++nt) {
                int r = w*32 + nt*16 + n;
                bfr[nt] = *reinterpret_cast<const short8*>(buf + r*64 + (((ks*4 + g) ^ (r & 7)) << 3));
            }
            #pragma unroll
            for (int mt = 0; mt < 2; ++mt)
                #pragma unroll
                for (int nt = 0; nt < 2; ++nt)
                    acc[mt][nt] = __builtin_amdgcn_mfma_f32_16x16x32_bf16(af[mt], bfr[nt], acc[mt][nt], 0, 0, 0);
        }
        __syncthreads();
    }
    // epilogue A: bias + residual + LN1 -> Hres (f32) + As (bf16); W1_0 DMA flies under it
    {
        float vals[2][2][4];
        #pragma unroll
        for (int nt = 0; nt < 2; ++nt) {
            int col = w*32 + nt*16 + n;
            float bv = bo[col];
            #pragma unroll
            for (int mt = 0; mt < 2; ++mt)
                #pragma unroll
                for (int r4 = 0; r4 < 4; ++r4) {
                    int row = row0 + mt*16 + g*4 + r4;
                    vals[mt][nt][r4] = acc[mt][nt][r4] + bv + h[(size_t)row*DIM + col];
                }
        }
        #pragma unroll
        for (int mt = 0; mt < 2; ++mt)
            #pragma unroll
            for (int r4 = 0; r4 < 4; ++r4) {
                float s  = vals[mt][0][r4] + vals[mt][1][r4];
                float s2 = vals[mt][0][r4]*vals[mt][0][r4] + vals[mt][1][r4]*vals[mt][1][r4];
                #pragma unroll
                for (int off = 1; off < 16; off <<= 1) {
                    s  += __shfl_xor(s, off);
                    s2 += __shfl_xor(s2, off);
                }
                if (n == 0) { red[w][mt*16 + g*4 + r4][0] = s; red[w][mt*16 + g*4 + r4][1] = s2; }
            }
        __syncthreads();
        if (tid < 32) {
            float s = 0.f, s2 = 0.f;
            #pragma unroll
            for (int ww = 0; ww < 4; ++ww) { s += red[ww][tid][0]; s2 += red[ww][tid][1]; }
            float mean = s * (1.f/128.f);
            float var  = s2 * (1.f/128.f) - mean*mean;
            stats[tid][0] = mean;
            stats[tid][1] = rsqrtf(var + 1e-5f);
        }
        __syncthreads();
        #pragma unroll
        for (int nt = 0; nt < 2; ++nt) {
            int col = w*32 + nt*16 + n;
            int ch = col >> 3, off8 = col & 7;
            float gv = ln1g[col], bv = ln1b[col];
            #pragma unroll
            for (int mt = 0; mt < 2; ++mt)
                #pragma unroll
                for (int r4 = 0; r4 < 4; ++r4) {
                    int rloc = mt*16 + g*4 + r4;
                    float y = (vals[mt][nt][r4] - stats[rloc][0]) * stats[rloc][1] * gv + bv;
                    Hres[rloc*132 + col] = y;
                    As[rloc*128 + ((ch ^ (rloc & 7)) << 3) + off8] = (ushort_t)bf16r(y);
                }
        }
    }
    __syncthreads();    // As(LN1) visible; W1_0 drained

    // ---- merged FFN: per k1-chunk {Mid_c = relu(As@W1_c+b1c); oacc += Mid_c@W2_c} ----
    f32x4 oacc[2][2];
    #pragma unroll
    for (int a = 0; a < 2; ++a)
        #pragma unroll
        for (int b = 0; b < 2; ++b) oacc[a][b] = (f32x4){0.f,0.f,0.f,0.f};
    for (int cc = 0; cc < 8; ++cc) {
        // sub-phase 1: issue W2_c -> Wb1; compute Mid_c from W1_c (Wb0)
        stageW2(Wb1, cc);
        {
            f32x4 acc1[2] = {{0.f,0.f,0.f,0.f},{0.f,0.f,0.f,0.f}};
            #pragma unroll
            for (int ks = 0; ks < 4; ++ks) {
                int rW = w*16 + n;
                short8 aw = *reinterpret_cast<const short8*>(Wb0 + rW*128 + (((ks*4 + g) ^ (rW & 7)) << 3));
                #pragma unroll
                for (int mt = 0; mt < 2; ++mt) {
                    int rA = mt*16 + n;
                    short8 bh_ = *reinterpret_cast<const short8*>(As + rA*128 + (((ks*4 + g) ^ (rA & 7)) << 3));
                    acc1[mt] = __builtin_amdgcn_mfma_f32_16x16x32_bf16(aw, bh_, acc1[mt], 0, 0, 0);
                }
            }
            int k1loc = w*16 + g*4;
            float4 bb = *reinterpret_cast<const float4*>(b1v + cc*64 + k1loc);
            int chloc = k1loc >> 3;
            int halfoff = (g & 1) * 4;
            #pragma unroll
            for (int mt = 0; mt < 2; ++mt) {
                int mrow = mt*16 + n;
                float v0 = fmaxf(acc1[mt][0] + bb.x, 0.f);
                float v1 = fmaxf(acc1[mt][1] + bb.y, 0.f);
                float v2 = fmaxf(acc1[mt][2] + bb.z, 0.f);
                float v3 = fmaxf(acc1[mt][3] + bb.w, 0.f);
                uint2 pk;
                pk.x = pkbf16(v0, v1);
                pk.y = pkbf16(v2, v3);
                *reinterpret_cast<uint2*>(Mid + mrow*64 + ((chloc ^ (mrow & 7)) << 3) + halfoff) = pk;
            }
        }
        __syncthreads();    // W2_c drained; Mid_c visible; Wb0 free

        // sub-phase 2: issue W1_{c+1} (or q0) -> Wb0; compute oacc += Mid_c @ W2_c (Wb1)
        if (cc < 7) stageW1(Wb0, cc + 1);
        else if (doqkv) stageQ(Wb0, 0);
        #pragma unroll
        for (int ks = 0; ks < 2; ++ks) {
            short8 aw[2], bm[2];
            #pragma unroll
            for (int ct = 0; ct < 2; ++ct) {
                int r = w*32 + ct*16 + n;
                aw[ct] = *reinterpret_cast<const short8*>(Wb1 + r*64 + (((ks*4 + g) ^ (r & 7)) << 3));
            }
            #pragma unroll
            for (int mt = 0; mt < 2; ++mt) {
                int r = mt*16 + n;
                bm[mt] = *reinterpret_cast<const short8*>(Mid + r*64 + (((ks*4 + g) ^ (r & 7)) << 3));
            }
            #pragma unroll
            for (int ct = 0; ct < 2; ++ct)
                #pragma unroll
                for (int mt = 0; mt < 2; ++mt)
                    oacc[ct][mt] = __builtin_amdgcn_mfma_f32_16x16x32_bf16(aw[ct], bm[mt], oacc[ct][mt], 0, 0, 0);
        }
        __syncthreads();    // W1_{c+1}/q0 drained; Mid free for overwrite
    }

    // epilogue B: bias + residual(Hres) + LN2 -> h (f32 global) + As (bf16 LDS)
    float vals[2][2][4];
    #pragma unroll
    for (int ct = 0; ct < 2; ++ct) {
        int colb = w*32 + ct*16 + g*4;
        float4 bb = *reinterpret_cast<const float4*>(b2v + colb);
        #pragma unroll
        for (int mt = 0; mt < 2; ++mt) {
            int rloc = mt*16 + n;
            float4 hres = *reinterpret_cast<const float4*>(&Hres[rloc*132 + colb]);
            vals[ct][mt][0] = oacc[ct][mt][0] + bb.x + hres.x;
            vals[ct][mt][1] = oacc[ct][mt][1] + bb.y + hres.y;
            vals[ct][mt][2] = oacc[ct][mt][2] + bb.z + hres.z;
            vals[ct][mt][3] = oacc[ct][mt][3] + bb.w + hres.w;
        }
    }
    #pragma unroll
    for (int mt = 0; mt < 2; ++mt) {
        float s = 0.f, s2 = 0.f;
        #pragma unroll
        for (int ct = 0; ct < 2; ++ct)
            #pragma unroll
            for (int r4 = 0; r4 < 4; ++r4) { float v = vals[ct][mt][r4]; s += v; s2 += v*v; }
        s  += __shfl_xor(s, 16);  s  += __shfl_xor(s, 32);
        s2 += __shfl_xor(s2, 16); s2 += __shfl_xor(s2, 32);
        if (g == 0) { red[w][mt*16 + n][0] = s; red[w][mt*16 + n][1] = s2; }
    }
    __syncthreads();
    if (tid < 32) {
        float s = 0.f, s2 = 0.f;
        #pragma unroll
        for (int ww = 0; ww < 4; ++ww) { s += red[ww][tid][0]; s2 += red[ww][tid][1]; }
        float mean = s * (1.f/128.f);
        float var  = s2 * (1.f/128.f) - mean*mean;
        stats[tid][0] = mean;
        stats[tid][1] = rsqrtf(var + 1e-5f);
    }
    __syncthreads();
    #pragma unroll
    for (int ct = 0; ct < 2; ++ct) {
        int colb = w*32 + ct*16 + g*4;
        float4 gv = *reinterpret_cast<const float4*>(ln2g + colb);
        float4 bv = *reinterpret_cast<const float4*>(ln2b + colb);
        int ch = colb >> 3;
        int halfoff = (g & 1) * 4;
        #pragma unroll
        for (int mt = 0; mt < 2; ++mt) {
            int rloc = mt*16 + n;
            int mrow = row0 + rloc;
            float mean = stats[rloc][0], rstd = stats[rloc][1];
            float y0 = (vals[ct][mt][0] - mean) * rstd * gv.x + bv.x;
            float y1 = (vals[ct][mt][1] - mean) * rstd * gv.y + bv.y;
            float y2 = (vals[ct][mt][2] - mean) * rstd * gv.z + bv.z;
            float y3 = (vals[ct][mt][3] - mean) * rstd * gv.w + bv.w;
            float4 yo = {y0, y1, y2, y3};
            *reinterpret_cast<float4*>(h + (size_t)mrow*DIM + colb) = yo;
            uint2 pk;
            pk.x = pkbf16(y0, y1);
            pk.y = pkbf16(y2, y3);
            *reinterpret_cast<uint2*>(As + rloc*128 + ((ch ^ (rloc & 7)) << 3) + halfoff) = pk;
        }
    }
    __syncthreads();    // As(LN2) visible; q0 drained

    // ---- phase C: next-layer qkv projection (ping-pong continues) ----
    if (doqkv) {
        for (int c6 = 0; c6 < 6; ++c6) {
            ushort_t* cur = (c6 & 1) ? Wb1 : Wb0;
            ushort_t* nxt = (c6 & 1) ? Wb0 : Wb1;
            if (c6 < 5) stageQ(nxt, c6 + 1);
            f32x4 qacc[2] = {{0.f,0.f,0.f,0.f},{0.f,0.f,0.f,0.f}};
            #pragma unroll
            for (int ks = 0; ks < 4; ++ks) {
                int rW = w*16 + n;
                short8 aw = *reinterpret_cast<const short8*>(cur + rW*128 + (((ks*4 + g) ^ (rW & 7)) << 3));
                #pragma unroll
                for (int mt = 0; mt < 2; ++mt) {
                    int rA = mt*16 + n;
                    short8 bh_ = *reinterpret_cast<const short8*>(As + rA*128 + (((ks*4 + g) ^ (rA & 7)) << 3));
                    qacc[mt] = __builtin_amdgcn_mfma_f32_16x16x32_bf16(aw, bh_, qacc[mt], 0, 0, 0);
                }
            }
            int colb = c6*64 + w*16 + g*4;
            float4 bb = *reinterpret_cast<const float4*>(bqkvN + colb);
            #pragma unroll
            for (int mt = 0; mt < 2; ++mt) {
                int mrow = row0 + mt*16 + n;
                uint2 pk;
                pk.x = pkbf16(qacc[mt][0] + bb.x, qacc[mt][1] + bb.y);
                pk.y = pkbf16(qacc[mt][2] + bb.z, qacc[mt][3] + bb.w);
                *reinterpret_cast<uint2*>(qkvout + (size_t)mrow*384 + colb) = pk;
            }
            if (c6 < 5) __syncthreads();
        }
    }
}

// ---------------- mean-pool + LN + classifier (4-way split pooling) ----------------
__global__ __launch_bounds__(512) void final_kernel(
    const float* __restrict__ h, const float* __restrict__ g,
    const float* __restrict__ bt, const float* __restrict__ cls_w,
    const float* __restrict__ cls_b, float* __restrict__ out)
{
    int b = blockIdx.x;
    int d = threadIdx.x & 127, q = threadIdx.x >> 7;
    __shared__ float psum[4][128];
    __shared__ float sm[4];
    __shared__ float px[DIM];
    float s = 0.f;
    int ta = q*125, tb = ta + 125;
    for (int t = ta; t < tb; ++t) s += h[((size_t)b*TT + t)*DIM + d];
    psum[q][d] = s;
    __syncthreads();
    if (q == 0) {
        float pooled = (psum[0][d] + psum[1][d] + psum[2][d] + psum[3][d]) * (1.f / TT);
        float v1 = pooled, v2 = pooled * pooled;
        #pragma unroll
        for (int off = 1; off < 64; off <<= 1) { v1 += __shfl_xor(v1, off); v2 += __shfl_xor(v2, off); }
        int wave = threadIdx.x >> 6, lane = threadIdx.x & 63;
        if (lane == 0) { sm[wave*2] = v1; sm[wave*2+1] = v2; }
        px[d] = pooled;
    }
    __syncthreads();
    if (q == 0) {
        float mean = (sm[0] + sm[2]) * (1.f/128.f);
        float var  = (sm[1] + sm[3]) * (1.f/128.f) - mean*mean;
        px[d] = (px[d] - mean) * rsqrtf(var + 1e-5f) * g[d] + bt[d];
    }
    __syncthreads();
    if (threadIdx.x < NCLS_) {
        float a = cls_b[threadIdx.x];
        for (int i = 0; i < DIM; ++i) a = fmaf(px[i], cls_w[i*NCLS_ + threadIdx.x], a);
        out[b*NCLS_ + threadIdx.x] = a;
    }
}

// ---------------- host ----------------
extern "C" void kernel_launch(void* const* d_in, const int* in_sizes, int n_in,
                              void* d_out, int out_size, void* d_ws, size_t ws_size,
                              hipStream_t stream)
{
    (void)in_sizes; (void)n_in; (void)out_size; (void)ws_size;
    const float* x1      = (const float*)d_in[0];
    const float* proj_w  = (const float*)d_in[1];
    const float* proj_b  = (const float*)d_in[2];
    const float* queries = (const float*)d_in[3];
    const float* fc_w    = (const float*)d_in[4];
    const float* fc_b    = (const float*)d_in[5];
    const float* embed_w = (const float*)d_in[6];
    const float* embed_b = (const float*)d_in[7];
    const float* wqkv    = (const float*)d_in[8];
    const float* bqkv    = (const float*)d_in[9];
    const float* wo      = (const float*)d_in[10];
    const float* bo      = (const float*)d_in[11];
    const float* w1      = (const float*)d_in[12];
    const float* b1      = (const float*)d_in[13];
    const float* w2      = (const float*)d_in[14];
    const float* b2      = (const float*)d_in[15];
    const float* ln1_g   = (const float*)d_in[16];
    const float* ln1_b   = (const float*)d_in[17];
    const float* ln2_g   = (const float*)d_in[18];
    const float* ln2_b   = (const float*)d_in[19];
    const float* rel_t   = (const float*)d_in[20];
    const float* final_g = (const float*)d_in[21];
    const float* final_b = (const float*)d_in[22];
    const float* cls_w   = (const float*)d_in[23];
    const float* cls_b   = (const float*)d_in[24];

    float* ws     = (float*)d_ws;
    float* h      = ws;                                    // MM*128 f32
    ushort_t* hb    = (ushort_t*)(h + (size_t)MM*DIM);     // MM*128 bf16 (enc -> first gemm)
    ushort_t* qkvb  = hb    + (size_t)MM*DIM;              // MM*384 bf16
    ushort_t* attno = qkvb  + (size_t)MM*384;              // MM*128 bf16
    ushort_t* wts   = attno + (size_t)MM*DIM;              // 1179648 bf16
    float* alpha  = (float*)(wts + 1179648);               // 16
    float* Emat   = alpha + 16;                            // 10*128
    float* c0     = Emat + QOUT_*DIM;                      // 128

    enc_pre_kernel<<<1, 128, 0, stream>>>(proj_w, proj_b, queries, fc_w, fc_b,
                                          embed_w, embed_b, alpha, Emat, c0);
    wtrans_kernel<<<288, 256, 0, stream>>>(wqkv, wo, w1, w2, wts);
    enc_kernel<<<MM/4, 256, 0, stream>>>(x1, alpha, Emat, c0, h, hb);

    // first-layer qkv projection (later layers fused into pa)
    gemm_mfma_kernel<128><<<dim3(384/64, MM/128), 256, 0, stream>>>(
        hb, wts, bqkv, qkvb, 384, DIM, 0, 1);

    for (int l = 0; l < NL; ++l) {
        const ushort_t* wo_t   = wts + 294912 + (size_t)l*16384;
        const ushort_t* w1_t   = wts + 393216 + (size_t)l*65536;
        const ushort_t* w2_t   = wts + 786432 + (size_t)l*65536;
        const int lnext = l + 1;
        const int doqkv = (lnext < NL);
        const ushort_t* wqkvN = wts + (size_t)(doqkv ? lnext : 0)*49152;
        const float*    bqkvN = bqkv + (doqkv ? lnext : 0)*3*DIM;

        attn_mfma_kernel<<<BB*NHEADS*4, 512, 0, stream>>>(
            qkvb, rel_t + l*RELLEN, attno);
        pa_kernel<<<MM/32, 256, 0, stream>>>(
            attno, wo_t, bo + l*DIM, w1_t, w2_t, b1 + l*FFD, b2 + l*DIM,
            h, ln1_g + l*DIM, ln1_b + l*DIM, ln2_g + l*DIM, ln2_b + l*DIM,
            wqkvN, bqkvN, qkvb, doqkv);
    }

    final_kernel<<<BB, 512, 0, stream>>>(h, final_g, final_b, cls_w, cls_b, (float*)d_out);
}

// Round 14
// 347.900 us; speedup vs baseline: 1.6804x; 1.0298x over previous
//
#include <hip/hip_runtime.h>
#include <hip/hip_bf16.h>
#include <cmath>

#define NL      6
#define NHEADS  4
#define DIM     128
#define FFD     512
#define CMID_   8
#define COUT_   16
#define QOUT_   10
#define MAXLEN_ 512
#define NCLS_   3
#define BB      32
#define TT      500
#define FIN_    232
#define MM      (BB*TT)
#define HD      32
#define RELLEN  (2*MAXLEN_-1)
#define LOG2E   1.4426950408889634f

typedef __attribute__((ext_vector_type(8))) short short8;
typedef __attribute__((ext_vector_type(4))) float f32x4;
typedef unsigned short ushort_t;

__device__ inline unsigned bf16r(float x) {   // RNE float->bf16 bits (finite inputs)
    unsigned u = __float_as_uint(x);
    return (u + 0x7fffu + ((u >> 16) & 1u)) >> 16;
}

// paired RNE pack via HW v_cvt_pk_bf16_f32
__device__ inline unsigned pkbf16(float a, float b) {
    __hip_bfloat162 h2 = __float22bfloat162_rn(float2{a, b});
    return *reinterpret_cast<unsigned*>(&h2);
}

// async 16B global->LDS DMA: per-lane global src, wave-uniform LDS base + lane*16
__device__ inline void gload16(const ushort_t* g, ushort_t* l) {
    __builtin_amdgcn_global_load_lds(
        (const __attribute__((address_space(1))) unsigned*)g,
        (__attribute__((address_space(3))) unsigned*)l, 16, 0, 0);
}

// ---------------- encoder precompute (1 block) ----------------
__global__ __launch_bounds__(128) void enc_pre_kernel(
    const float* __restrict__ proj_w, const float* __restrict__ proj_b,
    const float* __restrict__ queries, const float* __restrict__ fc_w,
    const float* __restrict__ fc_b, const float* __restrict__ embed_w,
    const float* __restrict__ embed_b,
    float* __restrict__ alpha, float* __restrict__ E, float* __restrict__ c0)
{
    __shared__ float pw[CMID_], cb[CMID_], gam[COUT_], del[COUT_];
    int t = threadIdx.x;
    if (t < CMID_) { pw[t] = proj_w[t]; cb[t] = proj_b[t] + ((t & 1) ? 1.f : 0.f); }
    __syncthreads();
    if (t < QOUT_) {
        float a = 0.f;
        for (int c = 0; c < CMID_; ++c) a += pw[c] * queries[t*CMID_ + c];
        alpha[t] = a;
    }
    if (t < COUT_) {
        float gg = 0.f, dd = 0.f;
        for (int c = 0; c < CMID_; ++c) {
            gg += pw[c] * fc_w[c*COUT_ + t];
            dd += cb[c] * fc_w[c*COUT_ + t];
        }
        gam[t] = gg; del[t] = dd + fc_b[t];
    }
    __syncthreads();
    for (int i = t; i < QOUT_*DIM; i += 128) {
        int q = i / DIM, d = i % DIM;
        float e = 0.f;
        for (int o = 0; o < COUT_; ++o) e += gam[o] * embed_w[(o*QOUT_ + q)*DIM + d];
        E[i] = e;
    }
    {
        float c = embed_b[t];
        for (int o = 0; o < COUT_; ++o) {
            float dl = del[o];
            for (int q = 0; q < QOUT_; ++q) c += dl * embed_w[(o*QOUT_ + q)*DIM + t];
        }
        c0[t] = c;
    }
}

// ---------------- encoder main (4 waves/block, one bt each) ----------------
__global__ __launch_bounds__(256) void enc_kernel(
    const float* __restrict__ x1, const float* __restrict__ alpha,
    const float* __restrict__ E, const float* __restrict__ c0,
    float* __restrict__ h, ushort_t* __restrict__ hb)
{
    int bt = (blockIdx.x << 2) + (threadIdx.x >> 6);
    int lane = threadIdx.x & 63;
    const float* xr = x1 + (size_t)bt * FIN_;
    float xv[4];
    bool vld[4];
    #pragma unroll
    for (int i = 0; i < 4; ++i) {
        int f = lane + (i << 6);
        vld[i] = (f < FIN_);
        xv[i] = vld[i] ? xr[f] : 0.f;
    }
    float vmax = -INFINITY, vmin = INFINITY;
    #pragma unroll
    for (int i = 0; i < 4; ++i) if (vld[i]) { vmax = fmaxf(vmax, xv[i]); vmin = fminf(vmin, xv[i]); }
    #pragma unroll
    for (int off = 1; off < 64; off <<= 1) {
        vmax = fmaxf(vmax, __shfl_xor(vmax, off));
        vmin = fminf(vmin, __shfl_xor(vmin, off));
    }
    float mq[QOUT_];
    for (int q = 0; q < QOUT_; ++q) {
        float a = alpha[q];
        float Mx = (a >= 0.f) ? a * vmax : a * vmin;
        float se = 0.f, sx = 0.f;
        #pragma unroll
        for (int i = 0; i < 4; ++i) if (vld[i]) {
            float e = __expf(fmaf(a, xv[i], -Mx));
            se += e; sx += e * xv[i];
        }
        #pragma unroll
        for (int off = 1; off < 64; off <<= 1) { se += __shfl_xor(se, off); sx += __shfl_xor(sx, off); }
        mq[q] = sx / se;
    }
    #pragma unroll
    for (int k = 0; k < 2; ++k) {
        int d = lane + (k << 6);
        float hv = c0[d];
        #pragma unroll
        for (int q = 0; q < QOUT_; ++q) hv = fmaf(mq[q], E[q*DIM + d], hv);
        h[(size_t)bt*DIM + d] = hv;
        hb[(size_t)bt*DIM + d] = (ushort_t)bf16r(hv);
    }
}

// ---------------- weight transpose + bf16 convert (once per launch) ----------------
__global__ __launch_bounds__(256) void wtrans_kernel(
    const float* __restrict__ wqkv, const float* __restrict__ wo,
    const float* __restrict__ w1, const float* __restrict__ w2,
    ushort_t* __restrict__ wts)
{
    int bid = blockIdx.x;
    const float* W; ushort_t* Wt; int K, N, tk, tn;
    if (bid < 72) {            // wqkv: K=128,N=384 -> 2x6 tiles x 6 layers
        int l = bid / 12, t = bid % 12; tk = t / 6; tn = t % 6; K = 128; N = 384;
        W = wqkv + (size_t)l*128*384; Wt = wts + (size_t)l*49152;
    } else if (bid < 96) {     // wo: 128x128 -> 2x2 x 6
        int q = bid - 72; int l = q / 4, t = q % 4; tk = t / 2; tn = t % 2; K = 128; N = 128;
        W = wo + (size_t)l*16384; Wt = wts + 294912 + (size_t)l*16384;
    } else if (bid < 192) {    // w1: K=128,N=512 -> 2x8 x 6
        int q = bid - 96; int l = q / 16, t = q % 16; tk = t / 8; tn = t % 8; K = 128; N = 512;
        W = w1 + (size_t)l*65536; Wt = wts + 393216 + (size_t)l*65536;
    } else {                   // w2: K=512,N=128 -> 8x2 x 6
        int q = bid - 192; int l = q / 16, t = q % 16; tk = t / 2; tn = t % 2; K = 512; N = 128;
        W = w2 + (size_t)l*65536; Wt = wts + 786432 + (size_t)l*65536;
    }
    int k0 = tk << 6, n0 = tn << 6;
    __shared__ float Ls[64][65];
    int tid = threadIdx.x;
    #pragma unroll
    for (int i = 0; i < 4; ++i) {
        int id = tid + 256*i;
        int r = id >> 4, ch = id & 15;
        float4 v = *reinterpret_cast<const float4*>(W + (size_t)(k0+r)*N + n0 + ch*4);
        Ls[ch*4+0][r] = v.x; Ls[ch*4+1][r] = v.y; Ls[ch*4+2][r] = v.z; Ls[ch*4+3][r] = v.w;
    }
    __syncthreads();
    #pragma unroll
    for (int i = 0; i < 4; ++i) {
        int id = tid + 256*i;
        int rr = id >> 4, ch = id & 15;
        uint2 o2;
        o2.x = pkbf16(Ls[rr][ch*4+0], Ls[rr][ch*4+1]);
        o2.y = pkbf16(Ls[rr][ch*4+2], Ls[rr][ch*4+3]);
        *reinterpret_cast<uint2*>(Wt + (size_t)(n0+rr)*K + k0 + ch*4) = o2;
    }
}

// ---------------- bf16 MFMA GEMM (first-layer qkv projection only) ----------
template<int BM>
__global__ __launch_bounds__(256) void gemm_mfma_kernel(
    const ushort_t* __restrict__ A, const ushort_t* __restrict__ Wt,
    const float* __restrict__ bias, void* __restrict__ C,
    int N, int K, int relu, int obf16)
{
    constexpr int MREP = BM / 32;
    constexpr int ASEG = BM / 32;
    __shared__ __align__(16) ushort_t As[BM * 64];
    __shared__ __align__(16) ushort_t Bs[64 * 64];
    const int tid = threadIdx.x;
    const int row0 = blockIdx.y * BM, col0 = blockIdx.x << 6;
    const int w = tid >> 6, lane = tid & 63, g = lane >> 4, n = lane & 15;
    const int wr = w & 1, wc = w >> 1;
    f32x4 acc[MREP][2];
    #pragma unroll
    for (int mt = 0; mt < MREP; ++mt)
        #pragma unroll
        for (int nt = 0; nt < 2; ++nt) acc[mt][nt] = (f32x4){0.f,0.f,0.f,0.f};

    for (int k0 = 0; k0 < K; k0 += 64) {
        __syncthreads();
        #pragma unroll
        for (int j = 0; j < ASEG; ++j) {
            int seg = w*ASEG + j;
            int id = seg*64 + lane;
            int r = id >> 3, cp = id & 7;
            gload16(A + (size_t)(row0 + r)*K + k0 + ((cp ^ (r & 7)) << 3),
                    As + seg*512);
        }
        #pragma unroll
        for (int j = 0; j < 2; ++j) {
            int seg = w*2 + j;
            int id = seg*64 + lane;
            int r = id >> 3, cp = id & 7;
            gload16(Wt + (size_t)(col0 + r)*K + k0 + ((cp ^ (r & 7)) << 3),
                    Bs + seg*512);
        }
        __syncthreads();
        #pragma unroll
        for (int ks = 0; ks < 2; ++ks) {
            short8 af[MREP], bfr[2];
            #pragma unroll
            for (int mt = 0; mt < MREP; ++mt) {
                int r = wr*(BM/2) + mt*16 + n;
                af[mt] = *reinterpret_cast<const short8*>(As + r*64 + (((ks*4 + g) ^ (r & 7)) << 3));
            }
            #pragma unroll
            for (int nt = 0; nt < 2; ++nt) {
                int r = wc*32 + nt*16 + n;
                bfr[nt] = *reinterpret_cast<const short8*>(Bs + r*64 + (((ks*4 + g) ^ (r & 7)) << 3));
            }
            #pragma unroll
            for (int mt = 0; mt < MREP; ++mt)
                #pragma unroll
                for (int nt = 0; nt < 2; ++nt)
                    acc[mt][nt] = __builtin_amdgcn_mfma_f32_16x16x32_bf16(af[mt], bfr[nt], acc[mt][nt], 0, 0, 0);
        }
    }
    #pragma unroll
    for (int mt = 0; mt < MREP; ++mt) {
        #pragma unroll
        for (int nt = 0; nt < 2; ++nt) {
            int col = col0 + wc*32 + nt*16 + n;
            float bv = bias[col];
            #pragma unroll
            for (int r4 = 0; r4 < 4; ++r4) {
                int row = row0 + wr*(BM/2) + mt*16 + g*4 + r4;
                float v = acc[mt][nt][r4] + bv;
                if (relu) v = fmaxf(v, 0.f);
                if (obf16) ((ushort_t*)C)[(size_t)row*N + col] = (ushort_t)bf16r(v);
                else       ((float*)C)[(size_t)row*N + col] = v;
            }
        }
    }
}

// ---------------- MFMA bf16 flash attention (QBLK=128, KVBLK=128, reg-prefetch) -------
// grid: B*NHEADS*4 blocks, 512 threads = 8 waves x 16 q-rows each.
// T3 ordering: bar1(drains prev prefetch) -> regs->LDS -> bar2 -> issue(kt+1) -> compute.
__global__ __launch_bounds__(512) void attn_mfma_kernel(
    const ushort_t* __restrict__ qkv, const float* __restrict__ rel,
    ushort_t* __restrict__ o)
{
    __shared__ __align__(16) ushort_t Ks[128][40];          // [kcol][dim] 80B rows
    __shared__ __align__(16) ushort_t Vs[128][40];          // [kcol][dim] 80B rows
    __shared__ __align__(16) ushort_t VB[4][2][4][16][8];   // [kch][dimhalf][g][n][j]
    __shared__ float rl[RELLEN];
    const int bid = blockIdx.x;
    const int qt = bid & 3;
    const int bh = bid >> 2;
    const int hh = bh & 3, b = bh >> 2;
    const int tid  = threadIdx.x;
    const int w    = tid >> 6;
    const int lane = tid & 63;
    const int g = lane >> 4, n = lane & 15;
    for (int i = tid; i < RELLEN; i += 512) rl[i] = rel[i] * LOG2E;

    const int qrow = (qt << 7) + (w << 4) + n;
    const bool qv = (qrow < TT);
    short8 qf = {0,0,0,0,0,0,0,0};
    if (qv) qf = *reinterpret_cast<const short8*>(qkv + (size_t)(b*TT + qrow)*384 + hh*HD + g*8);

    f32x4 acc0 = {0.f,0.f,0.f,0.f}, acc1 = {0.f,0.f,0.f,0.f};
    float m = -INFINITY, lsum = 0.f;
    const float scale2 = 0.17677669529663687f * LOG2E;
    const f32x4 zf = {0.f,0.f,0.f,0.f};

    const int sr = tid >> 2, sc = tid & 3;      // stage: 128 rows x 4 chunks of 16B
    uint4 kreg, vreg;
    auto issue = [&](const int kt, const bool domask) {
        int t = (kt << 7) + sr;
        kreg = make_uint4(0,0,0,0); vreg = make_uint4(0,0,0,0);
        if (!domask || t < TT) {
            const ushort_t* bp = qkv + (size_t)(b*TT + t)*384 + hh*HD + sc*8;
            kreg = *reinterpret_cast<const uint4*>(bp + 128);
            vreg = *reinterpret_cast<const uint4*>(bp + 256);
        }
    };

    auto compute = [&](const int kt, const bool domask) {
        const int k0 = kt << 7;
        // V relayout into fragment-linear VB (8 elems/thread, 512 threads)
        #pragma unroll
        for (int i = 0; i < 2; ++i) {
            int id = tid + (i << 9);
            int jh = (id & 1)*4, nn = (id >> 1) & 15, gg = (id >> 5) & 3;
            int dh = (id >> 7) & 1, kch = (id >> 8) & 3;
            ushort_t tmp[4];
            #pragma unroll
            for (int j = 0; j < 4; ++j) tmp[j] = Vs[kch*32 + gg*8 + jh + j][dh*16 + nn];
            *reinterpret_cast<uint2*>(&VB[kch][dh][gg][nn][jh]) = *reinterpret_cast<uint2*>(tmp);
        }

        // S^T = K . Q^T : 8 tiles of 16 kcols, in two halves (register pressure)
        float sv[32];
        float tmax = -INFINITY;
        #pragma unroll
        for (int half = 0; half < 2; ++half) {
            f32x4 s[4];
            #pragma unroll
            for (int c = 0; c < 4; ++c) {
                int cc = half*4 + c;
                short8 ak = *reinterpret_cast<const short8*>(&Ks[cc*16 + n][g*8]);
                s[c] = __builtin_amdgcn_mfma_f32_16x16x32_bf16(ak, qf, zf, 0, 0, 0);
            }
            #pragma unroll
            for (int c = 0; c < 4; ++c)
                #pragma unroll
                for (int r = 0; r < 4; ++r) {
                    int kc = k0 + (half*4 + c)*16 + g*4 + r;
                    float bia = rl[kc - qrow + (MAXLEN_-1)];
                    float v = fmaf(s[c][r], scale2, bia);
                    if (domask && kc >= TT) v = -1e30f;
                    sv[(half*4 + c)*4 + r] = v;
                    tmax = fmaxf(tmax, v);
                }
        }
        tmax = fmaxf(tmax, __shfl_xor(tmax, 16));
        tmax = fmaxf(tmax, __shfl_xor(tmax, 32));
        float mnew = fmaxf(m, tmax);
        float corr = exp2f(m - mnew);
        m = mnew;
        float ps = 0.f;
        #pragma unroll
        for (int r = 0; r < 32; ++r) { float e = exp2f(sv[r] - mnew); sv[r] = e; ps += e; }
        ps += __shfl_xor(ps, 16);
        ps += __shfl_xor(ps, 32);
        lsum = fmaf(lsum, corr, ps);

        // pack + exchange: 4 chains of 32 kcols each
        int src0 = n + ((g & 1) << 5);
        int src1 = src0 + 16;
        int t0 = (g < 2);
        short8 Pv[4];
        #pragma unroll
        for (int cch = 0; cch < 4; ++cch) {
            unsigned pk0lo = pkbf16(sv[cch*8+0], sv[cch*8+1]);
            unsigned pk0hi = pkbf16(sv[cch*8+2], sv[cch*8+3]);
            unsigned pk1lo = pkbf16(sv[cch*8+4], sv[cch*8+5]);
            unsigned pk1hi = pkbf16(sv[cch*8+6], sv[cch*8+7]);
            unsigned a0 = __shfl((int)pk0lo, src0), c0_ = __shfl((int)pk1lo, src0);
            unsigned a1 = __shfl((int)pk0hi, src0), c1_ = __shfl((int)pk1hi, src0);
            unsigned a2 = __shfl((int)pk0lo, src1), c2_ = __shfl((int)pk1lo, src1);
            unsigned a3 = __shfl((int)pk0hi, src1), c3_ = __shfl((int)pk1hi, src1);
            union { unsigned wd[4]; short8 v; } P;
            P.wd[0] = t0 ? a0 : c0_; P.wd[1] = t0 ? a1 : c1_;
            P.wd[2] = t0 ? a2 : c2_; P.wd[3] = t0 ? a3 : c3_;
            Pv[cch] = P.v;
        }

        #pragma unroll
        for (int r = 0; r < 4; ++r) { acc0[r] *= corr; acc1[r] *= corr; }
        #pragma unroll
        for (int kch = 0; kch < 4; ++kch) {
            short8 av0 = *reinterpret_cast<const short8*>(&VB[kch][0][g][n][0]);
            short8 av1 = *reinterpret_cast<const short8*>(&VB[kch][1][g][n][0]);
            acc0 = __builtin_amdgcn_mfma_f32_16x16x32_bf16(av0, Pv[kch], acc0, 0, 0, 0);
            acc1 = __builtin_amdgcn_mfma_f32_16x16x32_bf16(av1, Pv[kch], acc1, 0, 0, 0);
        }
    };

    issue(0, false);
    for (int kt = 0; kt < 4; ++kt) {
        __syncthreads();                        // LDS free; drains prefetch loads
        *reinterpret_cast<uint4*>(&Ks[sr][sc*8]) = kreg;
        *reinterpret_cast<uint4*>(&Vs[sr][sc*8]) = vreg;
        __syncthreads();                        // LDS ready (no loads in flight)
        if (kt < 3) issue(kt + 1, kt + 1 == 3); // loads fly under compute
        compute(kt, kt == 3);
    }

    if (qv) {
        float inv = 1.f / lsum;
        uint2 p0, p1;
        p0.x = pkbf16(acc0[0]*inv, acc0[1]*inv);
        p0.y = pkbf16(acc0[2]*inv, acc0[3]*inv);
        p1.x = pkbf16(acc1[0]*inv, acc1[1]*inv);
        p1.y = pkbf16(acc1[2]*inv, acc1[3]*inv);
        ushort_t* op = o + (size_t)(b*TT + qrow)*DIM + hh*HD + g*4;
        *reinterpret_cast<uint2*>(op)      = p0;
        *reinterpret_cast<uint2*>(op + 16) = p1;
    }
}

// ------- fused post-attention (T3 2-phase ping-pong weight staging) ----------
// wo GEMM + LN1 + merged FFN (per-chunk Mid) + LN2 + next-layer qkv.
__global__ __launch_bounds__(256) void pa_kernel(
    const ushort_t* __restrict__ attno, const ushort_t* __restrict__ wot,
    const float* __restrict__ bo, const ushort_t* __restrict__ W1t,
    const ushort_t* __restrict__ W2t, const float* __restrict__ b1v,
    const float* __restrict__ b2v, float* __restrict__ h,
    const float* __restrict__ ln1g, const float* __restrict__ ln1b,
    const float* __restrict__ ln2g, const float* __restrict__ ln2b,
    const ushort_t* __restrict__ wqkvN, const float* __restrict__ bqkvN,
    ushort_t* __restrict__ qkvout, int doqkv)
{
    __shared__ __align__(16) ushort_t As[32 * 128];     // 8 KB: attno, LN1 y, then LN2 y
    __shared__ __align__(16) ushort_t Wb0[8192];        // 16 KB ping
    __shared__ __align__(16) ushort_t Wb1[8192];        // 16 KB pong
    __shared__ __align__(16) ushort_t Mid[32 * 64];     // 4 KB (one k1-chunk)
    __shared__ float Hres[32 * 132];                    // 16.9 KB, padded rows
    __shared__ float red[4][32][2];
    __shared__ float stats[32][2];
    const int tid = threadIdx.x;
    const int row0 = blockIdx.x << 5;
    const int w = tid >> 6, lane = tid & 63, g = lane >> 4, n = lane & 15;

    // staging lambdas: per-lane swizzled global src -> linear LDS dest
    auto stageWo = [&](ushort_t* buf, int k0) {         // [128 n][64 k]
        #pragma unroll
        for (int j = 0; j < 4; ++j) {
            int seg = w*4 + j;
            int id = seg*64 + lane;
            int r = id >> 3, cp = id & 7;
            gload16(wot + (size_t)r*DIM + k0 + ((cp ^ (r & 7)) << 3), buf + seg*512);
        }
    };
    auto stageW1 = [&](ushort_t* buf, int cc) {         // [64 k1][128 k]
        #pragma unroll
        for (int j = 0; j < 4; ++j) {
            int seg = w*4 + j;
            int id = seg*64 + lane;
            int r = id >> 4, cp = id & 15;
            gload16(W1t + (size_t)(cc*64 + r)*DIM + ((cp ^ (r & 7)) << 3), buf + seg*512);
        }
    };
    auto stageW2 = [&](ushort_t* buf, int kc) {         // [128 c][64 k1]
        #pragma unroll
        for (int j = 0; j < 4; ++j) {
            int seg = w*4 + j;
            int id = seg*64 + lane;
            int r = id >> 3, cp = id & 7;
            gload16(W2t + (size_t)r*FFD + kc*64 + ((cp ^ (r & 7)) << 3), buf + seg*512);
        }
    };
    auto stageQ = [&](ushort_t* buf, int c) {           // [64 qcol][128 k]
        #pragma unroll
        for (int j = 0; j < 4; ++j) {
            int seg = w*4 + j;
            int id = seg*64 + lane;
            int r = id >> 4, cp = id & 15;
            gload16(wqkvN + (size_t)(c*64 + r)*DIM + ((cp ^ (r & 7)) << 3), buf + seg*512);
        }
    };

    // prologue: attno tile + wo chunk0
    #pragma unroll
    for (int j = 0; j < 2; ++j) {
        int seg = w*2 + j;
        int id = seg*64 + lane;
        int r = id >> 4, cp = id & 15;
        gload16(attno + (size_t)(row0 + r)*DIM + ((cp ^ (r & 7)) << 3), As + seg*512);
    }
    stageWo(Wb0, 0);
    __syncthreads();

    // ---- phase A: wo GEMM (K=128), 2 chunks ----
    f32x4 acc[2][2];
    #pragma unroll
    for (int a = 0; a < 2; ++a)
        #pragma unroll
        for (int b = 0; b < 2; ++b) acc[a][b] = (f32x4){0.f,0.f,0.f,0.f};
    #pragma unroll
    for (int ph = 0; ph < 2; ++ph) {
        // issue next chunk, then compute current (loads fly under MFMA)
        if (ph == 0) stageWo(Wb1, 64); else stageW1(Wb0, 0);
        const ushort_t* buf = (ph == 0) ? Wb0 : Wb1;
        int k0 = ph << 6;
        #pragma unroll
        for (int ks = 0; ks < 2; ++ks) {
            short8 af[2], bfr[2];
            #pragma unroll
            for (int mt = 0; mt < 2; ++mt) {
                int r = mt*16 + n;
                int ch = (k0 >> 3) + ks*4 + g;
                af[mt] = *reinterpret_cast<const short8*>(As + r*128 + ((ch ^ (r & 7)) << 3));
            }
            #pragma unroll
            for (int nt = 0; nt < 2; ++nt) {
                int r = w*32 + nt*16 + n;
                bfr[nt] = *reinterpret_cast<const short8*>(buf + r*64 + (((ks*4 + g) ^ (r & 7)) << 3));
            }
            #pragma unroll
            for (int mt = 0; mt < 2; ++mt)
                #pragma unroll
                for (int nt = 0; nt < 2; ++nt)
                    acc[mt][nt] = __builtin_amdgcn_mfma_f32_16x16x32_bf16(af[mt], bfr[nt], acc[mt][nt], 0, 0, 0);
        }
        __syncthreads();
    }
    // epilogue A: bias + residual + LN1 -> Hres (f32) + As (bf16); W1_0 DMA flies under it
    {
        float vals[2][2][4];
        #pragma unroll
        for (int nt = 0; nt < 2; ++nt) {
            int col = w*32 + nt*16 + n;
            float bv = bo[col];
            #pragma unroll
            for (int mt = 0; mt < 2; ++mt)
                #pragma unroll
                for (int r4 = 0; r4 < 4; ++r4) {
                    int row = row0 + mt*16 + g*4 + r4;
                    vals[mt][nt][r4] = acc[mt][nt][r4] + bv + h[(size_t)row*DIM + col];
                }
        }
        #pragma unroll
        for (int mt = 0; mt < 2; ++mt)
            #pragma unroll
            for (int r4 = 0; r4 < 4; ++r4) {
                float s  = vals[mt][0][r4] + vals[mt][1][r4];
                float s2 = vals[mt][0][r4]*vals[mt][0][r4] + vals[mt][1][r4]*vals[mt][1][r4];
                #pragma unroll
                for (int off = 1; off < 16; off <<= 1) {
                    s  += __shfl_xor(s, off);
                    s2 += __shfl_xor(s2, off);
                }
                if (n == 0) { red[w][mt*16 + g*4 + r4][0] = s; red[w][mt*16 + g*4 + r4][1] = s2; }
            }
        __syncthreads();
        if (tid < 32) {
            float s = 0.f, s2 = 0.f;
            #pragma unroll
            for (int ww = 0; ww < 4; ++ww) { s += red[ww][tid][0]; s2 += red[ww][tid][1]; }
            float mean = s * (1.f/128.f);
            float var  = s2 * (1.f/128.f) - mean*mean;
            stats[tid][0] = mean;
            stats[tid][1] = rsqrtf(var + 1e-5f);
        }
        __syncthreads();
        #pragma unroll
        for (int nt = 0; nt < 2; ++nt) {
            int col = w*32 + nt*16 + n;
            int ch = col >> 3, off8 = col & 7;
            float gv = ln1g[col], bv = ln1b[col];
            #pragma unroll
            for (int mt = 0; mt < 2; ++mt)
                #pragma unroll
                for (int r4 = 0; r4 < 4; ++r4) {
                    int rloc = mt*16 + g*4 + r4;
                    float y = (vals[mt][nt][r4] - stats[rloc][0]) * stats[rloc][1] * gv + bv;
                    Hres[rloc*132 + col] = y;
                    As[rloc*128 + ((ch ^ (rloc & 7)) << 3) + off8] = (ushort_t)bf16r(y);
                }
        }
    }
    __syncthreads();    // As(LN1) visible; W1_0 drained

    // ---- merged FFN: per k1-chunk {Mid_c = relu(As@W1_c+b1c); oacc += Mid_c@W2_c} ----
    f32x4 oacc[2][2];
    #pragma unroll
    for (int a = 0; a < 2; ++a)
        #pragma unroll
        for (int b = 0; b < 2; ++b) oacc[a][b] = (f32x4){0.f,0.f,0.f,0.f};
    for (int cc = 0; cc < 8; ++cc) {
        // sub-phase 1: issue W2_c -> Wb1; compute Mid_c from W1_c (Wb0)
        stageW2(Wb1, cc);
        {
            f32x4 acc1[2] = {{0.f,0.f,0.f,0.f},{0.f,0.f,0.f,0.f}};
            #pragma unroll
            for (int ks = 0; ks < 4; ++ks) {
                int rW = w*16 + n;
                short8 aw = *reinterpret_cast<const short8*>(Wb0 + rW*128 + (((ks*4 + g) ^ (rW & 7)) << 3));
                #pragma unroll
                for (int mt = 0; mt < 2; ++mt) {
                    int rA = mt*16 + n;
                    short8 bh_ = *reinterpret_cast<const short8*>(As + rA*128 + (((ks*4 + g) ^ (rA & 7)) << 3));
                    acc1[mt] = __builtin_amdgcn_mfma_f32_16x16x32_bf16(aw, bh_, acc1[mt], 0, 0, 0);
                }
            }
            int k1loc = w*16 + g*4;
            float4 bb = *reinterpret_cast<const float4*>(b1v + cc*64 + k1loc);
            int chloc = k1loc >> 3;
            int halfoff = (g & 1) * 4;
            #pragma unroll
            for (int mt = 0; mt < 2; ++mt) {
                int mrow = mt*16 + n;
                float v0 = fmaxf(acc1[mt][0] + bb.x, 0.f);
                float v1 = fmaxf(acc1[mt][1] + bb.y, 0.f);
                float v2 = fmaxf(acc1[mt][2] + bb.z, 0.f);
                float v3 = fmaxf(acc1[mt][3] + bb.w, 0.f);
                uint2 pk;
                pk.x = pkbf16(v0, v1);
                pk.y = pkbf16(v2, v3);
                *reinterpret_cast<uint2*>(Mid + mrow*64 + ((chloc ^ (mrow & 7)) << 3) + halfoff) = pk;
            }
        }
        __syncthreads();    // W2_c drained; Mid_c visible; Wb0 free

        // sub-phase 2: issue W1_{c+1} (or q0) -> Wb0; compute oacc += Mid_c @ W2_c (Wb1)
        if (cc < 7) stageW1(Wb0, cc + 1);
        else if (doqkv) stageQ(Wb0, 0);
        #pragma unroll
        for (int ks = 0; ks < 2; ++ks) {
            short8 aw[2], bm[2];
            #pragma unroll
            for (int ct = 0; ct < 2; ++ct) {
                int r = w*32 + ct*16 + n;
                aw[ct] = *reinterpret_cast<const short8*>(Wb1 + r*64 + (((ks*4 + g) ^ (r & 7)) << 3));
            }
            #pragma unroll
            for (int mt = 0; mt < 2; ++mt) {
                int r = mt*16 + n;
                bm[mt] = *reinterpret_cast<const short8*>(Mid + r*64 + (((ks*4 + g) ^ (r & 7)) << 3));
            }
            #pragma unroll
            for (int ct = 0; ct < 2; ++ct)
                #pragma unroll
                for (int mt = 0; mt < 2; ++mt)
                    oacc[ct][mt] = __builtin_amdgcn_mfma_f32_16x16x32_bf16(aw[ct], bm[mt], oacc[ct][mt], 0, 0, 0);
        }
        __syncthreads();    // W1_{c+1}/q0 drained; Mid free for overwrite
    }

    // epilogue B: bias + residual(Hres) + LN2 -> h (f32 global) + As (bf16 LDS)
    float vals[2][2][4];
    #pragma unroll
    for (int ct = 0; ct < 2; ++ct) {
        int colb = w*32 + ct*16 + g*4;
        float4 bb = *reinterpret_cast<const float4*>(b2v + colb);
        #pragma unroll
        for (int mt = 0; mt < 2; ++mt) {
            int rloc = mt*16 + n;
            float4 hres = *reinterpret_cast<const float4*>(&Hres[rloc*132 + colb]);
            vals[ct][mt][0] = oacc[ct][mt][0] + bb.x + hres.x;
            vals[ct][mt][1] = oacc[ct][mt][1] + bb.y + hres.y;
            vals[ct][mt][2] = oacc[ct][mt][2] + bb.z + hres.z;
            vals[ct][mt][3] = oacc[ct][mt][3] + bb.w + hres.w;
        }
    }
    #pragma unroll
    for (int mt = 0; mt < 2; ++mt) {
        float s = 0.f, s2 = 0.f;
        #pragma unroll
        for (int ct = 0; ct < 2; ++ct)
            #pragma unroll
            for (int r4 = 0; r4 < 4; ++r4) { float v = vals[ct][mt][r4]; s += v; s2 += v*v; }
        s  += __shfl_xor(s, 16);  s  += __shfl_xor(s, 32);
        s2 += __shfl_xor(s2, 16); s2 += __shfl_xor(s2, 32);
        if (g == 0) { red[w][mt*16 + n][0] = s; red[w][mt*16 + n][1] = s2; }
    }
    __syncthreads();
    if (tid < 32) {
        float s = 0.f, s2 = 0.f;
        #pragma unroll
        for (int ww = 0; ww < 4; ++ww) { s += red[ww][tid][0]; s2 += red[ww][tid][1]; }
        float mean = s * (1.f/128.f);
        float var  = s2 * (1.f/128.f) - mean*mean;
        stats[tid][0] = mean;
        stats[tid][1] = rsqrtf(var + 1e-5f);
    }
    __syncthreads();
    #pragma unroll
    for (int ct = 0; ct < 2; ++ct) {
        int colb = w*32 + ct*16 + g*4;
        float4 gv = *reinterpret_cast<const float4*>(ln2g + colb);
        float4 bv = *reinterpret_cast<const float4*>(ln2b + colb);
        int ch = colb >> 3;
        int halfoff = (g & 1) * 4;
        #pragma unroll
        for (int mt = 0; mt < 2; ++mt) {
            int rloc = mt*16 + n;
            int mrow = row0 + rloc;
            float mean = stats[rloc][0], rstd = stats[rloc][1];
            float y0 = (vals[ct][mt][0] - mean) * rstd * gv.x + bv.x;
            float y1 = (vals[ct][mt][1] - mean) * rstd * gv.y + bv.y;
            float y2 = (vals[ct][mt][2] - mean) * rstd * gv.z + bv.z;
            float y3 = (vals[ct][mt][3] - mean) * rstd * gv.w + bv.w;
            float4 yo = {y0, y1, y2, y3};
            *reinterpret_cast<float4*>(h + (size_t)mrow*DIM + colb) = yo;
            uint2 pk;
            pk.x = pkbf16(y0, y1);
            pk.y = pkbf16(y2, y3);
            *reinterpret_cast<uint2*>(As + rloc*128 + ((ch ^ (rloc & 7)) << 3) + halfoff) = pk;
        }
    }
    __syncthreads();    // As(LN2) visible; q0 drained

    // ---- phase C: next-layer qkv projection (ping-pong continues) ----
    if (doqkv) {
        for (int c6 = 0; c6 < 6; ++c6) {
            ushort_t* cur = (c6 & 1) ? Wb1 : Wb0;
            ushort_t* nxt = (c6 & 1) ? Wb0 : Wb1;
            if (c6 < 5) stageQ(nxt, c6 + 1);
            f32x4 qacc[2] = {{0.f,0.f,0.f,0.f},{0.f,0.f,0.f,0.f}};
            #pragma unroll
            for (int ks = 0; ks < 4; ++ks) {
                int rW = w*16 + n;
                short8 aw = *reinterpret_cast<const short8*>(cur + rW*128 + (((ks*4 + g) ^ (rW & 7)) << 3));
                #pragma unroll
                for (int mt = 0; mt < 2; ++mt) {
                    int rA = mt*16 + n;
                    short8 bh_ = *reinterpret_cast<const short8*>(As + rA*128 + (((ks*4 + g) ^ (rA & 7)) << 3));
                    qacc[mt] = __builtin_amdgcn_mfma_f32_16x16x32_bf16(aw, bh_, qacc[mt], 0, 0, 0);
                }
            }
            int colb = c6*64 + w*16 + g*4;
            float4 bb = *reinterpret_cast<const float4*>(bqkvN + colb);
            #pragma unroll
            for (int mt = 0; mt < 2; ++mt) {
                int mrow = row0 + mt*16 + n;
                uint2 pk;
                pk.x = pkbf16(qacc[mt][0] + bb.x, qacc[mt][1] + bb.y);
                pk.y = pkbf16(qacc[mt][2] + bb.z, qacc[mt][3] + bb.w);
                *reinterpret_cast<uint2*>(qkvout + (size_t)mrow*384 + colb) = pk;
            }
            if (c6 < 5) __syncthreads();
        }
    }
}

// ---------------- mean-pool + LN + classifier (4-way split pooling) ----------------
__global__ __launch_bounds__(512) void final_kernel(
    const float* __restrict__ h, const float* __restrict__ g,
    const float* __restrict__ bt, const float* __restrict__ cls_w,
    const float* __restrict__ cls_b, float* __restrict__ out)
{
    int b = blockIdx.x;
    int d = threadIdx.x & 127, q = threadIdx.x >> 7;
    __shared__ float psum[4][128];
    __shared__ float sm[4];
    __shared__ float px[DIM];
    float s = 0.f;
    int ta = q*125, tb = ta + 125;
    for (int t = ta; t < tb; ++t) s += h[((size_t)b*TT + t)*DIM + d];
    psum[q][d] = s;
    __syncthreads();
    if (q == 0) {
        float pooled = (psum[0][d] + psum[1][d] + psum[2][d] + psum[3][d]) * (1.f / TT);
        float v1 = pooled, v2 = pooled * pooled;
        #pragma unroll
        for (int off = 1; off < 64; off <<= 1) { v1 += __shfl_xor(v1, off); v2 += __shfl_xor(v2, off); }
        int wave = threadIdx.x >> 6, lane = threadIdx.x & 63;
        if (lane == 0) { sm[wave*2] = v1; sm[wave*2+1] = v2; }
        px[d] = pooled;
    }
    __syncthreads();
    if (q == 0) {
        float mean = (sm[0] + sm[2]) * (1.f/128.f);
        float var  = (sm[1] + sm[3]) * (1.f/128.f) - mean*mean;
        px[d] = (px[d] - mean) * rsqrtf(var + 1e-5f) * g[d] + bt[d];
    }
    __syncthreads();
    if (threadIdx.x < NCLS_) {
        float a = cls_b[threadIdx.x];
        for (int i = 0; i < DIM; ++i) a = fmaf(px[i], cls_w[i*NCLS_ + threadIdx.x], a);
        out[b*NCLS_ + threadIdx.x] = a;
    }
}

// ---------------- host ----------------
extern "C" void kernel_launch(void* const* d_in, const int* in_sizes, int n_in,
                              void* d_out, int out_size, void* d_ws, size_t ws_size,
                              hipStream_t stream)
{
    (void)in_sizes; (void)n_in; (void)out_size; (void)ws_size;
    const float* x1      = (const float*)d_in[0];
    const float* proj_w  = (const float*)d_in[1];
    const float* proj_b  = (const float*)d_in[2];
    const float* queries = (const float*)d_in[3];
    const float* fc_w    = (const float*)d_in[4];
    const float* fc_b    = (const float*)d_in[5];
    const float* embed_w = (const float*)d_in[6];
    const float* embed_b = (const float*)d_in[7];
    const float* wqkv    = (const float*)d_in[8];
    const float* bqkv    = (const float*)d_in[9];
    const float* wo      = (const float*)d_in[10];
    const float* bo      = (const float*)d_in[11];
    const float* w1      = (const float*)d_in[12];
    const float* b1      = (const float*)d_in[13];
    const float* w2      = (const float*)d_in[14];
    const float* b2      = (const float*)d_in[15];
    const float* ln1_g   = (const float*)d_in[16];
    const float* ln1_b   = (const float*)d_in[17];
    const float* ln2_g   = (const float*)d_in[18];
    const float* ln2_b   = (const float*)d_in[19];
    const float* rel_t   = (const float*)d_in[20];
    const float* final_g = (const float*)d_in[21];
    const float* final_b = (const float*)d_in[22];
    const float* cls_w   = (const float*)d_in[23];
    const float* cls_b   = (const float*)d_in[24];

    float* ws     = (float*)d_ws;
    float* h      = ws;                                    // MM*128 f32
    ushort_t* hb    = (ushort_t*)(h + (size_t)MM*DIM);     // MM*128 bf16 (enc -> first gemm)
    ushort_t* qkvb  = hb    + (size_t)MM*DIM;              // MM*384 bf16
    ushort_t* attno = qkvb  + (size_t)MM*384;              // MM*128 bf16
    ushort_t* wts   = attno + (size_t)MM*DIM;              // 1179648 bf16
    float* alpha  = (float*)(wts + 1179648);               // 16
    float* Emat   = alpha + 16;                            // 10*128
    float* c0     = Emat + QOUT_*DIM;                      // 128

    enc_pre_kernel<<<1, 128, 0, stream>>>(proj_w, proj_b, queries, fc_w, fc_b,
                                          embed_w, embed_b, alpha, Emat, c0);
    wtrans_kernel<<<288, 256, 0, stream>>>(wqkv, wo, w1, w2, wts);
    enc_kernel<<<MM/4, 256, 0, stream>>>(x1, alpha, Emat, c0, h, hb);

    // first-layer qkv projection (later layers fused into pa)
    gemm_mfma_kernel<128><<<dim3(384/64, MM/128), 256, 0, stream>>>(
        hb, wts, bqkv, qkvb, 384, DIM, 0, 1);

    for (int l = 0; l < NL; ++l) {
        const ushort_t* wo_t   = wts + 294912 + (size_t)l*16384;
        const ushort_t* w1_t   = wts + 393216 + (size_t)l*65536;
        const ushort_t* w2_t   = wts + 786432 + (size_t)l*65536;
        const int lnext = l + 1;
        const int doqkv = (lnext < NL);
        const ushort_t* wqkvN = wts + (size_t)(doqkv ? lnext : 0)*49152;
        const float*    bqkvN = bqkv + (doqkv ? lnext : 0)*3*DIM;

        attn_mfma_kernel<<<BB*NHEADS*4, 512, 0, stream>>>(
            qkvb, rel_t + l*RELLEN, attno);
        pa_kernel<<<MM/32, 256, 0, stream>>>(
            attno, wo_t, bo + l*DIM, w1_t, w2_t, b1 + l*FFD, b2 + l*DIM,
            h, ln1_g + l*DIM, ln1_b + l*DIM, ln2_g + l*DIM, ln2_b + l*DIM,
            wqkvN, bqkvN, qkvb, doqkv);
    }

    final_kernel<<<BB, 512, 0, stream>>>(h, final_g, final_b, cls_w, cls_b, (float*)d_out);
}